// Round 1
// baseline (1226.369 us; speedup 1.0000x reference)
//
#include <hip/hip_runtime.h>
#include <math.h>

// Problem constants
//  B=8, CTX=512, N_FRAMES=512, IN_DIM=1024, ST_DIM=128, HOP=512, N_SAMPLES=262144
//  HD=32, HL=16

// ---------------- workspace layout (float offsets) ----------------
static const size_t OFF_LAT   = 0;          // 5*8*16 = 640   (lat[m][b][l])
static const size_t OFF_IMP   = 1024;       // 8*512
static const size_t OFF_WSM   = 5120;       // Ws: 8*128*128
static const size_t OFF_WP    = 136192;     // Wp: 8*512*1024
static const size_t OFF_WO    = 4330496;    // Wo: 8*128*1024
static const size_t OFF_WDI   = 5379072;    // Wdi: 8*1024*1152  (Wd | Wi fused)
static const size_t OFF_CTRLT = 14816256;   // ctrl^2 transposed: 8*512*512 (later aliased by sig)
static const size_t OFF_PROJ  = 16913408;   // proj: 8*512*1024   (later aliased by Y)
static const size_t OFF_PROJD = 21107712;   // projD: 8*512*1152  (direct | Bu)
static const size_t OFF_S2    = 25826304;   // S2: 8*512*128
// total = 26350592 floats = ~100.5 MiB

// ---------------- K1: latents lat[m][b][l] = hv_m[b] @ A_m ----------------
__global__ void latents_kernel(
    const float* __restrict__ hv_p, const float* __restrict__ hv_s,
    const float* __restrict__ hv_i, const float* __restrict__ hv_o,
    const float* __restrict__ hv_d,
    const float* __restrict__ A_p, const float* __restrict__ A_s,
    const float* __restrict__ A_i, const float* __restrict__ A_o,
    const float* __restrict__ A_d,
    float* __restrict__ lat) {
  int tid = threadIdx.x;
  if (tid >= 640) return;
  int m = tid >> 7, b = (tid >> 4) & 7, l = tid & 15;
  const float* hv; const float* A;
  switch (m) {
    case 0: hv = hv_p; A = A_p; break;
    case 1: hv = hv_s; A = A_s; break;
    case 2: hv = hv_i; A = A_i; break;
    case 3: hv = hv_o; A = A_o; break;
    default: hv = hv_d; A = A_d; break;
  }
  float acc = 0.f;
  for (int h = 0; h < 32; ++h) acc = fmaf(hv[b * 32 + h], A[h * 16 + l], acc);
  lat[tid] = acc;
}

// ---------------- K2: W[b, r, c] = sum_l lat[b,l] * Bm[l, r*cols + c] ----------------
// out element at b*bstride + r*ostride + c  (ostride lets us fuse Wd|Wi into one buffer)
__global__ __launch_bounds__(256) void build_w_kernel(
    const float* __restrict__ lat,   // [8][16]
    const float* __restrict__ Bm,    // [16][total]
    float* __restrict__ out,
    int total, int cshift, int cmask, int ostride, size_t bstride) {
  int e = (blockIdx.x * 256 + threadIdx.x) * 4;
  if (e >= total) return;
  int r = e >> cshift, c = e & cmask;
  float4 v[16];
#pragma unroll
  for (int l = 0; l < 16; ++l)
    v[l] = *(const float4*)(Bm + (size_t)l * total + e);
  size_t obase = (size_t)r * ostride + c;
#pragma unroll 1
  for (int b = 0; b < 8; ++b) {
    float ax = 0.f, ay = 0.f, az = 0.f, aw = 0.f;
#pragma unroll
    for (int l = 0; l < 16; ++l) {
      float lv = lat[b * 16 + l];
      ax = fmaf(lv, v[l].x, ax);
      ay = fmaf(lv, v[l].y, ay);
      az = fmaf(lv, v[l].z, az);
      aw = fmaf(lv, v[l].w, aw);
    }
    float4 o = make_float4(ax, ay, az, aw);
    *(float4*)(out + (size_t)b * bstride + obase) = o;
  }
}

// ---------------- K3: ctrlT[b,f,c] = control[b,c,f]^2 ----------------
__global__ void transpose_sq_kernel(const float* __restrict__ in, float* __restrict__ out) {
  __shared__ float tile[32][33];
  int b = blockIdx.z;
  int c0 = blockIdx.x * 32, f0 = blockIdx.y * 32;
  int tx = threadIdx.x, ty = threadIdx.y;  // 32 x 8
  const float* inb = in + (size_t)b * 512 * 512;
  float* outb = out + (size_t)b * 512 * 512;
#pragma unroll
  for (int i = 0; i < 4; ++i) {
    float v = inb[(size_t)(c0 + ty + i * 8) * 512 + f0 + tx];
    tile[ty + i * 8][tx] = v * v;
  }
  __syncthreads();
#pragma unroll
  for (int i = 0; i < 4; ++i)
    outb[(size_t)(f0 + ty + i * 8) * 512 + c0 + tx] = tile[tx][ty + i * 8];
}

// ---------------- K4: batched f32 GEMM, BM=64 BN=128 BK=16, 256 thr, 4x8 micro ----------------
// C[b] = A[b](MxK, ld=lda) @ B[b](KxN row-major). EPI: C = (acc + D)*win(n), ld=ldd/ldc.
template <int EPI>
__global__ __launch_bounds__(256) void gemm_kernel(
    const float* __restrict__ A, int lda,
    const float* __restrict__ B,
    const float* __restrict__ D, int ldd,
    float* __restrict__ C, int ldc,
    int M, int N, int K) {
  const int b = blockIdx.z;
  A += (size_t)b * M * lda;
  B += (size_t)b * K * N;
  C += (size_t)b * M * ldc;
  if (EPI) D += (size_t)b * M * ldd;
  const int m0 = blockIdx.y * 64;
  const int n0 = blockIdx.x * 128;
  __shared__ __align__(16) float As[16][68];
  __shared__ __align__(16) float Bs[16][132];
  const int tid = threadIdx.x;
  const int tx = tid & 15, ty = tid >> 4;
  float acc[4][8];
#pragma unroll
  for (int i = 0; i < 4; ++i)
#pragma unroll
    for (int j = 0; j < 8; ++j) acc[i][j] = 0.f;

  const int am = tid >> 2, ak = (tid & 3) << 2;
  const int bk0 = tid >> 5, bn0 = (tid & 31) << 2;          // flat = tid
  const int bk1 = (256 + tid) >> 5, bn1 = ((256 + tid) & 31) << 2;  // flat = 256+tid

  for (int k0 = 0; k0 < K; k0 += 16) {
    float4 av = *(const float4*)(A + (size_t)(m0 + am) * lda + k0 + ak);
    float4 bv0 = *(const float4*)(B + (size_t)(k0 + bk0) * N + n0 + bn0);
    float4 bv1 = *(const float4*)(B + (size_t)(k0 + bk1) * N + n0 + bn1);
    __syncthreads();
    As[ak + 0][am] = av.x;
    As[ak + 1][am] = av.y;
    As[ak + 2][am] = av.z;
    As[ak + 3][am] = av.w;
    *(float4*)(&Bs[bk0][bn0]) = bv0;
    *(float4*)(&Bs[bk1][bn1]) = bv1;
    __syncthreads();
#pragma unroll
    for (int kk = 0; kk < 16; ++kk) {
      float4 a4 = *(const float4*)(&As[kk][ty << 2]);
      float4 b4a = *(const float4*)(&Bs[kk][tx << 2]);
      float4 b4b = *(const float4*)(&Bs[kk][64 + (tx << 2)]);
      float aa[4] = {a4.x, a4.y, a4.z, a4.w};
      float bb[8] = {b4a.x, b4a.y, b4a.z, b4a.w, b4b.x, b4b.y, b4b.z, b4b.w};
#pragma unroll
      for (int i = 0; i < 4; ++i)
#pragma unroll
        for (int j = 0; j < 8; ++j) acc[i][j] = fmaf(aa[i], bb[j], acc[i][j]);
    }
  }

  float win[8];
  if (EPI) {
#pragma unroll
    for (int j = 0; j < 8; ++j) {
      int n = n0 + ((j < 4) ? ((tx << 2) + j) : (64 + (tx << 2) + j - 4));
      win[j] = 0.5f - 0.5f * cosf(6.28318530717958647693f * (float)n / 1024.0f);
    }
  }
#pragma unroll
  for (int i = 0; i < 4; ++i) {
    int m = m0 + (ty << 2) + i;
#pragma unroll
    for (int half = 0; half < 2; ++half) {
      int n = n0 + half * 64 + (tx << 2);
      float o0 = acc[i][half * 4 + 0];
      float o1 = acc[i][half * 4 + 1];
      float o2 = acc[i][half * 4 + 2];
      float o3 = acc[i][half * 4 + 3];
      if (EPI) {
        const float* drow = D + (size_t)m * ldd + n;
        o0 = (o0 + drow[0]) * win[half * 4 + 0];
        o1 = (o1 + drow[1]) * win[half * 4 + 1];
        o2 = (o2 + drow[2]) * win[half * 4 + 2];
        o3 = (o3 + drow[3]) * win[half * 4 + 3];
      }
      float4 o = make_float4(o0, o1, o2, o3);
      *(float4*)(C + (size_t)m * ldc + n) = o;
    }
  }
}

// ---------------- K5: sequential state scan ----------------
// s2_f = s_f @ Ws ; S2[f] = s2_f ; s_{f+1} = s2_f + Bu[f]   (Bu lives in projD cols 1024..1151)
__global__ __launch_bounds__(128) void scan_kernel(
    const float* __restrict__ W,     // Ws: [8][128][128]
    const float* __restrict__ PD,    // projD: [8][512][1152]
    float* __restrict__ S2) {        // [8][512][128]
  int b = blockIdx.x, t = threadIdx.x;
  __shared__ __align__(16) float ssh[2][128];
  float w[128];
  const float* Wb = W + (size_t)b * 16384;
#pragma unroll
  for (int k = 0; k < 128; ++k) w[k] = Wb[k * 128 + t];
  ssh[0][t] = 0.f;
  __syncthreads();
  const float* Bu = PD + (size_t)b * 512 * 1152 + 1024;
  float* S2b = S2 + (size_t)b * 512 * 128;
  int cur = 0;
#pragma unroll 1
  for (int f = 0; f < 512; ++f) {
    float bu = Bu[(size_t)f * 1152 + t];  // independent of the dot; issues early
    float a0 = 0.f, a1 = 0.f, a2 = 0.f, a3 = 0.f;
#pragma unroll
    for (int k = 0; k < 128; k += 4) {
      float4 sv = *(const float4*)(&ssh[cur][k]);
      a0 = fmaf(sv.x, w[k + 0], a0);
      a1 = fmaf(sv.y, w[k + 1], a1);
      a2 = fmaf(sv.z, w[k + 2], a2);
      a3 = fmaf(sv.w, w[k + 3], a3);
    }
    float s2 = (a0 + a1) + (a2 + a3);
    S2b[(size_t)f * 128 + t] = s2;
    ssh[cur ^ 1][t] = s2 + bu;
    cur ^= 1;
    __syncthreads();
  }
}

// ---------------- K6: softmax over frames ----------------
__global__ void softmax_kernel(const float* __restrict__ times, float* __restrict__ imp) {
  int b = blockIdx.x, t = threadIdx.x;  // 512 threads
  __shared__ float red[512];
  float v = times[b * 512 + t];
  red[t] = v;
  __syncthreads();
  for (int s = 256; s > 0; s >>= 1) {
    if (t < s) red[t] = fmaxf(red[t], red[t + s]);
    __syncthreads();
  }
  float m = red[0];
  __syncthreads();
  float e = expf(v - m);
  red[t] = e;
  __syncthreads();
  for (int s = 256; s > 0; s >>= 1) {
    if (t < s) red[t] += red[t + s];
    __syncthreads();
  }
  imp[b * 512 + t] = e / red[0];
}

// ---------------- K7: overlap-add (window already applied in Y epilogue) ----------------
__global__ void ola_kernel(const float* __restrict__ Y, float* __restrict__ sig) {
  int idx = blockIdx.x * 256 + threadIdx.x;  // 8 * 262144 total
  int b = idx >> 18;
  int n = idx & 262143;
  int q = n >> 9, r = n & 511;
  float v = Y[((size_t)b * 512 + q) * 1024 + r];
  if (q > 0) v += Y[((size_t)b * 512 + q - 1) * 1024 + 512 + r];
  sig[idx] = v;
}

// ---------------- K8: sparse impulse convolution ----------------
// y[b, 512q + r] = sum_{p=0..q} imp[b, q-p] * sig[b, 512p + r]
__global__ __launch_bounds__(256) void conv_kernel(
    const float* __restrict__ sig, const float* __restrict__ imp,
    float* __restrict__ out) {
  int b = blockIdx.x >> 5;            // 8 batches x 32 q-tiles of 16
  int q0 = (blockIdx.x & 31) * 16;
  int tid = threadIdx.x;
  int qi = tid >> 4, rg = tid & 15;
  int q = q0 + qi;
  __shared__ float imp_sh[512];
  __shared__ __align__(16) float sg[4][512];
  imp_sh[tid] = imp[b * 512 + tid];
  imp_sh[256 + tid] = imp[b * 512 + 256 + tid];
  const float* sigb = sig + (size_t)b * 262144;
  float acc[32];
#pragma unroll
  for (int j = 0; j < 32; ++j) acc[j] = 0.f;
  int pmax = q0 + 15;
  for (int pc = 0; pc <= pmax; pc += 4) {
    __syncthreads();
#pragma unroll
    for (int ii = 0; ii < 8; ++ii) {
      int flat = ii * 256 + tid;
      int pp = flat >> 9, col = flat & 511;
      int p = pc + pp;
      sg[pp][col] = (p < 512) ? sigb[(size_t)p * 512 + col] : 0.f;
    }
    __syncthreads();
#pragma unroll
    for (int pp = 0; pp < 4; ++pp) {
      int p = pc + pp;
      float im = (p <= q) ? imp_sh[q - p] : 0.f;
#pragma unroll
      for (int j = 0; j < 32; ++j)
        acc[j] = fmaf(im, sg[pp][j * 16 + rg], acc[j]);
    }
  }
  float* outb = out + (size_t)b * 262144 + (size_t)q * 512;
#pragma unroll
  for (int j = 0; j < 32; ++j) outb[j * 16 + rg] = acc[j];
}

// ---------------- launcher ----------------
extern "C" void kernel_launch(void* const* d_in, const int* in_sizes, int n_in,
                              void* d_out, int out_size, void* d_ws, size_t ws_size,
                              hipStream_t stream) {
  const float* control   = (const float*)d_in[0];
  const float* state_hv  = (const float*)d_in[1];
  const float* output_hv = (const float*)d_in[2];
  const float* input_hv  = (const float*)d_in[3];
  const float* direct_hv = (const float*)d_in[4];
  const float* proj_hv   = (const float*)d_in[5];
  const float* times     = (const float*)d_in[6];
  const float* A_proj   = (const float*)d_in[7];
  const float* B_proj   = (const float*)d_in[8];
  const float* A_state  = (const float*)d_in[9];
  const float* B_state  = (const float*)d_in[10];
  const float* A_input  = (const float*)d_in[11];
  const float* B_input  = (const float*)d_in[12];
  const float* A_output = (const float*)d_in[13];
  const float* B_output = (const float*)d_in[14];
  const float* A_direct = (const float*)d_in[15];
  const float* B_direct = (const float*)d_in[16];

  float* ws    = (float*)d_ws;
  float* lat   = ws + OFF_LAT;
  float* impw  = ws + OFF_IMP;
  float* Wsm   = ws + OFF_WSM;
  float* Wp    = ws + OFF_WP;
  float* Wo    = ws + OFF_WO;
  float* Wdi   = ws + OFF_WDI;
  float* ctrlT = ws + OFF_CTRLT;
  float* proj  = ws + OFF_PROJ;
  float* projD = ws + OFF_PROJD;
  float* S2    = ws + OFF_S2;
  float* Y   = proj;    // proj dead after projD GEMM
  float* sig = ctrlT;   // ctrlT dead after proj GEMM
  float* out = (float*)d_out;

  // K1 latents: lat[m][b][l], m: 0=proj,1=state,2=input,3=output,4=direct
  latents_kernel<<<1, 640, 0, stream>>>(proj_hv, state_hv, input_hv, output_hv, direct_hv,
                                        A_proj, A_state, A_input, A_output, A_direct, lat);

  // K2 builds: (lat_m, Bm, out, total, cshift, cmask, ostride, bstride)
  build_w_kernel<<<512, 256, 0, stream>>>(lat + 0 * 128, B_proj, Wp, 524288, 10, 1023, 1024, 524288);
  build_w_kernel<<<16, 256, 0, stream>>>(lat + 1 * 128, B_state, Wsm, 16384, 7, 127, 128, 16384);
  build_w_kernel<<<1024, 256, 0, stream>>>(lat + 4 * 128, B_direct, Wdi, 1048576, 10, 1023, 1152, 1179648);
  build_w_kernel<<<128, 256, 0, stream>>>(lat + 2 * 128, B_input, Wdi + 1024, 131072, 7, 127, 1152, 1179648);
  build_w_kernel<<<128, 256, 0, stream>>>(lat + 3 * 128, B_output, Wo, 131072, 10, 1023, 1024, 131072);

  // K3 transpose + square
  transpose_sq_kernel<<<dim3(16, 16, 8), dim3(32, 8), 0, stream>>>(control, ctrlT);

  // K4a proj = ctrlT @ Wp   (M=512, N=1024, K=512)
  gemm_kernel<0><<<dim3(8, 8, 8), 256, 0, stream>>>(ctrlT, 512, Wp, nullptr, 0, proj, 1024, 512, 1024, 512);

  // K4b projD = proj @ [Wd|Wi]   (M=512, N=1152, K=1024)
  gemm_kernel<0><<<dim3(9, 8, 8), 256, 0, stream>>>(proj, 1024, Wdi, nullptr, 0, projD, 1152, 512, 1152, 1024);

  // K5 scan -> S2
  scan_kernel<<<8, 128, 0, stream>>>(Wsm, projD, S2);

  // K4c Y = (S2 @ Wo + direct) * win   (M=512, N=1024, K=128), direct = projD cols 0..1023
  gemm_kernel<1><<<dim3(8, 8, 8), 256, 0, stream>>>(S2, 128, Wo, projD, 1152, Y, 1024, 512, 1024, 128);

  // K6 softmax(times) -> imp
  softmax_kernel<<<8, 512, 0, stream>>>(times, impw);

  // K7 overlap-add -> sig
  ola_kernel<<<8192, 256, 0, stream>>>(Y, sig);

  // K8 sparse convolution -> out
  conv_kernel<<<256, 256, 0, stream>>>(sig, impw, out);
}

// Round 2
// 657.478 us; speedup vs baseline: 1.8653x; 1.8653x over previous
//
#include <hip/hip_runtime.h>
#include <math.h>

// Problem constants
//  B=8, CTX=512, N_FRAMES=512, IN_DIM=1024, ST_DIM=128, HOP=512, N_SAMPLES=262144
//  HD=32, HL=16
// Scan parallelization: T=8 frames/chunk, C=64 chunks.

// ---------------- workspace layout (float offsets) ----------------
static const size_t OFF_LAT   = 0;          // 5*8*16 = 640   (lat[m][b][l])
static const size_t OFF_IMP   = 1024;       // 8*512
static const size_t OFF_WSM   = 5120;       // Ws: 8*128*128
static const size_t OFF_WP    = 136192;     // Wp: 8*512*1024  (dead after proj GEMM -> Ec/Hc alias)
static const size_t OFF_WO    = 4330496;    // Wo: 8*128*1024
static const size_t OFF_WDI   = 5379072;    // Wdi: 8*1024*1152  (Wd | Wi fused)
static const size_t OFF_CTRLT = 14816256;   // ctrl^2 transposed: 8*512*512 (later: Mpow, then sig)
static const size_t OFF_PROJ  = 16913408;   // proj: 8*512*1024   (later aliased by Y)
static const size_t OFF_PROJD = 21107712;   // projD: 8*512*1152  (direct | Bu)
static const size_t OFF_S2    = 25826304;   // S2: 8*512*128
// aliases:
static const size_t OFF_MPOW  = OFF_CTRLT;  // Mpow: 8*9*16384 = 1,179,648 floats (ctrlT dead after proj GEMM)
static const size_t OFF_EC    = OFF_WP;           // Ec: 8*64*128
static const size_t OFF_HC    = OFF_WP + 65536;   // Hc: 8*64*128
// total = 26,350,592 floats = ~100.5 MiB (unchanged)

// ---------------- K1: latents lat[m][b][l] = hv_m[b] @ A_m ----------------
__global__ void latents_kernel(
    const float* __restrict__ hv_p, const float* __restrict__ hv_s,
    const float* __restrict__ hv_i, const float* __restrict__ hv_o,
    const float* __restrict__ hv_d,
    const float* __restrict__ A_p, const float* __restrict__ A_s,
    const float* __restrict__ A_i, const float* __restrict__ A_o,
    const float* __restrict__ A_d,
    float* __restrict__ lat) {
  int tid = threadIdx.x;
  if (tid >= 640) return;
  int m = tid >> 7, b = (tid >> 4) & 7, l = tid & 15;
  const float* hv; const float* A;
  switch (m) {
    case 0: hv = hv_p; A = A_p; break;
    case 1: hv = hv_s; A = A_s; break;
    case 2: hv = hv_i; A = A_i; break;
    case 3: hv = hv_o; A = A_o; break;
    default: hv = hv_d; A = A_d; break;
  }
  float acc = 0.f;
  for (int h = 0; h < 32; ++h) acc = fmaf(hv[b * 32 + h], A[h * 16 + l], acc);
  lat[tid] = acc;
}

// ---------------- K2: W[b, r, c] = sum_l lat[b,l] * Bm[l, r*cols + c] ----------------
__global__ __launch_bounds__(256) void build_w_kernel(
    const float* __restrict__ lat,   // [8][16]
    const float* __restrict__ Bm,    // [16][total]
    float* __restrict__ out,
    int total, int cshift, int cmask, int ostride, size_t bstride) {
  int e = (blockIdx.x * 256 + threadIdx.x) * 4;
  if (e >= total) return;
  int r = e >> cshift, c = e & cmask;
  float4 v[16];
#pragma unroll
  for (int l = 0; l < 16; ++l)
    v[l] = *(const float4*)(Bm + (size_t)l * total + e);
  size_t obase = (size_t)r * ostride + c;
#pragma unroll 1
  for (int b = 0; b < 8; ++b) {
    float ax = 0.f, ay = 0.f, az = 0.f, aw = 0.f;
#pragma unroll
    for (int l = 0; l < 16; ++l) {
      float lv = lat[b * 16 + l];
      ax = fmaf(lv, v[l].x, ax);
      ay = fmaf(lv, v[l].y, ay);
      az = fmaf(lv, v[l].z, az);
      aw = fmaf(lv, v[l].w, aw);
    }
    float4 o = make_float4(ax, ay, az, aw);
    *(float4*)(out + (size_t)b * bstride + obase) = o;
  }
}

// ---------------- K3: ctrlT[b,f,c] = control[b,c,f]^2 ----------------
__global__ void transpose_sq_kernel(const float* __restrict__ in, float* __restrict__ out) {
  __shared__ float tile[32][33];
  int b = blockIdx.z;
  int c0 = blockIdx.x * 32, f0 = blockIdx.y * 32;
  int tx = threadIdx.x, ty = threadIdx.y;  // 32 x 8
  const float* inb = in + (size_t)b * 512 * 512;
  float* outb = out + (size_t)b * 512 * 512;
#pragma unroll
  for (int i = 0; i < 4; ++i) {
    float v = inb[(size_t)(c0 + ty + i * 8) * 512 + f0 + tx];
    tile[ty + i * 8][tx] = v * v;
  }
  __syncthreads();
#pragma unroll
  for (int i = 0; i < 4; ++i)
    outb[(size_t)(f0 + ty + i * 8) * 512 + c0 + tx] = tile[tx][ty + i * 8];
}

// ---------------- K4: batched f32 GEMM, BM=64 BN=128 BK=16, 256 thr, 4x8 micro ----------------
template <int EPI>
__global__ __launch_bounds__(256) void gemm_kernel(
    const float* __restrict__ A, int lda,
    const float* __restrict__ B,
    const float* __restrict__ D, int ldd,
    float* __restrict__ C, int ldc,
    int M, int N, int K) {
  const int b = blockIdx.z;
  A += (size_t)b * M * lda;
  B += (size_t)b * K * N;
  C += (size_t)b * M * ldc;
  if (EPI) D += (size_t)b * M * ldd;
  const int m0 = blockIdx.y * 64;
  const int n0 = blockIdx.x * 128;
  __shared__ __align__(16) float As[16][68];
  __shared__ __align__(16) float Bs[16][132];
  const int tid = threadIdx.x;
  const int tx = tid & 15, ty = tid >> 4;
  float acc[4][8];
#pragma unroll
  for (int i = 0; i < 4; ++i)
#pragma unroll
    for (int j = 0; j < 8; ++j) acc[i][j] = 0.f;

  const int am = tid >> 2, ak = (tid & 3) << 2;
  const int bk0 = tid >> 5, bn0 = (tid & 31) << 2;
  const int bk1 = (256 + tid) >> 5, bn1 = ((256 + tid) & 31) << 2;

  for (int k0 = 0; k0 < K; k0 += 16) {
    float4 av = *(const float4*)(A + (size_t)(m0 + am) * lda + k0 + ak);
    float4 bv0 = *(const float4*)(B + (size_t)(k0 + bk0) * N + n0 + bn0);
    float4 bv1 = *(const float4*)(B + (size_t)(k0 + bk1) * N + n0 + bn1);
    __syncthreads();
    As[ak + 0][am] = av.x;
    As[ak + 1][am] = av.y;
    As[ak + 2][am] = av.z;
    As[ak + 3][am] = av.w;
    *(float4*)(&Bs[bk0][bn0]) = bv0;
    *(float4*)(&Bs[bk1][bn1]) = bv1;
    __syncthreads();
#pragma unroll
    for (int kk = 0; kk < 16; ++kk) {
      float4 a4 = *(const float4*)(&As[kk][ty << 2]);
      float4 b4a = *(const float4*)(&Bs[kk][tx << 2]);
      float4 b4b = *(const float4*)(&Bs[kk][64 + (tx << 2)]);
      float aa[4] = {a4.x, a4.y, a4.z, a4.w};
      float bb[8] = {b4a.x, b4a.y, b4a.z, b4a.w, b4b.x, b4b.y, b4b.z, b4b.w};
#pragma unroll
      for (int i = 0; i < 4; ++i)
#pragma unroll
        for (int j = 0; j < 8; ++j) acc[i][j] = fmaf(aa[i], bb[j], acc[i][j]);
    }
  }

  float win[8];
  if (EPI) {
#pragma unroll
    for (int j = 0; j < 8; ++j) {
      int n = n0 + ((j < 4) ? ((tx << 2) + j) : (64 + (tx << 2) + j - 4));
      win[j] = 0.5f - 0.5f * cosf(6.28318530717958647693f * (float)n / 1024.0f);
    }
  }
#pragma unroll
  for (int i = 0; i < 4; ++i) {
    int m = m0 + (ty << 2) + i;
#pragma unroll
    for (int half = 0; half < 2; ++half) {
      int n = n0 + half * 64 + (tx << 2);
      float o0 = acc[i][half * 4 + 0];
      float o1 = acc[i][half * 4 + 1];
      float o2 = acc[i][half * 4 + 2];
      float o3 = acc[i][half * 4 + 3];
      if (EPI) {
        const float* drow = D + (size_t)m * ldd + n;
        o0 = (o0 + drow[0]) * win[half * 4 + 0];
        o1 = (o1 + drow[1]) * win[half * 4 + 1];
        o2 = (o2 + drow[2]) * win[half * 4 + 2];
        o3 = (o3 + drow[3]) * win[half * 4 + 3];
      }
      float4 o = make_float4(o0, o1, o2, o3);
      *(float4*)(C + (size_t)m * ldc + n) = o;
    }
  }
}

// ---------------- K5a0: copy Ws into Mpow slot 1 ----------------
__global__ void copym1_kernel(const float* __restrict__ Wsm, float* __restrict__ Mpow) {
  int i = blockIdx.x * 256 + threadIdx.x;  // 32768 float4s total
  int b = i >> 12, r = i & 4095;
  *(float4*)(Mpow + ((size_t)b * 9 + 1) * 16384 + (size_t)r * 4) =
      *(const float4*)(Wsm + (size_t)b * 16384 + (size_t)r * 4);
}

// ---------------- K5a: power step  M_{half+k} = M_k @ M_half,  k=1..half ----------------
__global__ __launch_bounds__(256) void powers_kernel(float* __restrict__ Mpow, int half) {
  int z = blockIdx.x;
  int b = z / half, k = z - b * half + 1;
  const float* A = Mpow + ((size_t)b * 9 + k) * 16384;
  const float* Bm = Mpow + ((size_t)b * 9 + half) * 16384;
  float* C = Mpow + ((size_t)b * 9 + half + k) * 16384;
  __shared__ __align__(16) float As[16][132];
  __shared__ __align__(16) float Bs[16][132];
  int tid = threadIdx.x;
  int tx = tid & 15, ty = tid >> 4;
  float acc[8][8];
#pragma unroll
  for (int i = 0; i < 8; ++i)
#pragma unroll
    for (int j = 0; j < 8; ++j) acc[i][j] = 0.f;
  int ar = tid >> 1, ac = (tid & 1) * 8;
  int br = tid >> 4, bc = (tid & 15) * 8;
  for (int k0 = 0; k0 < 128; k0 += 16) {
    float4 a0 = *(const float4*)(A + (size_t)ar * 128 + k0 + ac);
    float4 a1 = *(const float4*)(A + (size_t)ar * 128 + k0 + ac + 4);
    float4 b0 = *(const float4*)(Bm + (size_t)(k0 + br) * 128 + bc);
    float4 b1 = *(const float4*)(Bm + (size_t)(k0 + br) * 128 + bc + 4);
    __syncthreads();
    As[ac + 0][ar] = a0.x; As[ac + 1][ar] = a0.y; As[ac + 2][ar] = a0.z; As[ac + 3][ar] = a0.w;
    As[ac + 4][ar] = a1.x; As[ac + 5][ar] = a1.y; As[ac + 6][ar] = a1.z; As[ac + 7][ar] = a1.w;
    *(float4*)(&Bs[br][bc]) = b0;
    *(float4*)(&Bs[br][bc + 4]) = b1;
    __syncthreads();
#pragma unroll
    for (int kk = 0; kk < 16; ++kk) {
      float4 av0 = *(const float4*)(&As[kk][ty * 8]);
      float4 av1 = *(const float4*)(&As[kk][ty * 8 + 4]);
      float4 bv0 = *(const float4*)(&Bs[kk][tx * 8]);
      float4 bv1 = *(const float4*)(&Bs[kk][tx * 8 + 4]);
      float aa[8] = {av0.x, av0.y, av0.z, av0.w, av1.x, av1.y, av1.z, av1.w};
      float bb[8] = {bv0.x, bv0.y, bv0.z, bv0.w, bv1.x, bv1.y, bv1.z, bv1.w};
#pragma unroll
      for (int i = 0; i < 8; ++i)
#pragma unroll
        for (int j = 0; j < 8; ++j) acc[i][j] = fmaf(aa[i], bb[j], acc[i][j]);
    }
  }
#pragma unroll
  for (int i = 0; i < 8; ++i) {
    float4 o0 = make_float4(acc[i][0], acc[i][1], acc[i][2], acc[i][3]);
    float4 o1 = make_float4(acc[i][4], acc[i][5], acc[i][6], acc[i][7]);
    *(float4*)(C + (size_t)(ty * 8 + i) * 128 + tx * 8) = o0;
    *(float4*)(C + (size_t)(ty * 8 + i) * 128 + tx * 8 + 4) = o1;
  }
}

// ---------------- K5b: chunk aggregates  e_c = sum_{i=0..6} Bu[c*8+i] M_{7-i} + Bu[c*8+7] ----------------
__global__ __launch_bounds__(256) void ec_kernel(
    const float* __restrict__ Mpow, const float* __restrict__ PD,
    float* __restrict__ Ec) {
  int b = blockIdx.x >> 6, c = blockIdx.x & 63;
  int tid = threadIdx.x, t = tid & 127, dh = tid >> 7;
  __shared__ __align__(16) float Bus[7][128];
  __shared__ float red[128];
  const float* Bu = PD + (size_t)b * 512 * 1152 + 1024;
  for (int idx = tid; idx < 896; idx += 256)
    Bus[idx >> 7][idx & 127] = Bu[(size_t)(c * 8 + (idx >> 7)) * 1152 + (idx & 127)];
  __syncthreads();
  float acc = 0.f;
  const float* Mb = Mpow + (size_t)b * 9 * 16384;
  int d0 = dh * 64;
#pragma unroll
  for (int i = 0; i < 7; ++i) {
    const float* Mk = Mb + (size_t)(7 - i) * 16384 + t;
#pragma unroll 8
    for (int d = 0; d < 64; ++d)
      acc = fmaf(Bus[i][d0 + d], Mk[(size_t)(d0 + d) * 128], acc);
  }
  if (dh == 1) red[t] = acc;
  __syncthreads();
  if (dh == 0) {
    float tot = acc + red[t] + Bu[(size_t)(c * 8 + 7) * 1152 + t];
    Ec[((size_t)b * 64 + c) * 128 + t] = tot;
  }
}

// ---------------- K5c: serial chunk combine  h_{c+1} = h_c @ M_8 + e_c ----------------
__global__ __launch_bounds__(128) void combine_kernel(
    const float* __restrict__ Mpow, const float* __restrict__ Ec,
    float* __restrict__ Hc) {
  int b = blockIdx.x, t = threadIdx.x;
  float w[128];
  const float* M8 = Mpow + ((size_t)b * 9 + 8) * 16384;
#pragma unroll
  for (int k = 0; k < 128; ++k) w[k] = M8[(size_t)k * 128 + t];
  __shared__ __align__(16) float sh[128];
  sh[t] = 0.f;
  Hc[((size_t)b * 64) * 128 + t] = 0.f;
  __syncthreads();
#pragma unroll 1
  for (int c = 0; c < 63; ++c) {
    float a0 = 0.f, a1 = 0.f, a2 = 0.f, a3 = 0.f;
#pragma unroll
    for (int k = 0; k < 128; k += 4) {
      float4 sv = *(const float4*)(&sh[k]);
      a0 = fmaf(sv.x, w[k + 0], a0);
      a1 = fmaf(sv.y, w[k + 1], a1);
      a2 = fmaf(sv.z, w[k + 2], a2);
      a3 = fmaf(sv.w, w[k + 3], a3);
    }
    float hn = (a0 + a1) + (a2 + a3) + Ec[((size_t)b * 64 + c) * 128 + t];
    __syncthreads();
    sh[t] = hn;
    __syncthreads();
    Hc[((size_t)b * 64 + c + 1) * 128 + t] = hn;
  }
}

// ---------------- K5d: pass 2 — S2[c*8+j] = sum_{k=1..8} Xs[(8-k)+j] @ M_k ----------------
// Xs rows 0..6 = 0, row 7 = h_c, rows 8..14 = Bu[c*8 + 0..6]  (zero-padding keeps indexing static)
__global__ __launch_bounds__(256) void pass2_kernel(
    const float* __restrict__ Mpow, const float* __restrict__ PD,
    const float* __restrict__ Hc, float* __restrict__ S2) {
  int b = blockIdx.x >> 6, c = blockIdx.x & 63;
  int tid = threadIdx.x, t = tid & 127, dh = tid >> 7;
  __shared__ __align__(16) float Xs[15][128];
  __shared__ __align__(16) float red[8][128];
  const float* Bu = PD + (size_t)b * 512 * 1152 + 1024;
  for (int idx = tid; idx < 15 * 128; idx += 256) {
    int rr = idx >> 7, cc = idx & 127;
    float v = 0.f;
    if (rr == 7) v = Hc[((size_t)b * 64 + c) * 128 + cc];
    else if (rr > 7) v = Bu[(size_t)(c * 8 + rr - 8) * 1152 + cc];
    Xs[rr][cc] = v;
  }
  __syncthreads();
  float acc[8];
#pragma unroll
  for (int j = 0; j < 8; ++j) acc[j] = 0.f;
  const float* Mb = Mpow + (size_t)b * 9 * 16384;
  int d0 = dh * 64;
#pragma unroll 1
  for (int k = 1; k <= 8; ++k) {
    const float* Mk = Mb + (size_t)k * 16384 + t;
    const int xbase = 8 - k;
#pragma unroll 4
    for (int d4 = 0; d4 < 16; ++d4) {
      int d = d0 + d4 * 4;
      float m0 = Mk[(size_t)(d + 0) * 128];
      float m1 = Mk[(size_t)(d + 1) * 128];
      float m2 = Mk[(size_t)(d + 2) * 128];
      float m3 = Mk[(size_t)(d + 3) * 128];
#pragma unroll
      for (int j = 0; j < 8; ++j) {
        float4 xv = *(const float4*)(&Xs[xbase + j][d]);
        acc[j] = fmaf(xv.x, m0, acc[j]);
        acc[j] = fmaf(xv.y, m1, acc[j]);
        acc[j] = fmaf(xv.z, m2, acc[j]);
        acc[j] = fmaf(xv.w, m3, acc[j]);
      }
    }
  }
  if (dh == 1) {
#pragma unroll
    for (int j = 0; j < 8; ++j) red[j][t] = acc[j];
  }
  __syncthreads();
  if (dh == 0) {
    float* S2b = S2 + ((size_t)b * 512 + c * 8) * 128;
#pragma unroll
    for (int j = 0; j < 8; ++j)
      S2b[(size_t)j * 128 + t] = acc[j] + red[j][t];
  }
}

// ---------------- K6: softmax over frames ----------------
__global__ void softmax_kernel(const float* __restrict__ times, float* __restrict__ imp) {
  int b = blockIdx.x, t = threadIdx.x;  // 512 threads
  __shared__ float red[512];
  float v = times[b * 512 + t];
  red[t] = v;
  __syncthreads();
  for (int s = 256; s > 0; s >>= 1) {
    if (t < s) red[t] = fmaxf(red[t], red[t + s]);
    __syncthreads();
  }
  float m = red[0];
  __syncthreads();
  float e = expf(v - m);
  red[t] = e;
  __syncthreads();
  for (int s = 256; s > 0; s >>= 1) {
    if (t < s) red[t] += red[t + s];
    __syncthreads();
  }
  imp[b * 512 + t] = e / red[0];
}

// ---------------- K7: overlap-add ----------------
__global__ void ola_kernel(const float* __restrict__ Y, float* __restrict__ sig) {
  int idx = blockIdx.x * 256 + threadIdx.x;
  int b = idx >> 18;
  int n = idx & 262143;
  int q = n >> 9, r = n & 511;
  float v = Y[((size_t)b * 512 + q) * 1024 + r];
  if (q > 0) v += Y[((size_t)b * 512 + q - 1) * 1024 + 512 + r];
  sig[idx] = v;
}

// ---------------- K8: sparse impulse convolution ----------------
__global__ __launch_bounds__(256) void conv_kernel(
    const float* __restrict__ sig, const float* __restrict__ imp,
    float* __restrict__ out) {
  int b = blockIdx.x >> 5;
  int q0 = (blockIdx.x & 31) * 16;
  int tid = threadIdx.x;
  int qi = tid >> 4, rg = tid & 15;
  int q = q0 + qi;
  __shared__ float imp_sh[512];
  __shared__ __align__(16) float sg[4][512];
  imp_sh[tid] = imp[b * 512 + tid];
  imp_sh[256 + tid] = imp[b * 512 + 256 + tid];
  const float* sigb = sig + (size_t)b * 262144;
  float acc[32];
#pragma unroll
  for (int j = 0; j < 32; ++j) acc[j] = 0.f;
  int pmax = q0 + 15;
  for (int pc = 0; pc <= pmax; pc += 4) {
    __syncthreads();
#pragma unroll
    for (int ii = 0; ii < 8; ++ii) {
      int flat = ii * 256 + tid;
      int pp = flat >> 9, col = flat & 511;
      int p = pc + pp;
      sg[pp][col] = (p < 512) ? sigb[(size_t)p * 512 + col] : 0.f;
    }
    __syncthreads();
#pragma unroll
    for (int pp = 0; pp < 4; ++pp) {
      int p = pc + pp;
      float im = (p <= q) ? imp_sh[q - p] : 0.f;
#pragma unroll
      for (int j = 0; j < 32; ++j)
        acc[j] = fmaf(im, sg[pp][j * 16 + rg], acc[j]);
    }
  }
  float* outb = out + (size_t)b * 262144 + (size_t)q * 512;
#pragma unroll
  for (int j = 0; j < 32; ++j) outb[j * 16 + rg] = acc[j];
}

// ---------------- launcher ----------------
extern "C" void kernel_launch(void* const* d_in, const int* in_sizes, int n_in,
                              void* d_out, int out_size, void* d_ws, size_t ws_size,
                              hipStream_t stream) {
  const float* control   = (const float*)d_in[0];
  const float* state_hv  = (const float*)d_in[1];
  const float* output_hv = (const float*)d_in[2];
  const float* input_hv  = (const float*)d_in[3];
  const float* direct_hv = (const float*)d_in[4];
  const float* proj_hv   = (const float*)d_in[5];
  const float* times     = (const float*)d_in[6];
  const float* A_proj   = (const float*)d_in[7];
  const float* B_proj   = (const float*)d_in[8];
  const float* A_state  = (const float*)d_in[9];
  const float* B_state  = (const float*)d_in[10];
  const float* A_input  = (const float*)d_in[11];
  const float* B_input  = (const float*)d_in[12];
  const float* A_output = (const float*)d_in[13];
  const float* B_output = (const float*)d_in[14];
  const float* A_direct = (const float*)d_in[15];
  const float* B_direct = (const float*)d_in[16];

  float* ws    = (float*)d_ws;
  float* lat   = ws + OFF_LAT;
  float* impw  = ws + OFF_IMP;
  float* Wsm   = ws + OFF_WSM;
  float* Wp    = ws + OFF_WP;
  float* Wo    = ws + OFF_WO;
  float* Wdi   = ws + OFF_WDI;
  float* ctrlT = ws + OFF_CTRLT;
  float* proj  = ws + OFF_PROJ;
  float* projD = ws + OFF_PROJD;
  float* S2    = ws + OFF_S2;
  float* Mpow  = ws + OFF_MPOW;   // aliases ctrlT (dead after proj GEMM)
  float* Ec    = ws + OFF_EC;     // aliases Wp (dead after proj GEMM)
  float* Hc    = ws + OFF_HC;
  float* Y   = proj;    // proj dead after projD GEMM
  float* sig = ctrlT;   // Mpow dead after pass2
  float* out = (float*)d_out;

  // K1 latents
  latents_kernel<<<1, 640, 0, stream>>>(proj_hv, state_hv, input_hv, output_hv, direct_hv,
                                        A_proj, A_state, A_input, A_output, A_direct, lat);

  // K2 builds
  build_w_kernel<<<512, 256, 0, stream>>>(lat + 0 * 128, B_proj, Wp, 524288, 10, 1023, 1024, 524288);
  build_w_kernel<<<16, 256, 0, stream>>>(lat + 1 * 128, B_state, Wsm, 16384, 7, 127, 128, 16384);
  build_w_kernel<<<1024, 256, 0, stream>>>(lat + 4 * 128, B_direct, Wdi, 1048576, 10, 1023, 1152, 1179648);
  build_w_kernel<<<128, 256, 0, stream>>>(lat + 2 * 128, B_input, Wdi + 1024, 131072, 7, 127, 1152, 1179648);
  build_w_kernel<<<128, 256, 0, stream>>>(lat + 3 * 128, B_output, Wo, 131072, 10, 1023, 1024, 131072);

  // K3 transpose + square
  transpose_sq_kernel<<<dim3(16, 16, 8), dim3(32, 8), 0, stream>>>(control, ctrlT);

  // K4a proj = ctrlT @ Wp   (M=512, N=1024, K=512)  -- ctrlT dead after this
  gemm_kernel<0><<<dim3(8, 8, 8), 256, 0, stream>>>(ctrlT, 512, Wp, nullptr, 0, proj, 1024, 512, 1024, 512);

  // K4b projD = proj @ [Wd|Wi]   (M=512, N=1152, K=1024) -- proj dead after this
  gemm_kernel<0><<<dim3(9, 8, 8), 256, 0, stream>>>(proj, 1024, Wdi, nullptr, 0, projD, 1152, 512, 1152, 1024);

  // K5 chunked scan: powers -> aggregates -> boundary combine -> pass2
  copym1_kernel<<<128, 256, 0, stream>>>(Wsm, Mpow);
  powers_kernel<<<8, 256, 0, stream>>>(Mpow, 1);   // M_2
  powers_kernel<<<16, 256, 0, stream>>>(Mpow, 2);  // M_3, M_4
  powers_kernel<<<32, 256, 0, stream>>>(Mpow, 4);  // M_5..M_8
  ec_kernel<<<512, 256, 0, stream>>>(Mpow, projD, Ec);
  combine_kernel<<<8, 128, 0, stream>>>(Mpow, Ec, Hc);
  pass2_kernel<<<512, 256, 0, stream>>>(Mpow, projD, Hc, S2);

  // K4c Y = (S2 @ Wo + direct) * win   (M=512, N=1024, K=128)
  gemm_kernel<1><<<dim3(8, 8, 8), 256, 0, stream>>>(S2, 128, Wo, projD, 1152, Y, 1024, 512, 1024, 128);

  // K6 softmax(times) -> imp
  softmax_kernel<<<8, 512, 0, stream>>>(times, impw);

  // K7 overlap-add -> sig (overwrites Mpow region; Mpow dead)
  ola_kernel<<<8192, 256, 0, stream>>>(Y, sig);

  // K8 sparse convolution -> out
  conv_kernel<<<256, 256, 0, stream>>>(sig, impw, out);
}

// Round 3
// 362.285 us; speedup vs baseline: 3.3851x; 1.8148x over previous
//
#include <hip/hip_runtime.h>
#include <math.h>

// Problem constants
//  B=8, CTX=512, N_FRAMES=512, IN_DIM=1024, ST_DIM=128, HOP=512, N_SAMPLES=262144
//  HD=32, HL=16
// Scan parallelization: T=8 frames/chunk, C=64 chunks.
// GEMMs (proj, projD, Y) run on bf16 MFMA 16x16x32; conv runs as triangular
// Toeplitz f32 GEMM; scan pieces stay f32.

typedef __attribute__((ext_vector_type(8))) short bfrag;   // 8 bf16 = 4 VGPRs
typedef __attribute__((ext_vector_type(4))) float f32x4;

__device__ inline unsigned short f2bf(float f) {
  unsigned int u = __float_as_uint(f);
  unsigned int r = (u + 0x7fff + ((u >> 16) & 1)) >> 16;   // RNE
  return (unsigned short)r;
}

// ---------------- workspace layout (float offsets) ----------------
static const size_t OFF_LAT   = 0;          // 640
static const size_t OFF_IMP   = 1024;       // 8*512
static const size_t OFF_WSM   = 8192;       // Ws f32: 8*128*128 = 131072
static const size_t OFF_WPT   = 139264;     // WpT bf16 [8][1024][512]  = 2,097,152 f32-eq
static const size_t OFF_WOT   = 2236416;    // WoT bf16 [8][1024][128]  = 524,288
static const size_t OFF_WDIT  = 2760704;    // WdiT bf16 [8][1152][1024] = 4,718,592
static const size_t OFF_CTRLT = 7479296;    // ctrlT bf16 [8][512][512] = 1,048,576
static const size_t OFF_PROJ  = 8527872;    // proj bf16 [8][512][1024] = 2,097,152
static const size_t OFF_PROJD = 10625024;   // projD f32 [8][512][1152] = 4,718,592
static const size_t OFF_S2    = 15343616;   // S2 bf16 [8][512][128] = 262,144
static const size_t OFF_MPOW  = 15605760;   // f32 8*9*16384 = 1,179,648
static const size_t OFF_EC    = 16785408;   // 65,536
static const size_t OFF_HC    = 16850944;   // 65,536
static const size_t OFF_Y     = 16916480;   // f32 [8][512][1024] = 4,194,304
static const size_t OFF_SIG   = 21110784;   // f32 [8][262144] = 2,097,152
static const size_t OFF_T     = 23207936;   // f32 [8][512][512] = 2,097,152
// total = 25,305,088 floats = 96.6 MiB (< previous 100.5 MiB footprint)

// ---------------- K1: latents lat[m][b][l] = hv_m[b] @ A_m ----------------
__global__ void latents_kernel(
    const float* __restrict__ hv_p, const float* __restrict__ hv_s,
    const float* __restrict__ hv_i, const float* __restrict__ hv_o,
    const float* __restrict__ hv_d,
    const float* __restrict__ A_p, const float* __restrict__ A_s,
    const float* __restrict__ A_i, const float* __restrict__ A_o,
    const float* __restrict__ A_d,
    float* __restrict__ lat) {
  int tid = threadIdx.x;
  if (tid >= 640) return;
  int m = tid >> 7, b = (tid >> 4) & 7, l = tid & 15;
  const float* hv; const float* A;
  switch (m) {
    case 0: hv = hv_p; A = A_p; break;
    case 1: hv = hv_s; A = A_s; break;
    case 2: hv = hv_i; A = A_i; break;
    case 3: hv = hv_o; A = A_o; break;
    default: hv = hv_d; A = A_d; break;
  }
  float acc = 0.f;
  for (int h = 0; h < 32; ++h) acc = fmaf(hv[b * 32 + h], A[h * 16 + l], acc);
  lat[tid] = acc;
}

// ---------------- K2a: f32 row-major W build (Ws only) ----------------
__global__ __launch_bounds__(256) void build_w_kernel(
    const float* __restrict__ lat,   // [8][16]
    const float* __restrict__ Bm,    // [16][total]
    float* __restrict__ out,
    int total, size_t bstride) {
  int e = (blockIdx.x * 256 + threadIdx.x) * 4;
  if (e >= total) return;
  float4 v[16];
#pragma unroll
  for (int l = 0; l < 16; ++l)
    v[l] = *(const float4*)(Bm + (size_t)l * total + e);
#pragma unroll 1
  for (int b = 0; b < 8; ++b) {
    float ax = 0.f, ay = 0.f, az = 0.f, aw = 0.f;
#pragma unroll
    for (int l = 0; l < 16; ++l) {
      float lv = lat[b * 16 + l];
      ax = fmaf(lv, v[l].x, ax);
      ay = fmaf(lv, v[l].y, ay);
      az = fmaf(lv, v[l].z, az);
      aw = fmaf(lv, v[l].w, aw);
    }
    *(float4*)(out + (size_t)b * bstride + e) = make_float4(ax, ay, az, aw);
  }
}

// ---------------- K2b: transposed bf16 W build ----------------
// W[r][c] = sum_l lat[b,l] * Bm[l][r*C + c]; writes WT[c][r] (bf16, row len R).
// thread: c = bx*16 + (t>>4), r0 = by*64 + (t&15)*4
__global__ __launch_bounds__(256) void build_wt_kernel(
    const float* __restrict__ lat,        // [8][16]
    const float* __restrict__ Bm,         // [16][R*C]
    unsigned short* __restrict__ out,     // [8 via bstride][C][R] bf16
    int R, int C, size_t bstride) {
  __shared__ float ls[128];
  int tid = threadIdx.x;
  if (tid < 128) ls[tid] = lat[tid];
  __syncthreads();
  int c = blockIdx.x * 16 + (tid >> 4);
  int r0 = blockIdx.y * 64 + (tid & 15) * 4;
  size_t RC = (size_t)R * C;
  float bm[16][4];
#pragma unroll
  for (int l = 0; l < 16; ++l)
#pragma unroll
    for (int i = 0; i < 4; ++i)
      bm[l][i] = Bm[(size_t)l * RC + (size_t)(r0 + i) * C + c];
#pragma unroll 1
  for (int b = 0; b < 8; ++b) {
    float a0 = 0.f, a1 = 0.f, a2 = 0.f, a3 = 0.f;
#pragma unroll
    for (int l = 0; l < 16; ++l) {
      float lv = ls[b * 16 + l];
      a0 = fmaf(lv, bm[l][0], a0);
      a1 = fmaf(lv, bm[l][1], a1);
      a2 = fmaf(lv, bm[l][2], a2);
      a3 = fmaf(lv, bm[l][3], a3);
    }
    ushort4 o;
    o.x = f2bf(a0); o.y = f2bf(a1); o.z = f2bf(a2); o.w = f2bf(a3);
    *(ushort4*)(out + (size_t)b * bstride + (size_t)c * R + r0) = o;
  }
}

// ---------------- K3: ctrlT[b,f,c] = control[b,c,f]^2  (bf16 out) ----------------
__global__ void transpose_sq_kernel(const float* __restrict__ in,
                                    unsigned short* __restrict__ out) {
  __shared__ float tile[32][33];
  int b = blockIdx.z;
  int c0 = blockIdx.x * 32, f0 = blockIdx.y * 32;
  int tx = threadIdx.x, ty = threadIdx.y;  // 32 x 8
  const float* inb = in + (size_t)b * 512 * 512;
  unsigned short* outb = out + (size_t)b * 512 * 512;
#pragma unroll
  for (int i = 0; i < 4; ++i) {
    float v = inb[(size_t)(c0 + ty + i * 8) * 512 + f0 + tx];
    tile[ty + i * 8][tx] = v * v;
  }
  __syncthreads();
#pragma unroll
  for (int i = 0; i < 4; ++i)
    outb[(size_t)(f0 + ty + i * 8) * 512 + c0 + tx] = f2bf(tile[tx][ty + i * 8]);
}

// ---------------- K4: bf16 MFMA GEMM  C[b] = A[b] @ BT[b]^T ----------------
// A: [M][K] bf16 row-major.  BT: [N][K] bf16 row-major.  BM=BN=128, BK=32.
// 4 waves, each 64x64 (4x4 frags of 16x16x32).  EPI: C=(acc+D)*win(n) f32.
// CD_BF16: C stored bf16.
template <int EPI, int CD_BF16>
__global__ __launch_bounds__(256) void mfma_gemm_kernel(
    const unsigned short* __restrict__ A,
    const unsigned short* __restrict__ BT,
    const float* __restrict__ D, int ldd,
    void* __restrict__ Cout,
    int M, int N, int K) {
  const int b = blockIdx.z;
  A  += (size_t)b * M * K;
  BT += (size_t)b * N * K;
  const int m0 = blockIdx.y * 128;
  const int n0 = blockIdx.x * 128;
  __shared__ __align__(16) unsigned short As[128][40];  // 32 + 8 pad
  __shared__ __align__(16) unsigned short Bs[128][40];
  const int tid = threadIdx.x;
  const int lane = tid & 63, wave = tid >> 6;
  const int wr = (wave >> 1) * 64, wc = (wave & 1) * 64;
  const int l15 = lane & 15, g = lane >> 4;
  f32x4 acc[4][4];
#pragma unroll
  for (int i = 0; i < 4; ++i)
#pragma unroll
    for (int j = 0; j < 4; ++j)
#pragma unroll
      for (int r = 0; r < 4; ++r) acc[i][j][r] = 0.f;

  const int srow = tid >> 2, soct = tid & 3;   // chunk tid -> (row, oct); +256 -> row+64
  const unsigned short* Ag = A + (size_t)(m0 + srow) * K + soct * 8;
  const unsigned short* Bg = BT + (size_t)(n0 + srow) * K + soct * 8;
  const size_t row64 = (size_t)64 * K;

  for (int k0 = 0; k0 < K; k0 += 32) {
    bfrag av0 = *(const bfrag*)(Ag + k0);
    bfrag av1 = *(const bfrag*)(Ag + row64 + k0);
    bfrag bv0 = *(const bfrag*)(Bg + k0);
    bfrag bv1 = *(const bfrag*)(Bg + row64 + k0);
    __syncthreads();
    *(bfrag*)(&As[srow][soct * 8]) = av0;
    *(bfrag*)(&As[64 + srow][soct * 8]) = av1;
    *(bfrag*)(&Bs[srow][soct * 8]) = bv0;
    *(bfrag*)(&Bs[64 + srow][soct * 8]) = bv1;
    __syncthreads();
    bfrag af[4], bf[4];
#pragma unroll
    for (int mi = 0; mi < 4; ++mi)
      af[mi] = *(const bfrag*)(&As[wr + mi * 16 + l15][g * 8]);
#pragma unroll
    for (int nj = 0; nj < 4; ++nj)
      bf[nj] = *(const bfrag*)(&Bs[wc + nj * 16 + l15][g * 8]);
#pragma unroll
    for (int mi = 0; mi < 4; ++mi)
#pragma unroll
      for (int nj = 0; nj < 4; ++nj)
        acc[mi][nj] = __builtin_amdgcn_mfma_f32_16x16x32_bf16(af[mi], bf[nj], acc[mi][nj], 0, 0, 0);
  }

  // epilogue: D/C frag mapping: col = l15, row = 4*g + r
  float* Cf = (float*)Cout + (size_t)b * M * N;
  unsigned short* Cb = (unsigned short*)Cout + (size_t)b * M * N;
  if (EPI) D += (size_t)b * M * ldd;
#pragma unroll
  for (int nj = 0; nj < 4; ++nj) {
    int n = n0 + wc + nj * 16 + l15;
    float win = 0.f;
    if (EPI) win = 0.5f - 0.5f * cosf(6.28318530717958647693f * (float)n / 1024.0f);
#pragma unroll
    for (int mi = 0; mi < 4; ++mi) {
      int mbase = m0 + wr + mi * 16 + 4 * g;
#pragma unroll
      for (int r = 0; r < 4; ++r) {
        int m = mbase + r;
        float v = acc[mi][nj][r];
        if (EPI) v = (v + D[(size_t)m * ldd + n]) * win;
        if (CD_BF16) Cb[(size_t)m * N + n] = f2bf(v);
        else         Cf[(size_t)m * N + n] = v;
      }
    }
  }
}

// ---------------- K4f: f32 GEMM (conv only), BM=64 BN=128 BK=16, TRI k-bound ----------------
template <int TRI>
__global__ __launch_bounds__(256) void gemm_kernel(
    const float* __restrict__ A, int lda,
    const float* __restrict__ B,
    float* __restrict__ C, int ldc,
    int M, int N, int K) {
  const int b = blockIdx.z;
  A += (size_t)b * M * lda;
  B += (size_t)b * K * N;
  C += (size_t)b * M * ldc;
  const int m0 = blockIdx.y * 64;
  const int n0 = blockIdx.x * 128;
  __shared__ __align__(16) float As[16][68];
  __shared__ __align__(16) float Bs[16][132];
  const int tid = threadIdx.x;
  const int tx = tid & 15, ty = tid >> 4;
  float acc[4][8];
#pragma unroll
  for (int i = 0; i < 4; ++i)
#pragma unroll
    for (int j = 0; j < 8; ++j) acc[i][j] = 0.f;

  const int am = tid >> 2, ak = (tid & 3) << 2;
  const int bk0 = tid >> 5, bn0 = (tid & 31) << 2;
  const int bk1 = (256 + tid) >> 5, bn1 = ((256 + tid) & 31) << 2;
  const int kend = TRI ? (m0 + 64) : K;

  for (int k0 = 0; k0 < kend; k0 += 16) {
    float4 av = *(const float4*)(A + (size_t)(m0 + am) * lda + k0 + ak);
    float4 bv0 = *(const float4*)(B + (size_t)(k0 + bk0) * N + n0 + bn0);
    float4 bv1 = *(const float4*)(B + (size_t)(k0 + bk1) * N + n0 + bn1);
    __syncthreads();
    As[ak + 0][am] = av.x;
    As[ak + 1][am] = av.y;
    As[ak + 2][am] = av.z;
    As[ak + 3][am] = av.w;
    *(float4*)(&Bs[bk0][bn0]) = bv0;
    *(float4*)(&Bs[bk1][bn1]) = bv1;
    __syncthreads();
#pragma unroll
    for (int kk = 0; kk < 16; ++kk) {
      float4 a4 = *(const float4*)(&As[kk][ty << 2]);
      float4 b4a = *(const float4*)(&Bs[kk][tx << 2]);
      float4 b4b = *(const float4*)(&Bs[kk][64 + (tx << 2)]);
      float aa[4] = {a4.x, a4.y, a4.z, a4.w};
      float bb[8] = {b4a.x, b4a.y, b4a.z, b4a.w, b4b.x, b4b.y, b4b.z, b4b.w};
#pragma unroll
      for (int i = 0; i < 4; ++i)
#pragma unroll
        for (int j = 0; j < 8; ++j) acc[i][j] = fmaf(aa[i], bb[j], acc[i][j]);
    }
  }
#pragma unroll
  for (int i = 0; i < 4; ++i) {
    int m = m0 + (ty << 2) + i;
#pragma unroll
    for (int half = 0; half < 2; ++half) {
      int n = n0 + half * 64 + (tx << 2);
      float4 o = make_float4(acc[i][half * 4 + 0], acc[i][half * 4 + 1],
                             acc[i][half * 4 + 2], acc[i][half * 4 + 3]);
      *(float4*)(C + (size_t)m * ldc + n) = o;
    }
  }
}

// ---------------- K5a0: copy Ws into Mpow slot 1 ----------------
__global__ void copym1_kernel(const float* __restrict__ Wsm, float* __restrict__ Mpow) {
  int i = blockIdx.x * 256 + threadIdx.x;
  int b = i >> 12, r = i & 4095;
  *(float4*)(Mpow + ((size_t)b * 9 + 1) * 16384 + (size_t)r * 4) =
      *(const float4*)(Wsm + (size_t)b * 16384 + (size_t)r * 4);
}

// ---------------- K5a: power step  M_{half+k} = M_k @ M_half ----------------
__global__ __launch_bounds__(256) void powers_kernel(float* __restrict__ Mpow, int half) {
  int z = blockIdx.x;
  int b = z / half, k = z - b * half + 1;
  const float* A = Mpow + ((size_t)b * 9 + k) * 16384;
  const float* Bm = Mpow + ((size_t)b * 9 + half) * 16384;
  float* C = Mpow + ((size_t)b * 9 + half + k) * 16384;
  __shared__ __align__(16) float As[16][132];
  __shared__ __align__(16) float Bs[16][132];
  int tid = threadIdx.x;
  int tx = tid & 15, ty = tid >> 4;
  float acc[8][8];
#pragma unroll
  for (int i = 0; i < 8; ++i)
#pragma unroll
    for (int j = 0; j < 8; ++j) acc[i][j] = 0.f;
  int ar = tid >> 1, ac = (tid & 1) * 8;
  int br = tid >> 4, bc = (tid & 15) * 8;
  for (int k0 = 0; k0 < 128; k0 += 16) {
    float4 a0 = *(const float4*)(A + (size_t)ar * 128 + k0 + ac);
    float4 a1 = *(const float4*)(A + (size_t)ar * 128 + k0 + ac + 4);
    float4 b0 = *(const float4*)(Bm + (size_t)(k0 + br) * 128 + bc);
    float4 b1 = *(const float4*)(Bm + (size_t)(k0 + br) * 128 + bc + 4);
    __syncthreads();
    As[ac + 0][ar] = a0.x; As[ac + 1][ar] = a0.y; As[ac + 2][ar] = a0.z; As[ac + 3][ar] = a0.w;
    As[ac + 4][ar] = a1.x; As[ac + 5][ar] = a1.y; As[ac + 6][ar] = a1.z; As[ac + 7][ar] = a1.w;
    *(float4*)(&Bs[br][bc]) = b0;
    *(float4*)(&Bs[br][bc + 4]) = b1;
    __syncthreads();
#pragma unroll
    for (int kk = 0; kk < 16; ++kk) {
      float4 av0 = *(const float4*)(&As[kk][ty * 8]);
      float4 av1 = *(const float4*)(&As[kk][ty * 8 + 4]);
      float4 bv0 = *(const float4*)(&Bs[kk][tx * 8]);
      float4 bv1 = *(const float4*)(&Bs[kk][tx * 8 + 4]);
      float aa[8] = {av0.x, av0.y, av0.z, av0.w, av1.x, av1.y, av1.z, av1.w};
      float bb[8] = {bv0.x, bv0.y, bv0.z, bv0.w, bv1.x, bv1.y, bv1.z, bv1.w};
#pragma unroll
      for (int i = 0; i < 8; ++i)
#pragma unroll
        for (int j = 0; j < 8; ++j) acc[i][j] = fmaf(aa[i], bb[j], acc[i][j]);
    }
  }
#pragma unroll
  for (int i = 0; i < 8; ++i) {
    *(float4*)(C + (size_t)(ty * 8 + i) * 128 + tx * 8) =
        make_float4(acc[i][0], acc[i][1], acc[i][2], acc[i][3]);
    *(float4*)(C + (size_t)(ty * 8 + i) * 128 + tx * 8 + 4) =
        make_float4(acc[i][4], acc[i][5], acc[i][6], acc[i][7]);
  }
}

// ---------------- K5b: chunk aggregates ----------------
__global__ __launch_bounds__(256) void ec_kernel(
    const float* __restrict__ Mpow, const float* __restrict__ PD,
    float* __restrict__ Ec) {
  int b = blockIdx.x >> 6, c = blockIdx.x & 63;
  int tid = threadIdx.x, t = tid & 127, dh = tid >> 7;
  __shared__ __align__(16) float Bus[7][128];
  __shared__ float red[128];
  const float* Bu = PD + (size_t)b * 512 * 1152 + 1024;
  for (int idx = tid; idx < 896; idx += 256)
    Bus[idx >> 7][idx & 127] = Bu[(size_t)(c * 8 + (idx >> 7)) * 1152 + (idx & 127)];
  __syncthreads();
  float acc = 0.f;
  const float* Mb = Mpow + (size_t)b * 9 * 16384;
  int d0 = dh * 64;
#pragma unroll
  for (int i = 0; i < 7; ++i) {
    const float* Mk = Mb + (size_t)(7 - i) * 16384 + t;
#pragma unroll 8
    for (int d = 0; d < 64; ++d)
      acc = fmaf(Bus[i][d0 + d], Mk[(size_t)(d0 + d) * 128], acc);
  }
  if (dh == 1) red[t] = acc;
  __syncthreads();
  if (dh == 0) {
    float tot = acc + red[t] + Bu[(size_t)(c * 8 + 7) * 1152 + t];
    Ec[((size_t)b * 64 + c) * 128 + t] = tot;
  }
}

// ---------------- K5c: serial chunk combine ----------------
__global__ __launch_bounds__(128) void combine_kernel(
    const float* __restrict__ Mpow, const float* __restrict__ Ec,
    float* __restrict__ Hc) {
  int b = blockIdx.x, t = threadIdx.x;
  float w[128];
  const float* M8 = Mpow + ((size_t)b * 9 + 8) * 16384;
#pragma unroll
  for (int k = 0; k < 128; ++k) w[k] = M8[(size_t)k * 128 + t];
  __shared__ __align__(16) float sh[128];
  sh[t] = 0.f;
  Hc[((size_t)b * 64) * 128 + t] = 0.f;
  __syncthreads();
#pragma unroll 1
  for (int c = 0; c < 63; ++c) {
    float a0 = 0.f, a1 = 0.f, a2 = 0.f, a3 = 0.f;
#pragma unroll
    for (int k = 0; k < 128; k += 4) {
      float4 sv = *(const float4*)(&sh[k]);
      a0 = fmaf(sv.x, w[k + 0], a0);
      a1 = fmaf(sv.y, w[k + 1], a1);
      a2 = fmaf(sv.z, w[k + 2], a2);
      a3 = fmaf(sv.w, w[k + 3], a3);
    }
    float hn = (a0 + a1) + (a2 + a3) + Ec[((size_t)b * 64 + c) * 128 + t];
    __syncthreads();
    sh[t] = hn;
    __syncthreads();
    Hc[((size_t)b * 64 + c + 1) * 128 + t] = hn;
  }
}

// ---------------- K5d: pass 2 (S2 out in bf16) ----------------
__global__ __launch_bounds__(256) void pass2_kernel(
    const float* __restrict__ Mpow, const float* __restrict__ PD,
    const float* __restrict__ Hc, unsigned short* __restrict__ S2) {
  int b = blockIdx.x >> 6, c = blockIdx.x & 63;
  int tid = threadIdx.x, t = tid & 127, dh = tid >> 7;
  __shared__ __align__(16) float Xs[15][128];
  __shared__ __align__(16) float red[8][128];
  const float* Bu = PD + (size_t)b * 512 * 1152 + 1024;
  for (int idx = tid; idx < 15 * 128; idx += 256) {
    int rr = idx >> 7, cc = idx & 127;
    float v = 0.f;
    if (rr == 7) v = Hc[((size_t)b * 64 + c) * 128 + cc];
    else if (rr > 7) v = Bu[(size_t)(c * 8 + rr - 8) * 1152 + cc];
    Xs[rr][cc] = v;
  }
  __syncthreads();
  float acc[8];
#pragma unroll
  for (int j = 0; j < 8; ++j) acc[j] = 0.f;
  const float* Mb = Mpow + (size_t)b * 9 * 16384;
  int d0 = dh * 64;
#pragma unroll 1
  for (int k = 1; k <= 8; ++k) {
    const float* Mk = Mb + (size_t)k * 16384 + t;
    const int xbase = 8 - k;
#pragma unroll 4
    for (int d4 = 0; d4 < 16; ++d4) {
      int d = d0 + d4 * 4;
      float m0 = Mk[(size_t)(d + 0) * 128];
      float m1 = Mk[(size_t)(d + 1) * 128];
      float m2 = Mk[(size_t)(d + 2) * 128];
      float m3 = Mk[(size_t)(d + 3) * 128];
#pragma unroll
      for (int j = 0; j < 8; ++j) {
        float4 xv = *(const float4*)(&Xs[xbase + j][d]);
        acc[j] = fmaf(xv.x, m0, acc[j]);
        acc[j] = fmaf(xv.y, m1, acc[j]);
        acc[j] = fmaf(xv.z, m2, acc[j]);
        acc[j] = fmaf(xv.w, m3, acc[j]);
      }
    }
  }
  if (dh == 1) {
#pragma unroll
    for (int j = 0; j < 8; ++j) red[j][t] = acc[j];
  }
  __syncthreads();
  if (dh == 0) {
    unsigned short* S2b = S2 + ((size_t)b * 512 + c * 8) * 128;
#pragma unroll
    for (int j = 0; j < 8; ++j)
      S2b[(size_t)j * 128 + t] = f2bf(acc[j] + red[j][t]);
  }
}

// ---------------- K6: softmax over frames ----------------
__global__ void softmax_kernel(const float* __restrict__ times, float* __restrict__ imp) {
  int b = blockIdx.x, t = threadIdx.x;  // 512 threads
  __shared__ float red[512];
  float v = times[b * 512 + t];
  red[t] = v;
  __syncthreads();
  for (int s = 256; s > 0; s >>= 1) {
    if (t < s) red[t] = fmaxf(red[t], red[t + s]);
    __syncthreads();
  }
  float m = red[0];
  __syncthreads();
  float e = expf(v - m);
  red[t] = e;
  __syncthreads();
  for (int s = 256; s > 0; s >>= 1) {
    if (t < s) red[t] += red[t + s];
    __syncthreads();
  }
  imp[b * 512 + t] = e / red[0];
}

// ---------------- K6b: Toeplitz build  T[b][q][p] = p<=q ? imp[b][q-p] : 0 ----------------
__global__ void toeplitz_kernel(const float* __restrict__ imp, float* __restrict__ T) {
  int idx = blockIdx.x * 256 + threadIdx.x;   // 8 * 512 * 128 threads (float4 each)
  int b = idx >> 16;
  int rem = idx & 65535;
  int q = rem >> 7, p4 = (rem & 127) * 4;
  const float* impb = imp + b * 512;
  float4 o;
  o.x = (p4 + 0 <= q) ? impb[q - p4 - 0] : 0.f;
  o.y = (p4 + 1 <= q) ? impb[q - p4 - 1] : 0.f;
  o.z = (p4 + 2 <= q) ? impb[q - p4 - 2] : 0.f;
  o.w = (p4 + 3 <= q) ? impb[q - p4 - 3] : 0.f;
  *(float4*)(T + ((size_t)b * 512 + q) * 512 + p4) = o;
}

// ---------------- K7: overlap-add ----------------
__global__ void ola_kernel(const float* __restrict__ Y, float* __restrict__ sig) {
  int idx = blockIdx.x * 256 + threadIdx.x;
  int b = idx >> 18;
  int n = idx & 262143;
  int q = n >> 9, r = n & 511;
  float v = Y[((size_t)b * 512 + q) * 1024 + r];
  if (q > 0) v += Y[((size_t)b * 512 + q - 1) * 1024 + 512 + r];
  sig[idx] = v;
}

// ---------------- launcher ----------------
extern "C" void kernel_launch(void* const* d_in, const int* in_sizes, int n_in,
                              void* d_out, int out_size, void* d_ws, size_t ws_size,
                              hipStream_t stream) {
  const float* control   = (const float*)d_in[0];
  const float* state_hv  = (const float*)d_in[1];
  const float* output_hv = (const float*)d_in[2];
  const float* input_hv  = (const float*)d_in[3];
  const float* direct_hv = (const float*)d_in[4];
  const float* proj_hv   = (const float*)d_in[5];
  const float* times     = (const float*)d_in[6];
  const float* A_proj   = (const float*)d_in[7];
  const float* B_proj   = (const float*)d_in[8];
  const float* A_state  = (const float*)d_in[9];
  const float* B_state  = (const float*)d_in[10];
  const float* A_input  = (const float*)d_in[11];
  const float* B_input  = (const float*)d_in[12];
  const float* A_output = (const float*)d_in[13];
  const float* B_output = (const float*)d_in[14];
  const float* A_direct = (const float*)d_in[15];
  const float* B_direct = (const float*)d_in[16];

  float* ws = (float*)d_ws;
  float* lat  = ws + OFF_LAT;
  float* impw = ws + OFF_IMP;
  float* Wsm  = ws + OFF_WSM;
  unsigned short* WpT   = (unsigned short*)(ws + OFF_WPT);
  unsigned short* WoT   = (unsigned short*)(ws + OFF_WOT);
  unsigned short* WdiT  = (unsigned short*)(ws + OFF_WDIT);
  unsigned short* ctrlT = (unsigned short*)(ws + OFF_CTRLT);
  unsigned short* proj  = (unsigned short*)(ws + OFF_PROJ);
  float* projD = ws + OFF_PROJD;
  unsigned short* S2 = (unsigned short*)(ws + OFF_S2);
  float* Mpow = ws + OFF_MPOW;
  float* Ec   = ws + OFF_EC;
  float* Hc   = ws + OFF_HC;
  float* Y    = ws + OFF_Y;
  float* sig  = ws + OFF_SIG;
  float* Tm   = ws + OFF_T;
  float* out  = (float*)d_out;

  // K1 latents (m: 0=proj,1=state,2=input,3=output,4=direct)
  latents_kernel<<<1, 640, 0, stream>>>(proj_hv, state_hv, input_hv, output_hv, direct_hv,
                                        A_proj, A_state, A_input, A_output, A_direct, lat);

  // Ws (f32 row-major, scan path)
  build_w_kernel<<<16, 256, 0, stream>>>(lat + 1 * 128, B_state, Wsm, 16384, 16384);

  // transposed bf16 weights: (lat_m, Bm, out, R=k-dim, C=n-dim, bstride)
  build_wt_kernel<<<dim3(64, 8), 256, 0, stream>>>(lat + 0 * 128, B_proj, WpT, 512, 1024, 524288);
  build_wt_kernel<<<dim3(64, 16), 256, 0, stream>>>(lat + 4 * 128, B_direct, WdiT, 1024, 1024, 1179648);
  build_wt_kernel<<<dim3(8, 16), 256, 0, stream>>>(lat + 2 * 128, B_input, WdiT + 1024 * 1024, 1024, 128, 1179648);
  build_wt_kernel<<<dim3(64, 2), 256, 0, stream>>>(lat + 3 * 128, B_output, WoT, 128, 1024, 131072);

  // ctrl^2 transpose -> bf16
  transpose_sq_kernel<<<dim3(16, 16, 8), dim3(32, 8), 0, stream>>>(control, ctrlT);

  // proj = ctrlT @ WpT^T  (M=512,N=1024,K=512) -> bf16
  mfma_gemm_kernel<0, 1><<<dim3(8, 4, 8), 256, 0, stream>>>(
      ctrlT, WpT, nullptr, 0, proj, 512, 1024, 512);

  // projD = proj @ WdiT^T  (M=512,N=1152,K=1024) -> f32
  mfma_gemm_kernel<0, 0><<<dim3(9, 4, 8), 256, 0, stream>>>(
      proj, WdiT, nullptr, 0, projD, 512, 1152, 1024);

  // chunked scan
  copym1_kernel<<<128, 256, 0, stream>>>(Wsm, Mpow);
  powers_kernel<<<8, 256, 0, stream>>>(Mpow, 1);
  powers_kernel<<<16, 256, 0, stream>>>(Mpow, 2);
  powers_kernel<<<32, 256, 0, stream>>>(Mpow, 4);
  ec_kernel<<<512, 256, 0, stream>>>(Mpow, projD, Ec);
  combine_kernel<<<8, 128, 0, stream>>>(Mpow, Ec, Hc);
  pass2_kernel<<<512, 256, 0, stream>>>(Mpow, projD, Hc, S2);

  // Y = (S2 @ WoT^T + direct) * win  (M=512,N=1024,K=128) -> f32
  mfma_gemm_kernel<1, 0><<<dim3(8, 4, 8), 256, 0, stream>>>(
      S2, WoT, projD, 1152, Y, 512, 1024, 128);

  // softmax -> imp ; Toeplitz -> T
  softmax_kernel<<<8, 512, 0, stream>>>(times, impw);
  toeplitz_kernel<<<2048, 256, 0, stream>>>(impw, Tm);

  // overlap-add -> sig
  ola_kernel<<<8192, 256, 0, stream>>>(Y, sig);

  // out = T @ sig  (triangular f32 GEMM, M=512,N=512,K=512)
  gemm_kernel<1><<<dim3(4, 8, 8), 256, 0, stream>>>(Tm, 512, sig, out, 512, 512, 512, 512);
}

// Round 4
// 291.260 us; speedup vs baseline: 4.2106x; 1.2439x over previous
//
#include <hip/hip_runtime.h>
#include <math.h>

// Problem constants
//  B=8, CTX=512, N_FRAMES=512, IN_DIM=1024, ST_DIM=128, HOP=512, N_SAMPLES=262144
//  HD=32, HL=16
// Scan parallelization: T=8 frames/chunk, C=64 chunks.
// GEMMs (proj, projD, Y) and conv (triangular Toeplitz) run on bf16 MFMA
// 16x16x32; scan pieces stay f32.

typedef __attribute__((ext_vector_type(8))) short bfrag;   // 8 bf16 = 4 VGPRs
typedef __attribute__((ext_vector_type(4))) float f32x4;

__device__ inline unsigned short f2bf(float f) {
  unsigned int u = __float_as_uint(f);
  unsigned int r = (u + 0x7fff + ((u >> 16) & 1)) >> 16;   // RNE
  return (unsigned short)r;
}

// ---------------- workspace layout (float offsets) ----------------
static const size_t OFF_LAT   = 0;          // 640
static const size_t OFF_IMP   = 1024;       // 8*512
static const size_t OFF_WSM   = 8192;       // Ws f32: 8*128*128 = 131072
static const size_t OFF_WPT   = 139264;     // WpT bf16 [8][1024][512]  = 2,097,152 f32-eq
static const size_t OFF_WOT   = 2236416;    // WoT bf16 [8][1024][128]  = 524,288
static const size_t OFF_WDIT  = 2760704;    // WdiT bf16 [8][1152][1024] = 4,718,592
static const size_t OFF_CTRLT = 7479296;    // ctrlT bf16 [8][512][512] = 1,048,576
static const size_t OFF_PROJ  = 8527872;    // proj bf16 [8][512][1024] = 2,097,152
static const size_t OFF_PROJD = 10625024;   // projD f32 [8][512][1152] = 4,718,592
static const size_t OFF_S2    = 15343616;   // S2 bf16 [8][512][128] = 262,144
static const size_t OFF_MPOW  = 15605760;   // f32 8*9*16384 = 1,179,648
static const size_t OFF_EC    = 16785408;   // 65,536
static const size_t OFF_HC    = 16850944;   // 65,536
static const size_t OFF_Y     = 16916480;   // f32 [8][512][1024] = 4,194,304
static const size_t OFF_SIG   = 21110784;   // sigT bf16 [8][512][512] = 1,048,576 f32-eq
static const size_t OFF_T     = 23207936;   // Tb bf16 [8][512][512] = 1,048,576 f32-eq
// total < 24.3M floats = ~93 MiB

// ---------------- K1: latents lat[m][b][l] = hv_m[b] @ A_m ----------------
__global__ void latents_kernel(
    const float* __restrict__ hv_p, const float* __restrict__ hv_s,
    const float* __restrict__ hv_i, const float* __restrict__ hv_o,
    const float* __restrict__ hv_d,
    const float* __restrict__ A_p, const float* __restrict__ A_s,
    const float* __restrict__ A_i, const float* __restrict__ A_o,
    const float* __restrict__ A_d,
    float* __restrict__ lat) {
  int tid = threadIdx.x;
  if (tid >= 640) return;
  int m = tid >> 7, b = (tid >> 4) & 7, l = tid & 15;
  const float* hv; const float* A;
  switch (m) {
    case 0: hv = hv_p; A = A_p; break;
    case 1: hv = hv_s; A = A_s; break;
    case 2: hv = hv_i; A = A_i; break;
    case 3: hv = hv_o; A = A_o; break;
    default: hv = hv_d; A = A_d; break;
  }
  float acc = 0.f;
  for (int h = 0; h < 32; ++h) acc = fmaf(hv[b * 32 + h], A[h * 16 + l], acc);
  lat[tid] = acc;
}

// ---------------- K2a: f32 row-major W build (Ws only) ----------------
__global__ __launch_bounds__(256) void build_w_kernel(
    const float* __restrict__ lat,   // [8][16]
    const float* __restrict__ Bm,    // [16][total]
    float* __restrict__ out,
    int total, size_t bstride) {
  int e = (blockIdx.x * 256 + threadIdx.x) * 4;
  if (e >= total) return;
  float4 v[16];
#pragma unroll
  for (int l = 0; l < 16; ++l)
    v[l] = *(const float4*)(Bm + (size_t)l * total + e);
#pragma unroll 1
  for (int b = 0; b < 8; ++b) {
    float ax = 0.f, ay = 0.f, az = 0.f, aw = 0.f;
#pragma unroll
    for (int l = 0; l < 16; ++l) {
      float lv = lat[b * 16 + l];
      ax = fmaf(lv, v[l].x, ax);
      ay = fmaf(lv, v[l].y, ay);
      az = fmaf(lv, v[l].z, az);
      aw = fmaf(lv, v[l].w, aw);
    }
    *(float4*)(out + (size_t)b * bstride + e) = make_float4(ax, ay, az, aw);
  }
}

// ---------------- K2b: transposed bf16 W build, coalesced reads + LDS transpose ----------------
// W[r][c] = sum_l lat[b,l]*Bm[l][r*C+c]; out WT[c][r] bf16 (row len R).
// Tile 32c x 32r. Reads: lane-fast index = c (coalesced 4B). Writes: 64B lines along r.
__global__ __launch_bounds__(256) void build_wt_kernel(
    const float* __restrict__ lat,        // [8][16]
    const float* __restrict__ Bm,         // [16][R*C]
    unsigned short* __restrict__ out,     // [8 via bstride][C][R] bf16
    int R, int C, size_t bstride) {
  __shared__ float ls[128];
  __shared__ unsigned short tile[32][36];   // [c][r], pad 36 (8B-align, conflict-free)
  int tid = threadIdx.x;
  if (tid < 128) ls[tid] = lat[tid];
  int cc = tid & 31, rg = tid >> 5;          // compute role: c fast, 4 r's per thread
  int c = blockIdx.x * 32 + cc;
  int r0 = blockIdx.y * 32 + rg * 4;
  size_t RC = (size_t)R * C;
  float bm[16][4];
#pragma unroll
  for (int l = 0; l < 16; ++l) {
    const float* p = Bm + (size_t)l * RC + (size_t)r0 * C + c;
#pragma unroll
    for (int j = 0; j < 4; ++j) bm[l][j] = p[(size_t)j * C];
  }
  int wc = tid >> 3, wrq = tid & 7;          // write role: 8 lanes cover one c-row (64B)
  __syncthreads();
#pragma unroll 1
  for (int b = 0; b < 8; ++b) {
    float a0 = 0.f, a1 = 0.f, a2 = 0.f, a3 = 0.f;
#pragma unroll
    for (int l = 0; l < 16; ++l) {
      float lv = ls[b * 16 + l];
      a0 = fmaf(lv, bm[l][0], a0);
      a1 = fmaf(lv, bm[l][1], a1);
      a2 = fmaf(lv, bm[l][2], a2);
      a3 = fmaf(lv, bm[l][3], a3);
    }
    __syncthreads();   // previous iteration's tile reads complete
    ushort2 p0, p1;
    p0.x = f2bf(a0); p0.y = f2bf(a1);
    p1.x = f2bf(a2); p1.y = f2bf(a3);
    *(ushort2*)&tile[cc][rg * 4] = p0;
    *(ushort2*)&tile[cc][rg * 4 + 2] = p1;
    __syncthreads();
    ushort4 v = *(const ushort4*)&tile[wc][wrq * 4];
    *(ushort4*)(out + (size_t)b * bstride +
                (size_t)(blockIdx.x * 32 + wc) * R + blockIdx.y * 32 + wrq * 4) = v;
  }
}

// ---------------- K3: ctrlT[b,f,c] = control[b,c,f]^2  (bf16 out) ----------------
__global__ void transpose_sq_kernel(const float* __restrict__ in,
                                    unsigned short* __restrict__ out) {
  __shared__ float tile[32][33];
  int b = blockIdx.z;
  int c0 = blockIdx.x * 32, f0 = blockIdx.y * 32;
  int tx = threadIdx.x, ty = threadIdx.y;  // 32 x 8
  const float* inb = in + (size_t)b * 512 * 512;
  unsigned short* outb = out + (size_t)b * 512 * 512;
#pragma unroll
  for (int i = 0; i < 4; ++i) {
    float v = inb[(size_t)(c0 + ty + i * 8) * 512 + f0 + tx];
    tile[ty + i * 8][tx] = v * v;
  }
  __syncthreads();
#pragma unroll
  for (int i = 0; i < 4; ++i)
    outb[(size_t)(f0 + ty + i * 8) * 512 + c0 + tx] = f2bf(tile[tx][ty + i * 8]);
}

// ---------------- K4: bf16 MFMA GEMM  C[b] = A[b] @ BT[b]^T ----------------
// A: [M][K] bf16 row-major.  BT: [N][K] bf16 row-major.  BM=BN=128, BK=32.
// 4 waves, each 64x64 (4x4 frags of 16x16x32).  EPI: C=(acc+D)*win(n) f32.
// CD_BF16: C stored bf16.  TRI: kend = m0+128 (lower-triangular A).
template <int EPI, int CD_BF16, int TRI>
__global__ __launch_bounds__(256) void mfma_gemm_kernel(
    const unsigned short* __restrict__ A,
    const unsigned short* __restrict__ BT,
    const float* __restrict__ D, int ldd,
    void* __restrict__ Cout,
    int M, int N, int K) {
  const int b = blockIdx.z;
  A  += (size_t)b * M * K;
  BT += (size_t)b * N * K;
  const int m0 = blockIdx.y * 128;
  const int n0 = blockIdx.x * 128;
  __shared__ __align__(16) unsigned short As[128][40];  // 32 + 8 pad
  __shared__ __align__(16) unsigned short Bs[128][40];
  const int tid = threadIdx.x;
  const int lane = tid & 63, wave = tid >> 6;
  const int wr = (wave >> 1) * 64, wc = (wave & 1) * 64;
  const int l15 = lane & 15, g = lane >> 4;
  f32x4 acc[4][4];
#pragma unroll
  for (int i = 0; i < 4; ++i)
#pragma unroll
    for (int j = 0; j < 4; ++j)
#pragma unroll
      for (int r = 0; r < 4; ++r) acc[i][j][r] = 0.f;

  const int srow = tid >> 2, soct = tid & 3;
  const unsigned short* Ag = A + (size_t)(m0 + srow) * K + soct * 8;
  const unsigned short* Bg = BT + (size_t)(n0 + srow) * K + soct * 8;
  const size_t row64 = (size_t)64 * K;
  const int kend = TRI ? (m0 + 128) : K;

  for (int k0 = 0; k0 < kend; k0 += 32) {
    bfrag av0 = *(const bfrag*)(Ag + k0);
    bfrag av1 = *(const bfrag*)(Ag + row64 + k0);
    bfrag bv0 = *(const bfrag*)(Bg + k0);
    bfrag bv1 = *(const bfrag*)(Bg + row64 + k0);
    __syncthreads();
    *(bfrag*)(&As[srow][soct * 8]) = av0;
    *(bfrag*)(&As[64 + srow][soct * 8]) = av1;
    *(bfrag*)(&Bs[srow][soct * 8]) = bv0;
    *(bfrag*)(&Bs[64 + srow][soct * 8]) = bv1;
    __syncthreads();
    bfrag af[4], bf[4];
#pragma unroll
    for (int mi = 0; mi < 4; ++mi)
      af[mi] = *(const bfrag*)(&As[wr + mi * 16 + l15][g * 8]);
#pragma unroll
    for (int nj = 0; nj < 4; ++nj)
      bf[nj] = *(const bfrag*)(&Bs[wc + nj * 16 + l15][g * 8]);
#pragma unroll
    for (int mi = 0; mi < 4; ++mi)
#pragma unroll
      for (int nj = 0; nj < 4; ++nj)
        acc[mi][nj] = __builtin_amdgcn_mfma_f32_16x16x32_bf16(af[mi], bf[nj], acc[mi][nj], 0, 0, 0);
  }

  // epilogue: C/D frag mapping: col = l15, row = 4*g + r
  float* Cf = (float*)Cout + (size_t)b * M * N;
  unsigned short* Cb = (unsigned short*)Cout + (size_t)b * M * N;
  if (EPI) D += (size_t)b * M * ldd;
#pragma unroll
  for (int nj = 0; nj < 4; ++nj) {
    int n = n0 + wc + nj * 16 + l15;
    float win = 0.f;
    if (EPI) win = 0.5f - 0.5f * cosf(6.28318530717958647693f * (float)n / 1024.0f);
#pragma unroll
    for (int mi = 0; mi < 4; ++mi) {
      int mbase = m0 + wr + mi * 16 + 4 * g;
#pragma unroll
      for (int r = 0; r < 4; ++r) {
        int m = mbase + r;
        float v = acc[mi][nj][r];
        if (EPI) v = (v + D[(size_t)m * ldd + n]) * win;
        if (CD_BF16) Cb[(size_t)m * N + n] = f2bf(v);
        else         Cf[(size_t)m * N + n] = v;
      }
    }
  }
}

// ---------------- K5a0: copy Ws into Mpow slot 1 ----------------
__global__ void copym1_kernel(const float* __restrict__ Wsm, float* __restrict__ Mpow) {
  int i = blockIdx.x * 256 + threadIdx.x;
  int b = i >> 12, r = i & 4095;
  *(float4*)(Mpow + ((size_t)b * 9 + 1) * 16384 + (size_t)r * 4) =
      *(const float4*)(Wsm + (size_t)b * 16384 + (size_t)r * 4);
}

// ---------------- K5a: power step  M_{half+k} = M_k @ M_half ----------------
__global__ __launch_bounds__(256) void powers_kernel(float* __restrict__ Mpow, int half) {
  int z = blockIdx.x;
  int b = z / half, k = z - b * half + 1;
  const float* A = Mpow + ((size_t)b * 9 + k) * 16384;
  const float* Bm = Mpow + ((size_t)b * 9 + half) * 16384;
  float* C = Mpow + ((size_t)b * 9 + half + k) * 16384;
  __shared__ __align__(16) float As[16][132];
  __shared__ __align__(16) float Bs[16][132];
  int tid = threadIdx.x;
  int tx = tid & 15, ty = tid >> 4;
  float acc[8][8];
#pragma unroll
  for (int i = 0; i < 8; ++i)
#pragma unroll
    for (int j = 0; j < 8; ++j) acc[i][j] = 0.f;
  int ar = tid >> 1, ac = (tid & 1) * 8;
  int br = tid >> 4, bc = (tid & 15) * 8;
  for (int k0 = 0; k0 < 128; k0 += 16) {
    float4 a0 = *(const float4*)(A + (size_t)ar * 128 + k0 + ac);
    float4 a1 = *(const float4*)(A + (size_t)ar * 128 + k0 + ac + 4);
    float4 b0 = *(const float4*)(Bm + (size_t)(k0 + br) * 128 + bc);
    float4 b1 = *(const float4*)(Bm + (size_t)(k0 + br) * 128 + bc + 4);
    __syncthreads();
    As[ac + 0][ar] = a0.x; As[ac + 1][ar] = a0.y; As[ac + 2][ar] = a0.z; As[ac + 3][ar] = a0.w;
    As[ac + 4][ar] = a1.x; As[ac + 5][ar] = a1.y; As[ac + 6][ar] = a1.z; As[ac + 7][ar] = a1.w;
    *(float4*)(&Bs[br][bc]) = b0;
    *(float4*)(&Bs[br][bc + 4]) = b1;
    __syncthreads();
#pragma unroll
    for (int kk = 0; kk < 16; ++kk) {
      float4 av0 = *(const float4*)(&As[kk][ty * 8]);
      float4 av1 = *(const float4*)(&As[kk][ty * 8 + 4]);
      float4 bv0 = *(const float4*)(&Bs[kk][tx * 8]);
      float4 bv1 = *(const float4*)(&Bs[kk][tx * 8 + 4]);
      float aa[8] = {av0.x, av0.y, av0.z, av0.w, av1.x, av1.y, av1.z, av1.w};
      float bb[8] = {bv0.x, bv0.y, bv0.z, bv0.w, bv1.x, bv1.y, bv1.z, bv1.w};
#pragma unroll
      for (int i = 0; i < 8; ++i)
#pragma unroll
        for (int j = 0; j < 8; ++j) acc[i][j] = fmaf(aa[i], bb[j], acc[i][j]);
    }
  }
#pragma unroll
  for (int i = 0; i < 8; ++i) {
    *(float4*)(C + (size_t)(ty * 8 + i) * 128 + tx * 8) =
        make_float4(acc[i][0], acc[i][1], acc[i][2], acc[i][3]);
    *(float4*)(C + (size_t)(ty * 8 + i) * 128 + tx * 8 + 4) =
        make_float4(acc[i][4], acc[i][5], acc[i][6], acc[i][7]);
  }
}

// ---------------- K5b: chunk aggregates ----------------
__global__ __launch_bounds__(256) void ec_kernel(
    const float* __restrict__ Mpow, const float* __restrict__ PD,
    float* __restrict__ Ec) {
  int b = blockIdx.x >> 6, c = blockIdx.x & 63;
  int tid = threadIdx.x, t = tid & 127, dh = tid >> 7;
  __shared__ __align__(16) float Bus[7][128];
  __shared__ float red[128];
  const float* Bu = PD + (size_t)b * 512 * 1152 + 1024;
  for (int idx = tid; idx < 896; idx += 256)
    Bus[idx >> 7][idx & 127] = Bu[(size_t)(c * 8 + (idx >> 7)) * 1152 + (idx & 127)];
  __syncthreads();
  float acc = 0.f;
  const float* Mb = Mpow + (size_t)b * 9 * 16384;
  int d0 = dh * 64;
#pragma unroll
  for (int i = 0; i < 7; ++i) {
    const float* Mk = Mb + (size_t)(7 - i) * 16384 + t;
#pragma unroll 8
    for (int d = 0; d < 64; ++d)
      acc = fmaf(Bus[i][d0 + d], Mk[(size_t)(d0 + d) * 128], acc);
  }
  if (dh == 1) red[t] = acc;
  __syncthreads();
  if (dh == 0) {
    float tot = acc + red[t] + Bu[(size_t)(c * 8 + 7) * 1152 + t];
    Ec[((size_t)b * 64 + c) * 128 + t] = tot;
  }
}

// ---------------- K5c: serial chunk combine ----------------
__global__ __launch_bounds__(128) void combine_kernel(
    const float* __restrict__ Mpow, const float* __restrict__ Ec,
    float* __restrict__ Hc) {
  int b = blockIdx.x, t = threadIdx.x;
  float w[128];
  const float* M8 = Mpow + ((size_t)b * 9 + 8) * 16384;
#pragma unroll
  for (int k = 0; k < 128; ++k) w[k] = M8[(size_t)k * 128 + t];
  __shared__ __align__(16) float sh[128];
  sh[t] = 0.f;
  Hc[((size_t)b * 64) * 128 + t] = 0.f;
  __syncthreads();
#pragma unroll 1
  for (int c = 0; c < 63; ++c) {
    float a0 = 0.f, a1 = 0.f, a2 = 0.f, a3 = 0.f;
#pragma unroll
    for (int k = 0; k < 128; k += 4) {
      float4 sv = *(const float4*)(&sh[k]);
      a0 = fmaf(sv.x, w[k + 0], a0);
      a1 = fmaf(sv.y, w[k + 1], a1);
      a2 = fmaf(sv.z, w[k + 2], a2);
      a3 = fmaf(sv.w, w[k + 3], a3);
    }
    float hn = (a0 + a1) + (a2 + a3) + Ec[((size_t)b * 64 + c) * 128 + t];
    __syncthreads();
    sh[t] = hn;
    __syncthreads();
    Hc[((size_t)b * 64 + c + 1) * 128 + t] = hn;
  }
}

// ---------------- K5d: pass 2 (S2 out in bf16) ----------------
__global__ __launch_bounds__(256) void pass2_kernel(
    const float* __restrict__ Mpow, const float* __restrict__ PD,
    const float* __restrict__ Hc, unsigned short* __restrict__ S2) {
  int b = blockIdx.x >> 6, c = blockIdx.x & 63;
  int tid = threadIdx.x, t = tid & 127, dh = tid >> 7;
  __shared__ __align__(16) float Xs[15][128];
  __shared__ __align__(16) float red[8][128];
  const float* Bu = PD + (size_t)b * 512 * 1152 + 1024;
  for (int idx = tid; idx < 15 * 128; idx += 256) {
    int rr = idx >> 7, cc = idx & 127;
    float v = 0.f;
    if (rr == 7) v = Hc[((size_t)b * 64 + c) * 128 + cc];
    else if (rr > 7) v = Bu[(size_t)(c * 8 + rr - 8) * 1152 + cc];
    Xs[rr][cc] = v;
  }
  __syncthreads();
  float acc[8];
#pragma unroll
  for (int j = 0; j < 8; ++j) acc[j] = 0.f;
  const float* Mb = Mpow + (size_t)b * 9 * 16384;
  int d0 = dh * 64;
#pragma unroll 1
  for (int k = 1; k <= 8; ++k) {
    const float* Mk = Mb + (size_t)k * 16384 + t;
    const int xbase = 8 - k;
#pragma unroll 4
    for (int d4 = 0; d4 < 16; ++d4) {
      int d = d0 + d4 * 4;
      float m0 = Mk[(size_t)(d + 0) * 128];
      float m1 = Mk[(size_t)(d + 1) * 128];
      float m2 = Mk[(size_t)(d + 2) * 128];
      float m3 = Mk[(size_t)(d + 3) * 128];
#pragma unroll
      for (int j = 0; j < 8; ++j) {
        float4 xv = *(const float4*)(&Xs[xbase + j][d]);
        acc[j] = fmaf(xv.x, m0, acc[j]);
        acc[j] = fmaf(xv.y, m1, acc[j]);
        acc[j] = fmaf(xv.z, m2, acc[j]);
        acc[j] = fmaf(xv.w, m3, acc[j]);
      }
    }
  }
  if (dh == 1) {
#pragma unroll
    for (int j = 0; j < 8; ++j) red[j][t] = acc[j];
  }
  __syncthreads();
  if (dh == 0) {
    unsigned short* S2b = S2 + ((size_t)b * 512 + c * 8) * 128;
#pragma unroll
    for (int j = 0; j < 8; ++j)
      S2b[(size_t)j * 128 + t] = f2bf(acc[j] + red[j][t]);
  }
}

// ---------------- K6: softmax over frames ----------------
__global__ void softmax_kernel(const float* __restrict__ times, float* __restrict__ imp) {
  int b = blockIdx.x, t = threadIdx.x;  // 512 threads
  __shared__ float red[512];
  float v = times[b * 512 + t];
  red[t] = v;
  __syncthreads();
  for (int s = 256; s > 0; s >>= 1) {
    if (t < s) red[t] = fmaxf(red[t], red[t + s]);
    __syncthreads();
  }
  float m = red[0];
  __syncthreads();
  float e = expf(v - m);
  red[t] = e;
  __syncthreads();
  for (int s = 256; s > 0; s >>= 1) {
    if (t < s) red[t] += red[t + s];
    __syncthreads();
  }
  imp[b * 512 + t] = e / red[0];
}

// ---------------- K6b: Toeplitz build  Tb[b][q][p] = p<=q ? imp[b][q-p] : 0  (bf16) ----------------
__global__ void toeplitz_kernel(const float* __restrict__ imp, unsigned short* __restrict__ T) {
  int idx = blockIdx.x * 256 + threadIdx.x;   // 8 * 512 * 128 threads (ushort4 each)
  int b = idx >> 16;
  int rem = idx & 65535;
  int q = rem >> 7, p4 = (rem & 127) * 4;
  const float* impb = imp + b * 512;
  ushort4 o;
  o.x = (p4 + 0 <= q) ? f2bf(impb[q - p4 - 0]) : (unsigned short)0;
  o.y = (p4 + 1 <= q) ? f2bf(impb[q - p4 - 1]) : (unsigned short)0;
  o.z = (p4 + 2 <= q) ? f2bf(impb[q - p4 - 2]) : (unsigned short)0;
  o.w = (p4 + 3 <= q) ? f2bf(impb[q - p4 - 3]) : (unsigned short)0;
  *(ushort4*)(T + ((size_t)b * 512 + q) * 512 + p4) = o;
}

// ---------------- K7: overlap-add + transpose -> sigT[b][r][p] bf16 ----------------
// sig[b][512p + r] = Y[b][p][r] + (p>0 ? Y[b][p-1][512+r] : 0); store transposed.
__global__ __launch_bounds__(256) void ola_t_kernel(const float* __restrict__ Y,
                                                    unsigned short* __restrict__ sigT) {
  __shared__ unsigned short tile[64][72];   // [q][r], row pad 72 (16B-aligned rows)
  int b = blockIdx.z;
  int q0 = blockIdx.x * 64, r0 = blockIdx.y * 64;
  int tid = threadIdx.x;
  int rr = tid & 63, qg = tid >> 6;          // read role: r fast (coalesced f32)
  const float* Yb = Y + (size_t)b * 512 * 1024;
#pragma unroll
  for (int i = 0; i < 16; ++i) {
    int q = q0 + qg * 16 + i;
    float v = Yb[(size_t)q * 1024 + r0 + rr];
    if (q > 0) v += Yb[(size_t)(q - 1) * 1024 + 512 + r0 + rr];
    tile[qg * 16 + i][rr] = f2bf(v);
  }
  __syncthreads();
  int rw = tid >> 2, qo = tid & 3;           // write role: q fast (coalesced bf16)
  unsigned short* outb = sigT + ((size_t)b * 512 + r0 + rw) * 512 + q0;
  *(bfrag*)(outb + qo * 16) = *(const bfrag*)&tile[qo * 16][0] ; // placeholder avoided
}

// NOTE: the line above is replaced by correct indexing below (kept single definition).

// ---------------- launcher ----------------
extern "C" void kernel_launch(void* const* d_in, const int* in_sizes, int n_in,
                              void* d_out, int out_size, void* d_ws, size_t ws_size,
                              hipStream_t stream);

// Correct ola_t implementation (separate name to avoid the bad write above).
__global__ __launch_bounds__(256) void ola_transpose_kernel(const float* __restrict__ Y,
                                                            unsigned short* __restrict__ sigT) {
  __shared__ unsigned short tile[64][72];   // [q][r]
  int b = blockIdx.z;
  int q0 = blockIdx.x * 64, r0 = blockIdx.y * 64;
  int tid = threadIdx.x;
  int rr = tid & 63, qg = tid >> 6;          // read role: r fast (coalesced f32)
  const float* Yb = Y + (size_t)b * 512 * 1024;
#pragma unroll
  for (int i = 0; i < 16; ++i) {
    int q = q0 + qg * 16 + i;
    float v = Yb[(size_t)q * 1024 + r0 + rr];
    if (q > 0) v += Yb[(size_t)(q - 1) * 1024 + 512 + r0 + rr];
    tile[qg * 16 + i][rr] = f2bf(v);
  }
  __syncthreads();
  int rw = tid >> 2, qo = tid & 3;           // write role: 4 lanes x 16q = 128B per r
  unsigned short* orow = sigT + ((size_t)b * 512 + r0 + rw) * 512 + q0 + qo * 16;
  ushort4 w0, w1, w2, w3;
  w0.x = tile[qo * 16 + 0][rw];  w0.y = tile[qo * 16 + 1][rw];
  w0.z = tile[qo * 16 + 2][rw];  w0.w = tile[qo * 16 + 3][rw];
  w1.x = tile[qo * 16 + 4][rw];  w1.y = tile[qo * 16 + 5][rw];
  w1.z = tile[qo * 16 + 6][rw];  w1.w = tile[qo * 16 + 7][rw];
  w2.x = tile[qo * 16 + 8][rw];  w2.y = tile[qo * 16 + 9][rw];
  w2.z = tile[qo * 16 + 10][rw]; w2.w = tile[qo * 16 + 11][rw];
  w3.x = tile[qo * 16 + 12][rw]; w3.y = tile[qo * 16 + 13][rw];
  w3.z = tile[qo * 16 + 14][rw]; w3.w = tile[qo * 16 + 15][rw];
  *(ushort4*)(orow + 0)  = w0;
  *(ushort4*)(orow + 4)  = w1;
  *(ushort4*)(orow + 8)  = w2;
  *(ushort4*)(orow + 12) = w3;
}

extern "C" void kernel_launch(void* const* d_in, const int* in_sizes, int n_in,
                              void* d_out, int out_size, void* d_ws, size_t ws_size,
                              hipStream_t stream) {
  const float* control   = (const float*)d_in[0];
  const float* state_hv  = (const float*)d_in[1];
  const float* output_hv = (const float*)d_in[2];
  const float* input_hv  = (const float*)d_in[3];
  const float* direct_hv = (const float*)d_in[4];
  const float* proj_hv   = (const float*)d_in[5];
  const float* times     = (const float*)d_in[6];
  const float* A_proj   = (const float*)d_in[7];
  const float* B_proj   = (const float*)d_in[8];
  const float* A_state  = (const float*)d_in[9];
  const float* B_state  = (const float*)d_in[10];
  const float* A_input  = (const float*)d_in[11];
  const float* B_input  = (const float*)d_in[12];
  const float* A_output = (const float*)d_in[13];
  const float* B_output = (const float*)d_in[14];
  const float* A_direct = (const float*)d_in[15];
  const float* B_direct = (const float*)d_in[16];

  float* ws = (float*)d_ws;
  float* lat  = ws + OFF_LAT;
  float* impw = ws + OFF_IMP;
  float* Wsm  = ws + OFF_WSM;
  unsigned short* WpT   = (unsigned short*)(ws + OFF_WPT);
  unsigned short* WoT   = (unsigned short*)(ws + OFF_WOT);
  unsigned short* WdiT  = (unsigned short*)(ws + OFF_WDIT);
  unsigned short* ctrlT = (unsigned short*)(ws + OFF_CTRLT);
  unsigned short* proj  = (unsigned short*)(ws + OFF_PROJ);
  float* projD = ws + OFF_PROJD;
  unsigned short* S2 = (unsigned short*)(ws + OFF_S2);
  float* Mpow = ws + OFF_MPOW;
  float* Ec   = ws + OFF_EC;
  float* Hc   = ws + OFF_HC;
  float* Y    = ws + OFF_Y;
  unsigned short* sigT = (unsigned short*)(ws + OFF_SIG);
  unsigned short* Tb   = (unsigned short*)(ws + OFF_T);
  float* out  = (float*)d_out;

  // K1 latents (m: 0=proj,1=state,2=input,3=output,4=direct)
  latents_kernel<<<1, 640, 0, stream>>>(proj_hv, state_hv, input_hv, output_hv, direct_hv,
                                        A_proj, A_state, A_input, A_output, A_direct, lat);

  // Ws (f32 row-major, scan path)
  build_w_kernel<<<16, 256, 0, stream>>>(lat + 1 * 128, B_state, Wsm, 16384, 16384);

  // transposed bf16 weights: grid (C/32, R/32); (lat_m, Bm, out, R, C, bstride)
  build_wt_kernel<<<dim3(32, 16), 256, 0, stream>>>(lat + 0 * 128, B_proj, WpT, 512, 1024, 524288);
  build_wt_kernel<<<dim3(32, 32), 256, 0, stream>>>(lat + 4 * 128, B_direct, WdiT, 1024, 1024, 1179648);
  build_wt_kernel<<<dim3(4, 32), 256, 0, stream>>>(lat + 2 * 128, B_input, WdiT + 1024 * 1024, 1024, 128, 1179648);
  build_wt_kernel<<<dim3(32, 4), 256, 0, stream>>>(lat + 3 * 128, B_output, WoT, 128, 1024, 131072);

  // ctrl^2 transpose -> bf16
  transpose_sq_kernel<<<dim3(16, 16, 8), dim3(32, 8), 0, stream>>>(control, ctrlT);

  // proj = ctrlT @ WpT^T  (M=512,N=1024,K=512) -> bf16
  mfma_gemm_kernel<0, 1, 0><<<dim3(8, 4, 8), 256, 0, stream>>>(
      ctrlT, WpT, nullptr, 0, proj, 512, 1024, 512);

  // projD = proj @ WdiT^T  (M=512,N=1152,K=1024) -> f32
  mfma_gemm_kernel<0, 0, 0><<<dim3(9, 4, 8), 256, 0, stream>>>(
      proj, WdiT, nullptr, 0, projD, 512, 1152, 1024);

  // chunked scan
  copym1_kernel<<<128, 256, 0, stream>>>(Wsm, Mpow);
  powers_kernel<<<8, 256, 0, stream>>>(Mpow, 1);
  powers_kernel<<<16, 256, 0, stream>>>(Mpow, 2);
  powers_kernel<<<32, 256, 0, stream>>>(Mpow, 4);
  ec_kernel<<<512, 256, 0, stream>>>(Mpow, projD, Ec);
  combine_kernel<<<8, 128, 0, stream>>>(Mpow, Ec, Hc);
  pass2_kernel<<<512, 256, 0, stream>>>(Mpow, projD, Hc, S2);

  // Y = (S2 @ WoT^T + direct) * win  (M=512,N=1024,K=128) -> f32
  mfma_gemm_kernel<1, 0, 0><<<dim3(8, 4, 8), 256, 0, stream>>>(
      S2, WoT, projD, 1152, Y, 512, 1024, 128);

  // softmax -> imp ; Toeplitz -> Tb (bf16)
  softmax_kernel<<<8, 512, 0, stream>>>(times, impw);
  toeplitz_kernel<<<2048, 256, 0, stream>>>(impw, Tb);

  // overlap-add + transpose -> sigT bf16
  ola_transpose_kernel<<<dim3(8, 8, 8), 256, 0, stream>>>(Y, sigT);

  // out = Tb @ sigT^T  (triangular bf16 MFMA, M=512,N=512,K=512) -> f32
  mfma_gemm_kernel<0, 0, 1><<<dim3(4, 4, 8), 256, 0, stream>>>(
      Tb, sigT, nullptr, 0, out, 512, 512, 512);
}

// Round 5
// 272.400 us; speedup vs baseline: 4.5021x; 1.0692x over previous
//
#include <hip/hip_runtime.h>
#include <math.h>

// Problem constants
//  B=8, CTX=512, N_FRAMES=512, IN_DIM=1024, ST_DIM=128, HOP=512, N_SAMPLES=262144
//  HD=32, HL=16
// Scan parallelization: T=8 frames/chunk, C=64 chunks.
// GEMMs (proj, projD, Y) and conv (triangular Toeplitz) run on bf16 MFMA
// 16x16x32 with double-buffered LDS (2-phase); scan pieces stay f32.

typedef __attribute__((ext_vector_type(8))) short bfrag;   // 8 bf16 = 4 VGPRs
typedef __attribute__((ext_vector_type(4))) float f32x4;

__device__ inline unsigned short f2bf(float f) {
  unsigned int u = __float_as_uint(f);
  unsigned int r = (u + 0x7fff + ((u >> 16) & 1)) >> 16;   // RNE
  return (unsigned short)r;
}

// ---------------- workspace layout (float offsets) ----------------
static const size_t OFF_LAT   = 0;          // 640
static const size_t OFF_IMP   = 1024;       // 8*512
static const size_t OFF_WPT   = 139264;     // WpT bf16 [8][1024][512]  = 2,097,152 f32-eq
static const size_t OFF_WOT   = 2236416;    // WoT bf16 [8][1024][128]  = 524,288
static const size_t OFF_WDIT  = 2760704;    // WdiT bf16 [8][1152][1024] = 4,718,592
static const size_t OFF_CTRLT = 7479296;    // ctrlT bf16 [8][512][512] = 1,048,576
static const size_t OFF_PROJ  = 8527872;    // proj bf16 [8][512][1024] = 2,097,152
static const size_t OFF_PROJD = 10625024;   // projD f32 [8][512][1152] = 4,718,592
static const size_t OFF_S2    = 15343616;   // S2 bf16 [8][512][128] = 262,144
static const size_t OFF_MPOW  = 15605760;   // f32 8*9*16384 = 1,179,648 (slot1 = Ws)
static const size_t OFF_EC    = 16785408;   // 65,536
static const size_t OFF_HC    = 16850944;   // 65,536
static const size_t OFF_Y     = 16916480;   // f32 [8][512][1024] = 4,194,304
static const size_t OFF_SIG   = 21110784;   // sigT bf16 [8][512][512] = 1,048,576 f32-eq
static const size_t OFF_T     = 23207936;   // Tb bf16 [8][512][512] = 1,048,576 f32-eq
// total < 24.3M floats = ~93 MiB

// ---------------- K1: latents lat[m][b][l] = hv_m[b] @ A_m ----------------
__global__ void latents_kernel(
    const float* __restrict__ hv_p, const float* __restrict__ hv_s,
    const float* __restrict__ hv_i, const float* __restrict__ hv_o,
    const float* __restrict__ hv_d,
    const float* __restrict__ A_p, const float* __restrict__ A_s,
    const float* __restrict__ A_i, const float* __restrict__ A_o,
    const float* __restrict__ A_d,
    float* __restrict__ lat) {
  int tid = threadIdx.x;
  if (tid >= 640) return;
  int m = tid >> 7, b = (tid >> 4) & 7, l = tid & 15;
  const float* hv; const float* A;
  switch (m) {
    case 0: hv = hv_p; A = A_p; break;
    case 1: hv = hv_s; A = A_s; break;
    case 2: hv = hv_i; A = A_i; break;
    case 3: hv = hv_o; A = A_o; break;
    default: hv = hv_d; A = A_d; break;
  }
  float acc = 0.f;
  for (int h = 0; h < 32; ++h) acc = fmaf(hv[b * 32 + h], A[h * 16 + l], acc);
  lat[tid] = acc;
}

// ---------------- K2a: f32 row-major W build (Ws -> Mpow slot 1) ----------------
__global__ __launch_bounds__(256) void build_w_kernel(
    const float* __restrict__ lat,   // [8][16]
    const float* __restrict__ Bm,    // [16][total]
    float* __restrict__ out,
    int total, size_t bstride) {
  int e = (blockIdx.x * 256 + threadIdx.x) * 4;
  if (e >= total) return;
  float4 v[16];
#pragma unroll
  for (int l = 0; l < 16; ++l)
    v[l] = *(const float4*)(Bm + (size_t)l * total + e);
#pragma unroll 1
  for (int b = 0; b < 8; ++b) {
    float ax = 0.f, ay = 0.f, az = 0.f, aw = 0.f;
#pragma unroll
    for (int l = 0; l < 16; ++l) {
      float lv = lat[b * 16 + l];
      ax = fmaf(lv, v[l].x, ax);
      ay = fmaf(lv, v[l].y, ay);
      az = fmaf(lv, v[l].z, az);
      aw = fmaf(lv, v[l].w, aw);
    }
    *(float4*)(out + (size_t)b * bstride + e) = make_float4(ax, ay, az, aw);
  }
}

// ---------------- K2b: transposed bf16 W build, coalesced reads + LDS transpose ----------------
__global__ __launch_bounds__(256) void build_wt_kernel(
    const float* __restrict__ lat,        // [8][16]
    const float* __restrict__ Bm,         // [16][R*C]
    unsigned short* __restrict__ out,     // [8 via bstride][C][R] bf16
    int R, int C, size_t bstride) {
  __shared__ float ls[128];
  __shared__ unsigned short tile[32][36];
  int tid = threadIdx.x;
  if (tid < 128) ls[tid] = lat[tid];
  int cc = tid & 31, rg = tid >> 5;
  int c = blockIdx.x * 32 + cc;
  int r0 = blockIdx.y * 32 + rg * 4;
  size_t RC = (size_t)R * C;
  float bm[16][4];
#pragma unroll
  for (int l = 0; l < 16; ++l) {
    const float* p = Bm + (size_t)l * RC + (size_t)r0 * C + c;
#pragma unroll
    for (int j = 0; j < 4; ++j) bm[l][j] = p[(size_t)j * C];
  }
  int wc = tid >> 3, wrq = tid & 7;
  __syncthreads();
#pragma unroll 1
  for (int b = 0; b < 8; ++b) {
    float a0 = 0.f, a1 = 0.f, a2 = 0.f, a3 = 0.f;
#pragma unroll
    for (int l = 0; l < 16; ++l) {
      float lv = ls[b * 16 + l];
      a0 = fmaf(lv, bm[l][0], a0);
      a1 = fmaf(lv, bm[l][1], a1);
      a2 = fmaf(lv, bm[l][2], a2);
      a3 = fmaf(lv, bm[l][3], a3);
    }
    __syncthreads();
    ushort2 p0, p1;
    p0.x = f2bf(a0); p0.y = f2bf(a1);
    p1.x = f2bf(a2); p1.y = f2bf(a3);
    *(ushort2*)&tile[cc][rg * 4] = p0;
    *(ushort2*)&tile[cc][rg * 4 + 2] = p1;
    __syncthreads();
    ushort4 v = *(const ushort4*)&tile[wc][wrq * 4];
    *(ushort4*)(out + (size_t)b * bstride +
                (size_t)(blockIdx.x * 32 + wc) * R + blockIdx.y * 32 + wrq * 4) = v;
  }
}

// ---------------- K3: ctrlT[b,f,c] = control[b,c,f]^2  (bf16 out) ----------------
__global__ void transpose_sq_kernel(const float* __restrict__ in,
                                    unsigned short* __restrict__ out) {
  __shared__ float tile[32][33];
  int b = blockIdx.z;
  int c0 = blockIdx.x * 32, f0 = blockIdx.y * 32;
  int tx = threadIdx.x, ty = threadIdx.y;  // 32 x 8
  const float* inb = in + (size_t)b * 512 * 512;
  unsigned short* outb = out + (size_t)b * 512 * 512;
#pragma unroll
  for (int i = 0; i < 4; ++i) {
    float v = inb[(size_t)(c0 + ty + i * 8) * 512 + f0 + tx];
    tile[ty + i * 8][tx] = v * v;
  }
  __syncthreads();
#pragma unroll
  for (int i = 0; i < 4; ++i)
    outb[(size_t)(f0 + ty + i * 8) * 512 + c0 + tx] = f2bf(tile[tx][ty + i * 8]);
}

// ---------------- K4: bf16 MFMA GEMM, double-buffered LDS (2-phase) ----------------
// C[b] = A[b] @ BT[b]^T.  A: [M][K] bf16.  BT: [N][K] bf16.  BM=BN=128, BK=32.
// One barrier per K-step; next tile's global loads issued right after the
// barrier so HBM latency hides under ds_read+MFMA.
// EPI: C=(acc+D)*win(n) f32.  CD_BF16: C bf16.  TRI: kend=m0+128.
template <int EPI, int CD_BF16, int TRI>
__global__ __launch_bounds__(256) void mfma_gemm_kernel(
    const unsigned short* __restrict__ A,
    const unsigned short* __restrict__ BT,
    const float* __restrict__ D, int ldd,
    void* __restrict__ Cout,
    int M, int N, int K) {
  const int b = blockIdx.z;
  A  += (size_t)b * M * K;
  BT += (size_t)b * N * K;
  const int m0 = blockIdx.y * 128;
  const int n0 = blockIdx.x * 128;
  __shared__ __align__(16) unsigned short As[2][128][40];  // 32 + 8 pad (2-way free)
  __shared__ __align__(16) unsigned short Bs[2][128][40];
  const int tid = threadIdx.x;
  const int lane = tid & 63, wave = tid >> 6;
  const int wr = (wave >> 1) * 64, wc = (wave & 1) * 64;
  const int l15 = lane & 15, g = lane >> 4;
  f32x4 acc[4][4];
#pragma unroll
  for (int i = 0; i < 4; ++i)
#pragma unroll
    for (int j = 0; j < 4; ++j)
#pragma unroll
      for (int r = 0; r < 4; ++r) acc[i][j][r] = 0.f;

  const int srow = tid >> 2, soct = tid & 3;
  const unsigned short* Ag = A + (size_t)(m0 + srow) * K + soct * 8;
  const unsigned short* Bg = BT + (size_t)(n0 + srow) * K + soct * 8;
  const size_t row64 = (size_t)64 * K;
  const int kend = TRI ? (m0 + 128) : K;
  const int nt = kend >> 5;

  bfrag av0 = *(const bfrag*)(Ag);
  bfrag av1 = *(const bfrag*)(Ag + row64);
  bfrag bv0 = *(const bfrag*)(Bg);
  bfrag bv1 = *(const bfrag*)(Bg + row64);

  int cur = 0;
#pragma unroll 1
  for (int t = 0; t < nt; ++t) {
    *(bfrag*)(&As[cur][srow][soct * 8]) = av0;
    *(bfrag*)(&As[cur][64 + srow][soct * 8]) = av1;
    *(bfrag*)(&Bs[cur][srow][soct * 8]) = bv0;
    *(bfrag*)(&Bs[cur][64 + srow][soct * 8]) = bv1;
    __syncthreads();
    if (t + 1 < nt) {
      const int k0 = (t + 1) << 5;
      av0 = *(const bfrag*)(Ag + k0);
      av1 = *(const bfrag*)(Ag + row64 + k0);
      bv0 = *(const bfrag*)(Bg + k0);
      bv1 = *(const bfrag*)(Bg + row64 + k0);
    }
    bfrag af[4], bf[4];
#pragma unroll
    for (int mi = 0; mi < 4; ++mi)
      af[mi] = *(const bfrag*)(&As[cur][wr + mi * 16 + l15][g * 8]);
#pragma unroll
    for (int nj = 0; nj < 4; ++nj)
      bf[nj] = *(const bfrag*)(&Bs[cur][wc + nj * 16 + l15][g * 8]);
#pragma unroll
    for (int mi = 0; mi < 4; ++mi)
#pragma unroll
      for (int nj = 0; nj < 4; ++nj)
        acc[mi][nj] = __builtin_amdgcn_mfma_f32_16x16x32_bf16(af[mi], bf[nj], acc[mi][nj], 0, 0, 0);
    cur ^= 1;
  }

  // epilogue: C/D frag mapping: col = l15, row = 4*g + r
  float* Cf = (float*)Cout + (size_t)b * M * N;
  unsigned short* Cb = (unsigned short*)Cout + (size_t)b * M * N;
  if (EPI) D += (size_t)b * M * ldd;
#pragma unroll
  for (int nj = 0; nj < 4; ++nj) {
    int n = n0 + wc + nj * 16 + l15;
    float win = 0.f;
    if (EPI) win = 0.5f - 0.5f * cosf(6.28318530717958647693f * (float)n / 1024.0f);
#pragma unroll
    for (int mi = 0; mi < 4; ++mi) {
      int mbase = m0 + wr + mi * 16 + 4 * g;
#pragma unroll
      for (int r = 0; r < 4; ++r) {
        int m = mbase + r;
        float v = acc[mi][nj][r];
        if (EPI) v = (v + D[(size_t)m * ldd + n]) * win;
        if (CD_BF16) Cb[(size_t)m * N + n] = f2bf(v);
        else         Cf[(size_t)m * N + n] = v;
      }
    }
  }
}

// ---------------- K5a: power step  M_{half+k} = M_k @ M_half ----------------
__global__ __launch_bounds__(256) void powers_kernel(float* __restrict__ Mpow, int half) {
  int z = blockIdx.x;
  int b = z / half, k = z - b * half + 1;
  const float* A = Mpow + ((size_t)b * 9 + k) * 16384;
  const float* Bm = Mpow + ((size_t)b * 9 + half) * 16384;
  float* C = Mpow + ((size_t)b * 9 + half + k) * 16384;
  __shared__ __align__(16) float As[16][132];
  __shared__ __align__(16) float Bs[16][132];
  int tid = threadIdx.x;
  int tx = tid & 15, ty = tid >> 4;
  float acc[8][8];
#pragma unroll
  for (int i = 0; i < 8; ++i)
#pragma unroll
    for (int j = 0; j < 8; ++j) acc[i][j] = 0.f;
  int ar = tid >> 1, ac = (tid & 1) * 8;
  int br = tid >> 4, bc = (tid & 15) * 8;
  for (int k0 = 0; k0 < 128; k0 += 16) {
    float4 a0 = *(const float4*)(A + (size_t)ar * 128 + k0 + ac);
    float4 a1 = *(const float4*)(A + (size_t)ar * 128 + k0 + ac + 4);
    float4 b0 = *(const float4*)(Bm + (size_t)(k0 + br) * 128 + bc);
    float4 b1 = *(const float4*)(Bm + (size_t)(k0 + br) * 128 + bc + 4);
    __syncthreads();
    As[ac + 0][ar] = a0.x; As[ac + 1][ar] = a0.y; As[ac + 2][ar] = a0.z; As[ac + 3][ar] = a0.w;
    As[ac + 4][ar] = a1.x; As[ac + 5][ar] = a1.y; As[ac + 6][ar] = a1.z; As[ac + 7][ar] = a1.w;
    *(float4*)(&Bs[br][bc]) = b0;
    *(float4*)(&Bs[br][bc + 4]) = b1;
    __syncthreads();
#pragma unroll
    for (int kk = 0; kk < 16; ++kk) {
      float4 av0 = *(const float4*)(&As[kk][ty * 8]);
      float4 av1 = *(const float4*)(&As[kk][ty * 8 + 4]);
      float4 bv0 = *(const float4*)(&Bs[kk][tx * 8]);
      float4 bv1 = *(const float4*)(&Bs[kk][tx * 8 + 4]);
      float aa[8] = {av0.x, av0.y, av0.z, av0.w, av1.x, av1.y, av1.z, av1.w};
      float bb[8] = {bv0.x, bv0.y, bv0.z, bv0.w, bv1.x, bv1.y, bv1.z, bv1.w};
#pragma unroll
      for (int i = 0; i < 8; ++i)
#pragma unroll
        for (int j = 0; j < 8; ++j) acc[i][j] = fmaf(aa[i], bb[j], acc[i][j]);
    }
  }
#pragma unroll
  for (int i = 0; i < 8; ++i) {
    *(float4*)(C + (size_t)(ty * 8 + i) * 128 + tx * 8) =
        make_float4(acc[i][0], acc[i][1], acc[i][2], acc[i][3]);
    *(float4*)(C + (size_t)(ty * 8 + i) * 128 + tx * 8 + 4) =
        make_float4(acc[i][4], acc[i][5], acc[i][6], acc[i][7]);
  }
}

// ---------------- K5b: chunk aggregates ----------------
__global__ __launch_bounds__(256) void ec_kernel(
    const float* __restrict__ Mpow, const float* __restrict__ PD,
    float* __restrict__ Ec) {
  int b = blockIdx.x >> 6, c = blockIdx.x & 63;
  int tid = threadIdx.x, t = tid & 127, dh = tid >> 7;
  __shared__ __align__(16) float Bus[7][128];
  __shared__ float red[128];
  const float* Bu = PD + (size_t)b * 512 * 1152 + 1024;
  for (int idx = tid; idx < 896; idx += 256)
    Bus[idx >> 7][idx & 127] = Bu[(size_t)(c * 8 + (idx >> 7)) * 1152 + (idx & 127)];
  __syncthreads();
  float acc = 0.f;
  const float* Mb = Mpow + (size_t)b * 9 * 16384;
  int d0 = dh * 64;
#pragma unroll
  for (int i = 0; i < 7; ++i) {
    const float* Mk = Mb + (size_t)(7 - i) * 16384 + t;
#pragma unroll 8
    for (int d = 0; d < 64; ++d)
      acc = fmaf(Bus[i][d0 + d], Mk[(size_t)(d0 + d) * 128], acc);
  }
  if (dh == 1) red[t] = acc;
  __syncthreads();
  if (dh == 0) {
    float tot = acc + red[t] + Bu[(size_t)(c * 8 + 7) * 1152 + t];
    Ec[((size_t)b * 64 + c) * 128 + t] = tot;
  }
}

// ---------------- K5c: serial chunk combine (Ec staged in LDS, dbuf state) ----------------
__global__ __launch_bounds__(128) void combine_kernel(
    const float* __restrict__ Mpow, const float* __restrict__ Ec,
    float* __restrict__ Hc) {
  int b = blockIdx.x, t = threadIdx.x;
  float w[128];
  const float* M8 = Mpow + ((size_t)b * 9 + 8) * 16384;
#pragma unroll
  for (int k = 0; k < 128; ++k) w[k] = M8[(size_t)k * 128 + t];
  __shared__ __align__(16) float ec_sh[64 * 128];   // 32 KB
  const float* Ecb = Ec + (size_t)b * 8192;
#pragma unroll
  for (int i = 0; i < 16; ++i) {
    int idx = (t + i * 128) * 4;
    *(float4*)&ec_sh[idx] = *(const float4*)(Ecb + idx);
  }
  __shared__ __align__(16) float sh[2][128];
  sh[0][t] = 0.f;
  float* Hcb = Hc + (size_t)b * 8192;
  Hcb[t] = 0.f;
  __syncthreads();
  int cur = 0;
#pragma unroll 1
  for (int c = 0; c < 63; ++c) {
    float a0 = 0.f, a1 = 0.f, a2 = 0.f, a3 = 0.f;
#pragma unroll
    for (int k = 0; k < 128; k += 4) {
      float4 sv = *(const float4*)(&sh[cur][k]);
      a0 = fmaf(sv.x, w[k + 0], a0);
      a1 = fmaf(sv.y, w[k + 1], a1);
      a2 = fmaf(sv.z, w[k + 2], a2);
      a3 = fmaf(sv.w, w[k + 3], a3);
    }
    float hn = (a0 + a1) + (a2 + a3) + ec_sh[c * 128 + t];
    sh[cur ^ 1][t] = hn;
    Hcb[(c + 1) * 128 + t] = hn;
    __syncthreads();
    cur ^= 1;
  }
}

// ---------------- K5d: pass 2 (S2 out in bf16) ----------------
__global__ __launch_bounds__(256) void pass2_kernel(
    const float* __restrict__ Mpow, const float* __restrict__ PD,
    const float* __restrict__ Hc, unsigned short* __restrict__ S2) {
  int b = blockIdx.x >> 6, c = blockIdx.x & 63;
  int tid = threadIdx.x, t = tid & 127, dh = tid >> 7;
  __shared__ __align__(16) float Xs[15][128];
  __shared__ __align__(16) float red[8][128];
  const float* Bu = PD + (size_t)b * 512 * 1152 + 1024;
  for (int idx = tid; idx < 15 * 128; idx += 256) {
    int rr = idx >> 7, cc = idx & 127;
    float v = 0.f;
    if (rr == 7) v = Hc[((size_t)b * 64 + c) * 128 + cc];
    else if (rr > 7) v = Bu[(size_t)(c * 8 + rr - 8) * 1152 + cc];
    Xs[rr][cc] = v;
  }
  __syncthreads();
  float acc[8];
#pragma unroll
  for (int j = 0; j < 8; ++j) acc[j] = 0.f;
  const float* Mb = Mpow + (size_t)b * 9 * 16384;
  int d0 = dh * 64;
#pragma unroll 1
  for (int k = 1; k <= 8; ++k) {
    const float* Mk = Mb + (size_t)k * 16384 + t;
    const int xbase = 8 - k;
#pragma unroll 4
    for (int d4 = 0; d4 < 16; ++d4) {
      int d = d0 + d4 * 4;
      float m0 = Mk[(size_t)(d + 0) * 128];
      float m1 = Mk[(size_t)(d + 1) * 128];
      float m2 = Mk[(size_t)(d + 2) * 128];
      float m3 = Mk[(size_t)(d + 3) * 128];
#pragma unroll
      for (int j = 0; j < 8; ++j) {
        float4 xv = *(const float4*)(&Xs[xbase + j][d]);
        acc[j] = fmaf(xv.x, m0, acc[j]);
        acc[j] = fmaf(xv.y, m1, acc[j]);
        acc[j] = fmaf(xv.z, m2, acc[j]);
        acc[j] = fmaf(xv.w, m3, acc[j]);
      }
    }
  }
  if (dh == 1) {
#pragma unroll
    for (int j = 0; j < 8; ++j) red[j][t] = acc[j];
  }
  __syncthreads();
  if (dh == 0) {
    unsigned short* S2b = S2 + ((size_t)b * 512 + c * 8) * 128;
#pragma unroll
    for (int j = 0; j < 8; ++j)
      S2b[(size_t)j * 128 + t] = f2bf(acc[j] + red[j][t]);
  }
}

// ---------------- K6: softmax over frames ----------------
__global__ void softmax_kernel(const float* __restrict__ times, float* __restrict__ imp) {
  int b = blockIdx.x, t = threadIdx.x;  // 512 threads
  __shared__ float red[512];
  float v = times[b * 512 + t];
  red[t] = v;
  __syncthreads();
  for (int s = 256; s > 0; s >>= 1) {
    if (t < s) red[t] = fmaxf(red[t], red[t + s]);
    __syncthreads();
  }
  float m = red[0];
  __syncthreads();
  float e = expf(v - m);
  red[t] = e;
  __syncthreads();
  for (int s = 256; s > 0; s >>= 1) {
    if (t < s) red[t] += red[t + s];
    __syncthreads();
  }
  imp[b * 512 + t] = e / red[0];
}

// ---------------- K6b: Toeplitz build (bf16) ----------------
__global__ void toeplitz_kernel(const float* __restrict__ imp, unsigned short* __restrict__ T) {
  int idx = blockIdx.x * 256 + threadIdx.x;   // 8 * 512 * 128 threads (ushort4 each)
  int b = idx >> 16;
  int rem = idx & 65535;
  int q = rem >> 7, p4 = (rem & 127) * 4;
  const float* impb = imp + b * 512;
  ushort4 o;
  o.x = (p4 + 0 <= q) ? f2bf(impb[q - p4 - 0]) : (unsigned short)0;
  o.y = (p4 + 1 <= q) ? f2bf(impb[q - p4 - 1]) : (unsigned short)0;
  o.z = (p4 + 2 <= q) ? f2bf(impb[q - p4 - 2]) : (unsigned short)0;
  o.w = (p4 + 3 <= q) ? f2bf(impb[q - p4 - 3]) : (unsigned short)0;
  *(ushort4*)(T + ((size_t)b * 512 + q) * 512 + p4) = o;
}

// ---------------- K7: overlap-add + transpose -> sigT[b][r][p] bf16 ----------------
__global__ __launch_bounds__(256) void ola_transpose_kernel(const float* __restrict__ Y,
                                                            unsigned short* __restrict__ sigT) {
  __shared__ unsigned short tile[64][72];   // [q][r]
  int b = blockIdx.z;
  int q0 = blockIdx.x * 64, r0 = blockIdx.y * 64;
  int tid = threadIdx.x;
  int rr = tid & 63, qg = tid >> 6;          // read role: r fast (coalesced f32)
  const float* Yb = Y + (size_t)b * 512 * 1024;
#pragma unroll
  for (int i = 0; i < 16; ++i) {
    int q = q0 + qg * 16 + i;
    float v = Yb[(size_t)q * 1024 + r0 + rr];
    if (q > 0) v += Yb[(size_t)(q - 1) * 1024 + 512 + r0 + rr];
    tile[qg * 16 + i][rr] = f2bf(v);
  }
  __syncthreads();
  int rw = tid >> 2, qo = tid & 3;           // write role: 4 lanes x 16q = 128B per r
  unsigned short* orow = sigT + ((size_t)b * 512 + r0 + rw) * 512 + q0 + qo * 16;
  ushort4 w0, w1, w2, w3;
  w0.x = tile[qo * 16 + 0][rw];  w0.y = tile[qo * 16 + 1][rw];
  w0.z = tile[qo * 16 + 2][rw];  w0.w = tile[qo * 16 + 3][rw];
  w1.x = tile[qo * 16 + 4][rw];  w1.y = tile[qo * 16 + 5][rw];
  w1.z = tile[qo * 16 + 6][rw];  w1.w = tile[qo * 16 + 7][rw];
  w2.x = tile[qo * 16 + 8][rw];  w2.y = tile[qo * 16 + 9][rw];
  w2.z = tile[qo * 16 + 10][rw]; w2.w = tile[qo * 16 + 11][rw];
  w3.x = tile[qo * 16 + 12][rw]; w3.y = tile[qo * 16 + 13][rw];
  w3.z = tile[qo * 16 + 14][rw]; w3.w = tile[qo * 16 + 15][rw];
  *(ushort4*)(orow + 0)  = w0;
  *(ushort4*)(orow + 4)  = w1;
  *(ushort4*)(orow + 8)  = w2;
  *(ushort4*)(orow + 12) = w3;
}

// ---------------- launcher ----------------
extern "C" void kernel_launch(void* const* d_in, const int* in_sizes, int n_in,
                              void* d_out, int out_size, void* d_ws, size_t ws_size,
                              hipStream_t stream) {
  const float* control   = (const float*)d_in[0];
  const float* state_hv  = (const float*)d_in[1];
  const float* output_hv = (const float*)d_in[2];
  const float* input_hv  = (const float*)d_in[3];
  const float* direct_hv = (const float*)d_in[4];
  const float* proj_hv   = (const float*)d_in[5];
  const float* times     = (const float*)d_in[6];
  const float* A_proj   = (const float*)d_in[7];
  const float* B_proj   = (const float*)d_in[8];
  const float* A_state  = (const float*)d_in[9];
  const float* B_state  = (const float*)d_in[10];
  const float* A_input  = (const float*)d_in[11];
  const float* B_input  = (const float*)d_in[12];
  const float* A_output = (const float*)d_in[13];
  const float* B_output = (const float*)d_in[14];
  const float* A_direct = (const float*)d_in[15];
  const float* B_direct = (const float*)d_in[16];

  float* ws = (float*)d_ws;
  float* lat  = ws + OFF_LAT;
  float* impw = ws + OFF_IMP;
  unsigned short* WpT   = (unsigned short*)(ws + OFF_WPT);
  unsigned short* WoT   = (unsigned short*)(ws + OFF_WOT);
  unsigned short* WdiT  = (unsigned short*)(ws + OFF_WDIT);
  unsigned short* ctrlT = (unsigned short*)(ws + OFF_CTRLT);
  unsigned short* proj  = (unsigned short*)(ws + OFF_PROJ);
  float* projD = ws + OFF_PROJD;
  unsigned short* S2 = (unsigned short*)(ws + OFF_S2);
  float* Mpow = ws + OFF_MPOW;
  float* Ec   = ws + OFF_EC;
  float* Hc   = ws + OFF_HC;
  float* Y    = ws + OFF_Y;
  unsigned short* sigT = (unsigned short*)(ws + OFF_SIG);
  unsigned short* Tb   = (unsigned short*)(ws + OFF_T);
  float* out  = (float*)d_out;

  // K1 latents (m: 0=proj,1=state,2=input,3=output,4=direct)
  latents_kernel<<<1, 640, 0, stream>>>(proj_hv, state_hv, input_hv, output_hv, direct_hv,
                                        A_proj, A_state, A_input, A_output, A_direct, lat);

  // Ws (f32) written directly into Mpow slot 1 (bstride = 9*16384)
  build_w_kernel<<<16, 256, 0, stream>>>(lat + 1 * 128, B_state, Mpow + 16384, 16384, 147456);

  // transposed bf16 weights: grid (C/32, R/32); (lat_m, Bm, out, R, C, bstride)
  build_wt_kernel<<<dim3(32, 16), 256, 0, stream>>>(lat + 0 * 128, B_proj, WpT, 512, 1024, 524288);
  build_wt_kernel<<<dim3(32, 32), 256, 0, stream>>>(lat + 4 * 128, B_direct, WdiT, 1024, 1024, 1179648);
  build_wt_kernel<<<dim3(4, 32), 256, 0, stream>>>(lat + 2 * 128, B_input, WdiT + 1024 * 1024, 1024, 128, 1179648);
  build_wt_kernel<<<dim3(32, 4), 256, 0, stream>>>(lat + 3 * 128, B_output, WoT, 128, 1024, 131072);

  // ctrl^2 transpose -> bf16
  transpose_sq_kernel<<<dim3(16, 16, 8), dim3(32, 8), 0, stream>>>(control, ctrlT);

  // proj = ctrlT @ WpT^T  (M=512,N=1024,K=512) -> bf16
  mfma_gemm_kernel<0, 1, 0><<<dim3(8, 4, 8), 256, 0, stream>>>(
      ctrlT, WpT, nullptr, 0, proj, 512, 1024, 512);

  // projD = proj @ WdiT^T  (M=512,N=1152,K=1024) -> f32
  mfma_gemm_kernel<0, 0, 0><<<dim3(9, 4, 8), 256, 0, stream>>>(
      proj, WdiT, nullptr, 0, projD, 512, 1152, 1024);

  // chunked scan
  powers_kernel<<<8, 256, 0, stream>>>(Mpow, 1);
  powers_kernel<<<16, 256, 0, stream>>>(Mpow, 2);
  powers_kernel<<<32, 256, 0, stream>>>(Mpow, 4);
  ec_kernel<<<512, 256, 0, stream>>>(Mpow, projD, Ec);
  combine_kernel<<<8, 128, 0, stream>>>(Mpow, Ec, Hc);
  pass2_kernel<<<512, 256, 0, stream>>>(Mpow, projD, Hc, S2);

  // Y = (S2 @ WoT^T + direct) * win  (M=512,N=1024,K=128) -> f32
  mfma_gemm_kernel<1, 0, 0><<<dim3(8, 4, 8), 256, 0, stream>>>(
      S2, WoT, projD, 1152, Y, 512, 1024, 128);

  // softmax -> imp ; Toeplitz -> Tb (bf16)
  softmax_kernel<<<8, 512, 0, stream>>>(times, impw);
  toeplitz_kernel<<<2048, 256, 0, stream>>>(impw, Tb);

  // overlap-add + transpose -> sigT bf16
  ola_transpose_kernel<<<dim3(8, 8, 8), 256, 0, stream>>>(Y, sigT);

  // out = Tb @ sigT^T  (triangular bf16 MFMA, M=512,N=512,K=512) -> f32
  mfma_gemm_kernel<0, 0, 1><<<dim3(4, 4, 8), 256, 0, stream>>>(
      Tb, sigT, nullptr, 0, out, 512, 512, 512);
}

// Round 6
// 240.167 us; speedup vs baseline: 5.1063x; 1.1342x over previous
//
#include <hip/hip_runtime.h>
#include <math.h>

// Problem constants
//  B=8, CTX=512, N_FRAMES=512, IN_DIM=1024, ST_DIM=128, HOP=512, N_SAMPLES=262144
//  HD=32, HL=16
// Scan parallelization: T=8 frames/chunk, C=64 chunks.
// 12 launches: megabuild, proj, projD, powers x3, ec, combine, pass2, Y(->YT),
// ola, conv(softmax+Toeplitz fused).

typedef __attribute__((ext_vector_type(8))) short bfrag;   // 8 bf16 = 4 VGPRs
typedef __attribute__((ext_vector_type(4))) float f32x4;

__device__ inline unsigned short f2bf(float f) {
  unsigned int u = __float_as_uint(f);
  unsigned int r = (u + 0x7fff + ((u >> 16) & 1)) >> 16;   // RNE
  return (unsigned short)r;
}
__device__ inline float bf2f(unsigned short u) {
  return __uint_as_float(((unsigned int)u) << 16);
}

// ---------------- workspace layout (float offsets) ----------------
static const size_t OFF_IMP   = 1024;       // 8*512 (unused now, kept for layout stability)
static const size_t OFF_WPT   = 139264;     // WpT bf16 [8][1024][512]
static const size_t OFF_WOT   = 2236416;    // WoT bf16 [8][1024][128]
static const size_t OFF_WDIT  = 2760704;    // WdiT bf16 [8][1152][1024]
static const size_t OFF_CTRLT = 7479296;    // ctrlT bf16 [8][512][512]
static const size_t OFF_PROJ  = 8527872;    // proj bf16 [8][512][1024]
static const size_t OFF_PROJD = 10625024;   // projD f32 [8][512][1152]
static const size_t OFF_S2    = 15343616;   // S2 bf16 [8][512][128]
static const size_t OFF_MPOW  = 15605760;   // f32 8*9*16384 (slot1 = Ws)
static const size_t OFF_EC    = 16785408;   // 65,536
static const size_t OFF_HC    = 16850944;   // 65,536
static const size_t OFF_Y     = 16916480;   // YT bf16 [8][1024][512] = 2,097,152 f32-eq
static const size_t OFF_SIG   = 21110784;   // sigT bf16 [8][512][512]

// ---------------- K1: mega-build ----------------
// blocks [0,512)      WpT   (R=512,  C=1024, grid 32x16)  model=proj
// blocks [512,1536)   WdT   (R=1024, C=1024, grid 32x32)  model=direct
// blocks [1536,1664)  WiT   (R=1024, C=128,  grid 4x32)   model=input
// blocks [1664,1792)  WoT   (R=128,  C=1024, grid 32x4)   model=output
// blocks [1792,1808)  Ws f32 -> Mpow slot 1               model=state
// blocks [1808,3856)  transpose_sq: ctrlT[b,f,c] = control[b,c,f]^2 (bf16)
__global__ __launch_bounds__(256) void megabuild_kernel(
    const float* __restrict__ hv_p, const float* __restrict__ hv_s,
    const float* __restrict__ hv_i, const float* __restrict__ hv_o,
    const float* __restrict__ hv_d,
    const float* __restrict__ A_p, const float* __restrict__ A_s,
    const float* __restrict__ A_i, const float* __restrict__ A_o,
    const float* __restrict__ A_d,
    const float* __restrict__ B_p, const float* __restrict__ B_s,
    const float* __restrict__ B_i, const float* __restrict__ B_o,
    const float* __restrict__ B_d,
    const float* __restrict__ control,
    unsigned short* __restrict__ WpT, unsigned short* __restrict__ WoT,
    unsigned short* __restrict__ WdiT, float* __restrict__ Ws1,
    unsigned short* __restrict__ ctrlT) {
  __shared__ float ls[128];
  __shared__ unsigned short tile[32][36];
  __shared__ float ttile[32][33];
  const int blk = blockIdx.x;
  const int tid = threadIdx.x;

  if (blk >= 1808) {
    // ---- transpose+square role ----
    int z = blk - 1808;
    int b = z >> 8;
    int c0 = (z & 15) * 32, f0 = ((z >> 4) & 15) * 32;
    int tx = tid & 31, ty = tid >> 5;   // 32 x 8
    const float* inb = control + (size_t)b * 512 * 512;
    unsigned short* outb = ctrlT + (size_t)b * 512 * 512;
#pragma unroll
    for (int i = 0; i < 4; ++i) {
      float v = inb[(size_t)(c0 + ty + i * 8) * 512 + f0 + tx];
      ttile[ty + i * 8][tx] = v * v;
    }
    __syncthreads();
#pragma unroll
    for (int i = 0; i < 4; ++i)
      outb[(size_t)(f0 + ty + i * 8) * 512 + c0 + tx] = f2bf(ttile[tx][ty + i * 8]);
    return;
  }

  // ---- weight-build roles: select model ----
  const float* hv; const float* Am; const float* Bm;
  unsigned short* outw = nullptr; int R = 0, C = 0; size_t bstride = 0; int bx = 0, by = 0;
  int role;   // 0..3 = WT builds, 4 = Ws f32
  if (blk < 512)        { role = 0; hv = hv_p; Am = A_p; Bm = B_p; outw = WpT;  R = 512;  C = 1024; bstride = 524288;  bx = blk & 31;           by = blk >> 5; }
  else if (blk < 1536)  { role = 1; hv = hv_d; Am = A_d; Bm = B_d; outw = WdiT; R = 1024; C = 1024; bstride = 1179648; bx = (blk - 512) & 31;   by = (blk - 512) >> 5; }
  else if (blk < 1664)  { role = 2; hv = hv_i; Am = A_i; Bm = B_i; outw = WdiT + 1024 * 1024; R = 1024; C = 128; bstride = 1179648; bx = (blk - 1536) & 3; by = (blk - 1536) >> 2; }
  else if (blk < 1792)  { role = 3; hv = hv_o; Am = A_o; Bm = B_o; outw = WoT;  R = 128;  C = 1024; bstride = 131072;  bx = (blk - 1664) & 31;  by = (blk - 1664) >> 5; }
  else                  { role = 4; hv = hv_s; Am = A_s; Bm = B_s; }

  // latent slice for this model: ls[b*16+l] = sum_h hv[b*32+h] * Am[h*16+l]
  if (tid < 128) {
    int b = tid >> 4, l = tid & 15;
    float acc = 0.f;
#pragma unroll
    for (int h = 0; h < 32; ++h) acc = fmaf(hv[b * 32 + h], Am[h * 16 + l], acc);
    ls[tid] = acc;
  }
  __syncthreads();

  if (role == 4) {
    // Ws f32 -> Mpow slot 1 (bstride 9*16384)
    int e = ((blk - 1792) * 256 + tid) * 4;
    float4 v[16];
#pragma unroll
    for (int l = 0; l < 16; ++l)
      v[l] = *(const float4*)(Bm + (size_t)l * 16384 + e);
#pragma unroll 1
    for (int b = 0; b < 8; ++b) {
      float ax = 0.f, ay = 0.f, az = 0.f, aw = 0.f;
#pragma unroll
      for (int l = 0; l < 16; ++l) {
        float lv = ls[b * 16 + l];
        ax = fmaf(lv, v[l].x, ax);
        ay = fmaf(lv, v[l].y, ay);
        az = fmaf(lv, v[l].z, az);
        aw = fmaf(lv, v[l].w, aw);
      }
      *(float4*)(Ws1 + (size_t)b * 147456 + e) = make_float4(ax, ay, az, aw);
    }
    return;
  }

  // transposed bf16 W build: tile 32c x 32r, coalesced reads, LDS transpose
  int cc = tid & 31, rg = tid >> 5;
  int c = bx * 32 + cc;
  int r0 = by * 32 + rg * 4;
  size_t RC = (size_t)R * C;
  float bm[16][4];
#pragma unroll
  for (int l = 0; l < 16; ++l) {
    const float* p = Bm + (size_t)l * RC + (size_t)r0 * C + c;
#pragma unroll
    for (int j = 0; j < 4; ++j) bm[l][j] = p[(size_t)j * C];
  }
  int wc = tid >> 3, wrq = tid & 7;
#pragma unroll 1
  for (int b = 0; b < 8; ++b) {
    float a0 = 0.f, a1 = 0.f, a2 = 0.f, a3 = 0.f;
#pragma unroll
    for (int l = 0; l < 16; ++l) {
      float lv = ls[b * 16 + l];
      a0 = fmaf(lv, bm[l][0], a0);
      a1 = fmaf(lv, bm[l][1], a1);
      a2 = fmaf(lv, bm[l][2], a2);
      a3 = fmaf(lv, bm[l][3], a3);
    }
    __syncthreads();
    ushort2 p0, p1;
    p0.x = f2bf(a0); p0.y = f2bf(a1);
    p1.x = f2bf(a2); p1.y = f2bf(a3);
    *(ushort2*)&tile[cc][rg * 4] = p0;
    *(ushort2*)&tile[cc][rg * 4 + 2] = p1;
    __syncthreads();
    ushort4 v = *(const ushort4*)&tile[wc][wrq * 4];
    *(ushort4*)(outw + (size_t)b * bstride +
                (size_t)(bx * 32 + wc) * R + by * 32 + wrq * 4) = v;
  }
}

// ---------------- K4: bf16 MFMA GEMM, double-buffered LDS ----------------
// C[b] = A[b] @ BT[b]^T.  A: [M][K] bf16.  BT: [N][K] bf16.  BM=BN=128, BK=32.
// OUTM: 0 = f32 [M][N]; 1 = bf16 [M][N]; 2 = bf16 [N][M] (YT).
// EPI: v = (acc + D[m][n]) * win(n) before store.
template <int EPI, int OUTM>
__global__ __launch_bounds__(256) void mfma_gemm_kernel(
    const unsigned short* __restrict__ A,
    const unsigned short* __restrict__ BT,
    const float* __restrict__ D, int ldd,
    void* __restrict__ Cout,
    int M, int N, int K) {
  const int b = blockIdx.z;
  A  += (size_t)b * M * K;
  BT += (size_t)b * N * K;
  const int m0 = blockIdx.y * 128;
  const int n0 = blockIdx.x * 128;
  __shared__ __align__(16) unsigned short As[2][128][40];
  __shared__ __align__(16) unsigned short Bs[2][128][40];
  const int tid = threadIdx.x;
  const int lane = tid & 63, wave = tid >> 6;
  const int wr = (wave >> 1) * 64, wc = (wave & 1) * 64;
  const int l15 = lane & 15, g = lane >> 4;
  f32x4 acc[4][4];
#pragma unroll
  for (int i = 0; i < 4; ++i)
#pragma unroll
    for (int j = 0; j < 4; ++j)
#pragma unroll
      for (int r = 0; r < 4; ++r) acc[i][j][r] = 0.f;

  const int srow = tid >> 2, soct = tid & 3;
  const unsigned short* Ag = A + (size_t)(m0 + srow) * K + soct * 8;
  const unsigned short* Bg = BT + (size_t)(n0 + srow) * K + soct * 8;
  const size_t row64 = (size_t)64 * K;
  const int nt = K >> 5;

  bfrag av0 = *(const bfrag*)(Ag);
  bfrag av1 = *(const bfrag*)(Ag + row64);
  bfrag bv0 = *(const bfrag*)(Bg);
  bfrag bv1 = *(const bfrag*)(Bg + row64);

  int cur = 0;
#pragma unroll 1
  for (int t = 0; t < nt; ++t) {
    *(bfrag*)(&As[cur][srow][soct * 8]) = av0;
    *(bfrag*)(&As[cur][64 + srow][soct * 8]) = av1;
    *(bfrag*)(&Bs[cur][srow][soct * 8]) = bv0;
    *(bfrag*)(&Bs[cur][64 + srow][soct * 8]) = bv1;
    __syncthreads();
    if (t + 1 < nt) {
      const int k0 = (t + 1) << 5;
      av0 = *(const bfrag*)(Ag + k0);
      av1 = *(const bfrag*)(Ag + row64 + k0);
      bv0 = *(const bfrag*)(Bg + k0);
      bv1 = *(const bfrag*)(Bg + row64 + k0);
    }
    bfrag af[4], bf[4];
#pragma unroll
    for (int mi = 0; mi < 4; ++mi)
      af[mi] = *(const bfrag*)(&As[cur][wr + mi * 16 + l15][g * 8]);
#pragma unroll
    for (int nj = 0; nj < 4; ++nj)
      bf[nj] = *(const bfrag*)(&Bs[cur][wc + nj * 16 + l15][g * 8]);
#pragma unroll
    for (int mi = 0; mi < 4; ++mi)
#pragma unroll
      for (int nj = 0; nj < 4; ++nj)
        acc[mi][nj] = __builtin_amdgcn_mfma_f32_16x16x32_bf16(af[mi], bf[nj], acc[mi][nj], 0, 0, 0);
    cur ^= 1;
  }

  // epilogue: C/D frag mapping: col = l15, row = 4*g + r
  float* Cf = (float*)Cout + (size_t)b * M * N;
  unsigned short* Cb = (unsigned short*)Cout + (size_t)b * M * N;
  if (EPI) D += (size_t)b * M * ldd;
#pragma unroll
  for (int nj = 0; nj < 4; ++nj) {
    int n = n0 + wc + nj * 16 + l15;
    float win = 0.f;
    if (EPI) win = 0.5f - 0.5f * cosf(6.28318530717958647693f * (float)n / 1024.0f);
#pragma unroll
    for (int mi = 0; mi < 4; ++mi) {
      int mbase = m0 + wr + mi * 16 + 4 * g;
      float v[4];
#pragma unroll
      for (int r = 0; r < 4; ++r) {
        v[r] = acc[mi][nj][r];
        if (EPI) v[r] = (v[r] + D[(size_t)(mbase + r) * ldd + n]) * win;
      }
      if (OUTM == 2) {
        ushort4 o;
        o.x = f2bf(v[0]); o.y = f2bf(v[1]); o.z = f2bf(v[2]); o.w = f2bf(v[3]);
        *(ushort4*)(Cb + (size_t)n * M + mbase) = o;
      } else {
#pragma unroll
        for (int r = 0; r < 4; ++r) {
          if (OUTM == 1) Cb[(size_t)(mbase + r) * N + n] = f2bf(v[r]);
          else           Cf[(size_t)(mbase + r) * N + n] = v[r];
        }
      }
    }
  }
}

// ---------------- K5a: power step  M_{half+k} = M_k @ M_half ----------------
__global__ __launch_bounds__(256) void powers_kernel(float* __restrict__ Mpow, int half) {
  int z = blockIdx.x;
  int b = z / half, k = z - b * half + 1;
  const float* A = Mpow + ((size_t)b * 9 + k) * 16384;
  const float* Bm = Mpow + ((size_t)b * 9 + half) * 16384;
  float* C = Mpow + ((size_t)b * 9 + half + k) * 16384;
  __shared__ __align__(16) float As[16][132];
  __shared__ __align__(16) float Bs[16][132];
  int tid = threadIdx.x;
  int tx = tid & 15, ty = tid >> 4;
  float acc[8][8];
#pragma unroll
  for (int i = 0; i < 8; ++i)
#pragma unroll
    for (int j = 0; j < 8; ++j) acc[i][j] = 0.f;
  int ar = tid >> 1, ac = (tid & 1) * 8;
  int br = tid >> 4, bc = (tid & 15) * 8;
  for (int k0 = 0; k0 < 128; k0 += 16) {
    float4 a0 = *(const float4*)(A + (size_t)ar * 128 + k0 + ac);
    float4 a1 = *(const float4*)(A + (size_t)ar * 128 + k0 + ac + 4);
    float4 b0 = *(const float4*)(Bm + (size_t)(k0 + br) * 128 + bc);
    float4 b1 = *(const float4*)(Bm + (size_t)(k0 + br) * 128 + bc + 4);
    __syncthreads();
    As[ac + 0][ar] = a0.x; As[ac + 1][ar] = a0.y; As[ac + 2][ar] = a0.z; As[ac + 3][ar] = a0.w;
    As[ac + 4][ar] = a1.x; As[ac + 5][ar] = a1.y; As[ac + 6][ar] = a1.z; As[ac + 7][ar] = a1.w;
    *(float4*)(&Bs[br][bc]) = b0;
    *(float4*)(&Bs[br][bc + 4]) = b1;
    __syncthreads();
#pragma unroll
    for (int kk = 0; kk < 16; ++kk) {
      float4 av0 = *(const float4*)(&As[kk][ty * 8]);
      float4 av1 = *(const float4*)(&As[kk][ty * 8 + 4]);
      float4 bv0 = *(const float4*)(&Bs[kk][tx * 8]);
      float4 bv1 = *(const float4*)(&Bs[kk][tx * 8 + 4]);
      float aa[8] = {av0.x, av0.y, av0.z, av0.w, av1.x, av1.y, av1.z, av1.w};
      float bb[8] = {bv0.x, bv0.y, bv0.z, bv0.w, bv1.x, bv1.y, bv1.z, bv1.w};
#pragma unroll
      for (int i = 0; i < 8; ++i)
#pragma unroll
        for (int j = 0; j < 8; ++j) acc[i][j] = fmaf(aa[i], bb[j], acc[i][j]);
    }
  }
#pragma unroll
  for (int i = 0; i < 8; ++i) {
    *(float4*)(C + (size_t)(ty * 8 + i) * 128 + tx * 8) =
        make_float4(acc[i][0], acc[i][1], acc[i][2], acc[i][3]);
    *(float4*)(C + (size_t)(ty * 8 + i) * 128 + tx * 8 + 4) =
        make_float4(acc[i][4], acc[i][5], acc[i][6], acc[i][7]);
  }
}

// ---------------- K5b: chunk aggregates ----------------
__global__ __launch_bounds__(256) void ec_kernel(
    const float* __restrict__ Mpow, const float* __restrict__ PD,
    float* __restrict__ Ec) {
  int b = blockIdx.x >> 6, c = blockIdx.x & 63;
  int tid = threadIdx.x, t = tid & 127, dh = tid >> 7;
  __shared__ __align__(16) float Bus[7][128];
  __shared__ float red[128];
  const float* Bu = PD + (size_t)b * 512 * 1152 + 1024;
  for (int idx = tid; idx < 896; idx += 256)
    Bus[idx >> 7][idx & 127] = Bu[(size_t)(c * 8 + (idx >> 7)) * 1152 + (idx & 127)];
  __syncthreads();
  float acc = 0.f;
  const float* Mb = Mpow + (size_t)b * 9 * 16384;
  int d0 = dh * 64;
#pragma unroll
  for (int i = 0; i < 7; ++i) {
    const float* Mk = Mb + (size_t)(7 - i) * 16384 + t;
#pragma unroll 8
    for (int d = 0; d < 64; ++d)
      acc = fmaf(Bus[i][d0 + d], Mk[(size_t)(d0 + d) * 128], acc);
  }
  if (dh == 1) red[t] = acc;
  __syncthreads();
  if (dh == 0) {
    float tot = acc + red[t] + Bu[(size_t)(c * 8 + 7) * 1152 + t];
    Ec[((size_t)b * 64 + c) * 128 + t] = tot;
  }
}

// ---------------- K5c: serial chunk combine (Ec staged in LDS, dbuf state) ----------------
__global__ __launch_bounds__(128) void combine_kernel(
    const float* __restrict__ Mpow, const float* __restrict__ Ec,
    float* __restrict__ Hc) {
  int b = blockIdx.x, t = threadIdx.x;
  float w[128];
  const float* M8 = Mpow + ((size_t)b * 9 + 8) * 16384;
#pragma unroll
  for (int k = 0; k < 128; ++k) w[k] = M8[(size_t)k * 128 + t];
  __shared__ __align__(16) float ec_sh[64 * 128];
  const float* Ecb = Ec + (size_t)b * 8192;
#pragma unroll
  for (int i = 0; i < 16; ++i) {
    int idx = (t + i * 128) * 4;
    *(float4*)&ec_sh[idx] = *(const float4*)(Ecb + idx);
  }
  __shared__ __align__(16) float sh[2][128];
  sh[0][t] = 0.f;
  float* Hcb = Hc + (size_t)b * 8192;
  Hcb[t] = 0.f;
  __syncthreads();
  int cur = 0;
#pragma unroll 1
  for (int c = 0; c < 63; ++c) {
    float a0 = 0.f, a1 = 0.f, a2 = 0.f, a3 = 0.f;
#pragma unroll
    for (int k = 0; k < 128; k += 4) {
      float4 sv = *(const float4*)(&sh[cur][k]);
      a0 = fmaf(sv.x, w[k + 0], a0);
      a1 = fmaf(sv.y, w[k + 1], a1);
      a2 = fmaf(sv.z, w[k + 2], a2);
      a3 = fmaf(sv.w, w[k + 3], a3);
    }
    float hn = (a0 + a1) + (a2 + a3) + ec_sh[c * 128 + t];
    sh[cur ^ 1][t] = hn;
    Hcb[(c + 1) * 128 + t] = hn;
    __syncthreads();
    cur ^= 1;
  }
}

// ---------------- K5d: pass 2 (S2 out in bf16) ----------------
__global__ __launch_bounds__(256) void pass2_kernel(
    const float* __restrict__ Mpow, const float* __restrict__ PD,
    const float* __restrict__ Hc, unsigned short* __restrict__ S2) {
  int b = blockIdx.x >> 6, c = blockIdx.x & 63;
  int tid = threadIdx.x, t = tid & 127, dh = tid >> 7;
  __shared__ __align__(16) float Xs[15][128];
  __shared__ __align__(16) float red[8][128];
  const float* Bu = PD + (size_t)b * 512 * 1152 + 1024;
  for (int idx = tid; idx < 15 * 128; idx += 256) {
    int rr = idx >> 7, cc = idx & 127;
    float v = 0.f;
    if (rr == 7) v = Hc[((size_t)b * 64 + c) * 128 + cc];
    else if (rr > 7) v = Bu[(size_t)(c * 8 + rr - 8) * 1152 + cc];
    Xs[rr][cc] = v;
  }
  __syncthreads();
  float acc[8];
#pragma unroll
  for (int j = 0; j < 8; ++j) acc[j] = 0.f;
  const float* Mb = Mpow + (size_t)b * 9 * 16384;
  int d0 = dh * 64;
#pragma unroll 1
  for (int k = 1; k <= 8; ++k) {
    const float* Mk = Mb + (size_t)k * 16384 + t;
    const int xbase = 8 - k;
#pragma unroll 4
    for (int d4 = 0; d4 < 16; ++d4) {
      int d = d0 + d4 * 4;
      float m0 = Mk[(size_t)(d + 0) * 128];
      float m1 = Mk[(size_t)(d + 1) * 128];
      float m2 = Mk[(size_t)(d + 2) * 128];
      float m3 = Mk[(size_t)(d + 3) * 128];
#pragma unroll
      for (int j = 0; j < 8; ++j) {
        float4 xv = *(const float4*)(&Xs[xbase + j][d]);
        acc[j] = fmaf(xv.x, m0, acc[j]);
        acc[j] = fmaf(xv.y, m1, acc[j]);
        acc[j] = fmaf(xv.z, m2, acc[j]);
        acc[j] = fmaf(xv.w, m3, acc[j]);
      }
    }
  }
  if (dh == 1) {
#pragma unroll
    for (int j = 0; j < 8; ++j) red[j][t] = acc[j];
  }
  __syncthreads();
  if (dh == 0) {
    unsigned short* S2b = S2 + ((size_t)b * 512 + c * 8) * 128;
#pragma unroll
    for (int j = 0; j < 8; ++j)
      S2b[(size_t)j * 128 + t] = f2bf(acc[j] + red[j][t]);
  }
}

// ---------------- K7: OLA from YT -> sigT (both bf16, fully coalesced) ----------------
// sigT[b][r][p] = YT[b][r][p] + (p>0 ? YT[b][512+r][p-1] : 0)
__global__ void ola_kernel(const unsigned short* __restrict__ YT,
                           unsigned short* __restrict__ sigT) {
  int idx = blockIdx.x * 256 + threadIdx.x;   // 8*512*128 threads, 4 p's each
  int b = idx >> 16;
  int rem = idx & 65535;
  int r = rem >> 7, p4 = (rem & 127) * 4;
  const unsigned short* Y1 = YT + (size_t)b * 524288 + (size_t)r * 512 + p4;
  const unsigned short* Y2 = YT + (size_t)b * 524288 + (size_t)(512 + r) * 512 + p4 - 1;
  ushort4 t1 = *(const ushort4*)Y1;
  float o0 = bf2f(t1.x), o1 = bf2f(t1.y), o2 = bf2f(t1.z), o3 = bf2f(t1.w);
  if (p4 > 0) o0 += bf2f(Y2[0]);
  o1 += bf2f(Y2[1]);
  o2 += bf2f(Y2[2]);
  o3 += bf2f(Y2[3]);
  ushort4 o;
  o.x = f2bf(o0); o.y = f2bf(o1); o.z = f2bf(o2); o.w = f2bf(o3);
  *(ushort4*)(sigT + (size_t)b * 262144 + (size_t)r * 512 + p4) = o;
}

// ---------------- K8: conv = softmax + Toeplitz-on-the-fly + triangular MFMA GEMM ----------------
// out[b][q][r] = sum_{p<=q} imp[q-p] * sigT[r][p];  A generated from imp in LDS.
__global__ __launch_bounds__(256) void conv_mfma_kernel(
    const float* __restrict__ times,
    const unsigned short* __restrict__ sigT,   // [B][512][512]
    float* __restrict__ out) {                 // [B][512*512]
  const int b = blockIdx.z;
  const int m0 = blockIdx.y * 128;
  const int n0 = blockIdx.x * 128;
  __shared__ unsigned short imp_bf[512];
  __shared__ float red[256];
  __shared__ __align__(16) unsigned short As[2][128][40];
  __shared__ __align__(16) unsigned short Bs[2][128][40];
  const int tid = threadIdx.x;

  // softmax(times[b][0..511]) -> imp_bf (bf16)
  float v0 = times[b * 512 + tid], v1 = times[b * 512 + 256 + tid];
  red[tid] = fmaxf(v0, v1);
  __syncthreads();
  for (int s = 128; s > 0; s >>= 1) {
    if (tid < s) red[tid] = fmaxf(red[tid], red[tid + s]);
    __syncthreads();
  }
  float mx = red[0];
  __syncthreads();
  float e0 = expf(v0 - mx), e1 = expf(v1 - mx);
  red[tid] = e0 + e1;
  __syncthreads();
  for (int s = 128; s > 0; s >>= 1) {
    if (tid < s) red[tid] += red[tid + s];
    __syncthreads();
  }
  float inv = 1.f / red[0];
  imp_bf[tid] = f2bf(e0 * inv);
  imp_bf[256 + tid] = f2bf(e1 * inv);
  __syncthreads();

  const int lane = tid & 63, wave = tid >> 6;
  const int wr = (wave >> 1) * 64, wc = (wave & 1) * 64;
  const int l15 = lane & 15, g = lane >> 4;
  f32x4 acc[4][4];
#pragma unroll
  for (int i = 0; i < 4; ++i)
#pragma unroll
    for (int j = 0; j < 4; ++j)
#pragma unroll
      for (int r = 0; r < 4; ++r) acc[i][j][r] = 0.f;

  const int srow = tid >> 2, soct = tid & 3;
  const int q0 = m0 + srow, q1 = m0 + 64 + srow;
  const unsigned short* Bg = sigT + (size_t)b * 262144 + (size_t)(n0 + srow) * 512 + soct * 8;
  const size_t row64 = (size_t)64 * 512;
  const int nt = (m0 + 128) >> 5;   // triangular K bound

  bfrag bv0 = *(const bfrag*)(Bg);
  bfrag bv1 = *(const bfrag*)(Bg + row64);

  int cur = 0;
#pragma unroll 1
  for (int t = 0; t < nt; ++t) {
    const int k0 = t << 5;
    bfrag av0, av1;
#pragma unroll
    for (int j = 0; j < 8; ++j) {
      int p = k0 + soct * 8 + j;
      av0[j] = (p <= q0) ? (short)imp_bf[q0 - p] : (short)0;
      av1[j] = (p <= q1) ? (short)imp_bf[q1 - p] : (short)0;
    }
    *(bfrag*)(&As[cur][srow][soct * 8]) = av0;
    *(bfrag*)(&As[cur][64 + srow][soct * 8]) = av1;
    *(bfrag*)(&Bs[cur][srow][soct * 8]) = bv0;
    *(bfrag*)(&Bs[cur][64 + srow][soct * 8]) = bv1;
    __syncthreads();
    if (t + 1 < nt) {
      const int kn = (t + 1) << 5;
      bv0 = *(const bfrag*)(Bg + kn);
      bv1 = *(const bfrag*)(Bg + row64 + kn);
    }
    bfrag af[4], bf[4];
#pragma unroll
    for (int mi = 0; mi < 4; ++mi)
      af[mi] = *(const bfrag*)(&As[cur][wr + mi * 16 + l15][g * 8]);
#pragma unroll
    for (int nj = 0; nj < 4; ++nj)
      bf[nj] = *(const bfrag*)(&Bs[cur][wc + nj * 16 + l15][g * 8]);
#pragma unroll
    for (int mi = 0; mi < 4; ++mi)
#pragma unroll
      for (int nj = 0; nj < 4; ++nj)
        acc[mi][nj] = __builtin_amdgcn_mfma_f32_16x16x32_bf16(af[mi], bf[nj], acc[mi][nj], 0, 0, 0);
    cur ^= 1;
  }

  float* Cf = out + (size_t)b * 262144;
#pragma unroll
  for (int nj = 0; nj < 4; ++nj) {
    int n = n0 + wc + nj * 16 + l15;
#pragma unroll
    for (int mi = 0; mi < 4; ++mi) {
      int mbase = m0 + wr + mi * 16 + 4 * g;
#pragma unroll
      for (int r = 0; r < 4; ++r)
        Cf[(size_t)(mbase + r) * 512 + n] = acc[mi][nj][r];
    }
  }
}

// ---------------- launcher ----------------
extern "C" void kernel_launch(void* const* d_in, const int* in_sizes, int n_in,
                              void* d_out, int out_size, void* d_ws, size_t ws_size,
                              hipStream_t stream) {
  const float* control   = (const float*)d_in[0];
  const float* state_hv  = (const float*)d_in[1];
  const float* output_hv = (const float*)d_in[2];
  const float* input_hv  = (const float*)d_in[3];
  const float* direct_hv = (const float*)d_in[4];
  const float* proj_hv   = (const float*)d_in[5];
  const float* times     = (const float*)d_in[6];
  const float* A_proj   = (const float*)d_in[7];
  const float* B_proj   = (const float*)d_in[8];
  const float* A_state  = (const float*)d_in[9];
  const float* B_state  = (const float*)d_in[10];
  const float* A_input  = (const float*)d_in[11];
  const float* B_input  = (const float*)d_in[12];
  const float* A_output = (const float*)d_in[13];
  const float* B_output = (const float*)d_in[14];
  const float* A_direct = (const float*)d_in[15];
  const float* B_direct = (const float*)d_in[16];

  float* ws = (float*)d_ws;
  unsigned short* WpT   = (unsigned short*)(ws + OFF_WPT);
  unsigned short* WoT   = (unsigned short*)(ws + OFF_WOT);
  unsigned short* WdiT  = (unsigned short*)(ws + OFF_WDIT);
  unsigned short* ctrlT = (unsigned short*)(ws + OFF_CTRLT);
  unsigned short* proj  = (unsigned short*)(ws + OFF_PROJ);
  float* projD = ws + OFF_PROJD;
  unsigned short* S2 = (unsigned short*)(ws + OFF_S2);
  float* Mpow = ws + OFF_MPOW;
  float* Ec   = ws + OFF_EC;
  float* Hc   = ws + OFF_HC;
  unsigned short* YT   = (unsigned short*)(ws + OFF_Y);
  unsigned short* sigT = (unsigned short*)(ws + OFF_SIG);
  float* out  = (float*)d_out;

  // K1: all weight builds + latents + ctrl^2 transpose in one launch
  megabuild_kernel<<<3856, 256, 0, stream>>>(
      proj_hv, state_hv, input_hv, output_hv, direct_hv,
      A_proj, A_state, A_input, A_output, A_direct,
      B_proj, B_state, B_input, B_output, B_direct,
      control, WpT, WoT, WdiT, Mpow + 16384, ctrlT);

  // proj = ctrlT @ WpT^T  (M=512,N=1024,K=512) -> bf16
  mfma_gemm_kernel<0, 1><<<dim3(8, 4, 8), 256, 0, stream>>>(
      ctrlT, WpT, nullptr, 0, proj, 512, 1024, 512);

  // projD = proj @ WdiT^T  (M=512,N=1152,K=1024) -> f32
  mfma_gemm_kernel<0, 0><<<dim3(9, 4, 8), 256, 0, stream>>>(
      proj, WdiT, nullptr, 0, projD, 512, 1152, 1024);

  // chunked scan
  powers_kernel<<<8, 256, 0, stream>>>(Mpow, 1);
  powers_kernel<<<16, 256, 0, stream>>>(Mpow, 2);
  powers_kernel<<<32, 256, 0, stream>>>(Mpow, 4);
  ec_kernel<<<512, 256, 0, stream>>>(Mpow, projD, Ec);
  combine_kernel<<<8, 128, 0, stream>>>(Mpow, Ec, Hc);
  pass2_kernel<<<512, 256, 0, stream>>>(Mpow, projD, Hc, S2);

  // YT = ((S2 @ WoT^T + direct) * win)^T  (M=512,N=1024,K=128) -> bf16 [N][M]
  mfma_gemm_kernel<1, 2><<<dim3(8, 4, 8), 256, 0, stream>>>(
      S2, WoT, projD, 1152, YT, 512, 1024, 128);

  // OLA: sigT[r][p] = YT[r][p] + YT[512+r][p-1]
  ola_kernel<<<2048, 256, 0, stream>>>(YT, sigT);

  // conv: softmax + Toeplitz-A on the fly + triangular MFMA GEMM -> out
  conv_mfma_kernel<<<dim3(4, 4, 8), 256, 0, stream>>>(times, sigT, out);
}

// Round 7
// 239.794 us; speedup vs baseline: 5.1143x; 1.0016x over previous
//
#include <hip/hip_runtime.h>
#include <math.h>

// Problem constants
//  B=8, CTX=512, N_FRAMES=512, IN_DIM=1024, ST_DIM=128, HOP=512, N_SAMPLES=262144
//  HD=32, HL=16
// Scan parallelization: T=8 frames/chunk, C=64 chunks.
// 12 launches: megabuild, proj, projD, powers x3, ec, combine, pass2, Y(->YT),
// ola, conv(softmax+Toeplitz fused).

typedef __attribute__((ext_vector_type(8))) short bfrag;   // 8 bf16 = 4 VGPRs
typedef __attribute__((ext_vector_type(4))) float f32x4;

__device__ inline unsigned short f2bf(float f) {
  unsigned int u = __float_as_uint(f);
  unsigned int r = (u + 0x7fff + ((u >> 16) & 1)) >> 16;   // RNE
  return (unsigned short)r;
}
__device__ inline float bf2f(unsigned short u) {
  return __uint_as_float(((unsigned int)u) << 16);
}

// ---------------- workspace layout (float offsets) ----------------
static const size_t OFF_WPT   = 139264;     // WpT bf16 [8][1024][512]
static const size_t OFF_WOT   = 2236416;    // WoT bf16 [8][1024][128]
static const size_t OFF_WDIT  = 2760704;    // WdiT bf16 [8][1152][1024]
static const size_t OFF_CTRLT = 7479296;    // ctrlT bf16 [8][512][512]
static const size_t OFF_PROJ  = 8527872;    // proj bf16 [8][512][1024]
static const size_t OFF_PROJD = 10625024;   // projD f32 [8][512][1152]
static const size_t OFF_S2    = 15343616;   // S2 bf16 [8][512][128]
static const size_t OFF_MPOW  = 15605760;   // f32 8*9*16384 (slot1 = Ws)
static const size_t OFF_EC    = 16785408;   // 65,536
static const size_t OFF_HC    = 16850944;   // 65,536
static const size_t OFF_Y     = 16916480;   // YT bf16 [8][1024][512]
static const size_t OFF_SIG   = 21110784;   // sigT bf16 [8][512][512]

// ---------------- K1: mega-build ----------------
// blocks [0,512)      WpT   (R=512,  C=1024, grid 32x16)  model=proj
// blocks [512,1536)   WdT   (R=1024, C=1024, grid 32x32)  model=direct
// blocks [1536,1664)  WiT   (R=1024, C=128,  grid 4x32)   model=input
// blocks [1664,1792)  WoT   (R=128,  C=1024, grid 32x4)   model=output
// blocks [1792,1808)  Ws f32 -> Mpow slot 1               model=state
// blocks [1808,3856)  transpose_sq: ctrlT[b,f,c] = control[b,c,f]^2 (bf16)
__global__ __launch_bounds__(256) void megabuild_kernel(
    const float* __restrict__ hv_p, const float* __restrict__ hv_s,
    const float* __restrict__ hv_i, const float* __restrict__ hv_o,
    const float* __restrict__ hv_d,
    const float* __restrict__ A_p, const float* __restrict__ A_s,
    const float* __restrict__ A_i, const float* __restrict__ A_o,
    const float* __restrict__ A_d,
    const float* __restrict__ B_p, const float* __restrict__ B_s,
    const float* __restrict__ B_i, const float* __restrict__ B_o,
    const float* __restrict__ B_d,
    const float* __restrict__ control,
    unsigned short* __restrict__ WpT, unsigned short* __restrict__ WoT,
    unsigned short* __restrict__ WdiT, float* __restrict__ Ws1,
    unsigned short* __restrict__ ctrlT) {
  __shared__ float ls[128];
  __shared__ unsigned short tile[8][32][36];   // [b][c][r] bf16, 18 KB
  __shared__ float ttile[32][33];
  const int blk = blockIdx.x;
  const int tid = threadIdx.x;

  if (blk >= 1808) {
    // ---- transpose+square role ----
    int z = blk - 1808;
    int b = z >> 8;
    int c0 = (z & 15) * 32, f0 = ((z >> 4) & 15) * 32;
    int tx = tid & 31, ty = tid >> 5;   // 32 x 8
    const float* inb = control + (size_t)b * 512 * 512;
    unsigned short* outb = ctrlT + (size_t)b * 512 * 512;
#pragma unroll
    for (int i = 0; i < 4; ++i) {
      float v = inb[(size_t)(c0 + ty + i * 8) * 512 + f0 + tx];
      ttile[ty + i * 8][tx] = v * v;
    }
    __syncthreads();
#pragma unroll
    for (int i = 0; i < 4; ++i)
      outb[(size_t)(f0 + ty + i * 8) * 512 + c0 + tx] = f2bf(ttile[tx][ty + i * 8]);
    return;
  }

  // ---- weight-build roles: select model ----
  const float* hv; const float* Am; const float* Bm;
  unsigned short* outw = nullptr; int R = 0, C = 0; size_t bstride = 0; int bx = 0, by = 0;
  int role;   // 0..3 = WT builds, 4 = Ws f32
  if (blk < 512)        { role = 0; hv = hv_p; Am = A_p; Bm = B_p; outw = WpT;  R = 512;  C = 1024; bstride = 524288;  bx = blk & 31;           by = blk >> 5; }
  else if (blk < 1536)  { role = 1; hv = hv_d; Am = A_d; Bm = B_d; outw = WdiT; R = 1024; C = 1024; bstride = 1179648; bx = (blk - 512) & 31;   by = (blk - 512) >> 5; }
  else if (blk < 1664)  { role = 2; hv = hv_i; Am = A_i; Bm = B_i; outw = WdiT + 1024 * 1024; R = 1024; C = 128; bstride = 1179648; bx = (blk - 1536) & 3; by = (blk - 1536) >> 2; }
  else if (blk < 1792)  { role = 3; hv = hv_o; Am = A_o; Bm = B_o; outw = WoT;  R = 128;  C = 1024; bstride = 131072;  bx = (blk - 1664) & 31;  by = (blk - 1664) >> 5; }
  else                  { role = 4; hv = hv_s; Am = A_s; Bm = B_s; }

  // latent slice for this model: ls[b*16+l] = sum_h hv[b*32+h] * Am[h*16+l]
  if (tid < 128) {
    int b = tid >> 4, l = tid & 15;
    float acc = 0.f;
#pragma unroll
    for (int h = 0; h < 32; ++h) acc = fmaf(hv[b * 32 + h], Am[h * 16 + l], acc);
    ls[tid] = acc;
  }

  if (role == 4) {
    __syncthreads();
    // Ws f32 -> Mpow slot 1 (bstride 9*16384)
    int e = ((blk - 1792) * 256 + tid) * 4;
    float4 v[16];
#pragma unroll
    for (int l = 0; l < 16; ++l)
      v[l] = *(const float4*)(Bm + (size_t)l * 16384 + e);
#pragma unroll 1
    for (int b = 0; b < 8; ++b) {
      float ax = 0.f, ay = 0.f, az = 0.f, aw = 0.f;
#pragma unroll
      for (int l = 0; l < 16; ++l) {
        float lv = ls[b * 16 + l];
        ax = fmaf(lv, v[l].x, ax);
        ay = fmaf(lv, v[l].y, ay);
        az = fmaf(lv, v[l].z, az);
        aw = fmaf(lv, v[l].w, aw);
      }
      *(float4*)(Ws1 + (size_t)b * 147456 + e) = make_float4(ax, ay, az, aw);
    }
    return;
  }

  // transposed bf16 W build: tile 32c x 32r, float4 reads, batched LDS transpose.
  // read/compute role: thread owns r = by*32 + (tid>>3), c = bx*32 + (tid&7)*4 (+4 cols)
  const int rl = tid >> 3;            // 0..31
  const int c4 = (tid & 7) * 4;       // 0,4,...,28
  const size_t RC = (size_t)R * C;
  const float* Bp = Bm + (size_t)(by * 32 + rl) * C + bx * 32 + c4;
  float4 bm4[16];
#pragma unroll
  for (int l = 0; l < 16; ++l)
    bm4[l] = *(const float4*)(Bp + (size_t)l * RC);
  __syncthreads();   // ls ready

#pragma unroll 1
  for (int b = 0; b < 8; ++b) {
    float a0 = 0.f, a1 = 0.f, a2 = 0.f, a3 = 0.f;
#pragma unroll
    for (int l = 0; l < 16; ++l) {
      float lv = ls[b * 16 + l];
      a0 = fmaf(lv, bm4[l].x, a0);
      a1 = fmaf(lv, bm4[l].y, a1);
      a2 = fmaf(lv, bm4[l].z, a2);
      a3 = fmaf(lv, bm4[l].w, a3);
    }
    tile[b][c4 + 0][rl] = f2bf(a0);
    tile[b][c4 + 1][rl] = f2bf(a1);
    tile[b][c4 + 2][rl] = f2bf(a2);
    tile[b][c4 + 3][rl] = f2bf(a3);
  }
  __syncthreads();

  // write role: 8 lanes cover one c-row (64B); wave writes 8 rows
  const int wc = tid >> 3, wrq = tid & 7;
  unsigned short* ob = outw + (size_t)(bx * 32 + wc) * R + by * 32 + wrq * 4;
#pragma unroll 1
  for (int b = 0; b < 8; ++b) {
    ushort4 v = *(const ushort4*)&tile[b][wc][wrq * 4];
    *(ushort4*)(ob + (size_t)b * bstride) = v;
  }
}

// ---------------- K4: bf16 MFMA GEMM, double-buffered LDS ----------------
// C[b] = A[b] @ BT[b]^T.  A: [M][K] bf16.  BT: [N][K] bf16.  BM=BN=128, BK=32.
// OUTM: 0 = f32 [M][N]; 1 = bf16 [M][N]; 2 = bf16 [N][M] (YT).
// EPI: v = (acc + D[m][n]) * win(n) before store.
template <int EPI, int OUTM>
__global__ __launch_bounds__(256) void mfma_gemm_kernel(
    const unsigned short* __restrict__ A,
    const unsigned short* __restrict__ BT,
    const float* __restrict__ D, int ldd,
    void* __restrict__ Cout,
    int M, int N, int K) {
  const int b = blockIdx.z;
  A  += (size_t)b * M * K;
  BT += (size_t)b * N * K;
  const int m0 = blockIdx.y * 128;
  const int n0 = blockIdx.x * 128;
  __shared__ __align__(16) unsigned short As[2][128][40];
  __shared__ __align__(16) unsigned short Bs[2][128][40];
  const int tid = threadIdx.x;
  const int lane = tid & 63, wave = tid >> 6;
  const int wr = (wave >> 1) * 64, wc = (wave & 1) * 64;
  const int l15 = lane & 15, g = lane >> 4;
  f32x4 acc[4][4];
#pragma unroll
  for (int i = 0; i < 4; ++i)
#pragma unroll
    for (int j = 0; j < 4; ++j)
#pragma unroll
      for (int r = 0; r < 4; ++r) acc[i][j][r] = 0.f;

  const int srow = tid >> 2, soct = tid & 3;
  const unsigned short* Ag = A + (size_t)(m0 + srow) * K + soct * 8;
  const unsigned short* Bg = BT + (size_t)(n0 + srow) * K + soct * 8;
  const size_t row64 = (size_t)64 * K;
  const int nt = K >> 5;

  bfrag av0 = *(const bfrag*)(Ag);
  bfrag av1 = *(const bfrag*)(Ag + row64);
  bfrag bv0 = *(const bfrag*)(Bg);
  bfrag bv1 = *(const bfrag*)(Bg + row64);

  int cur = 0;
#pragma unroll 1
  for (int t = 0; t < nt; ++t) {
    *(bfrag*)(&As[cur][srow][soct * 8]) = av0;
    *(bfrag*)(&As[cur][64 + srow][soct * 8]) = av1;
    *(bfrag*)(&Bs[cur][srow][soct * 8]) = bv0;
    *(bfrag*)(&Bs[cur][64 + srow][soct * 8]) = bv1;
    __syncthreads();
    if (t + 1 < nt) {
      const int k0 = (t + 1) << 5;
      av0 = *(const bfrag*)(Ag + k0);
      av1 = *(const bfrag*)(Ag + row64 + k0);
      bv0 = *(const bfrag*)(Bg + k0);
      bv1 = *(const bfrag*)(Bg + row64 + k0);
    }
    bfrag af[4], bf[4];
#pragma unroll
    for (int mi = 0; mi < 4; ++mi)
      af[mi] = *(const bfrag*)(&As[cur][wr + mi * 16 + l15][g * 8]);
#pragma unroll
    for (int nj = 0; nj < 4; ++nj)
      bf[nj] = *(const bfrag*)(&Bs[cur][wc + nj * 16 + l15][g * 8]);
#pragma unroll
    for (int mi = 0; mi < 4; ++mi)
#pragma unroll
      for (int nj = 0; nj < 4; ++nj)
        acc[mi][nj] = __builtin_amdgcn_mfma_f32_16x16x32_bf16(af[mi], bf[nj], acc[mi][nj], 0, 0, 0);
    cur ^= 1;
  }

  // epilogue: C/D frag mapping: col = l15, row = 4*g + r
  float* Cf = (float*)Cout + (size_t)b * M * N;
  unsigned short* Cb = (unsigned short*)Cout + (size_t)b * M * N;
  if (EPI) D += (size_t)b * M * ldd;
#pragma unroll
  for (int nj = 0; nj < 4; ++nj) {
    int n = n0 + wc + nj * 16 + l15;
    float win = 0.f;
    if (EPI) win = 0.5f - 0.5f * cosf(6.28318530717958647693f * (float)n / 1024.0f);
#pragma unroll
    for (int mi = 0; mi < 4; ++mi) {
      int mbase = m0 + wr + mi * 16 + 4 * g;
      float v[4];
#pragma unroll
      for (int r = 0; r < 4; ++r) {
        v[r] = acc[mi][nj][r];
        if (EPI) v[r] = (v[r] + D[(size_t)(mbase + r) * ldd + n]) * win;
      }
      if (OUTM == 2) {
        ushort4 o;
        o.x = f2bf(v[0]); o.y = f2bf(v[1]); o.z = f2bf(v[2]); o.w = f2bf(v[3]);
        *(ushort4*)(Cb + (size_t)n * M + mbase) = o;
      } else {
#pragma unroll
        for (int r = 0; r < 4; ++r) {
          if (OUTM == 1) Cb[(size_t)(mbase + r) * N + n] = f2bf(v[r]);
          else           Cf[(size_t)(mbase + r) * N + n] = v[r];
        }
      }
    }
  }
}

// ---------------- K5a: power step  M_{half+k} = M_k @ M_half ----------------
__global__ __launch_bounds__(256) void powers_kernel(float* __restrict__ Mpow, int half) {
  int z = blockIdx.x;
  int b = z / half, k = z - b * half + 1;
  const float* A = Mpow + ((size_t)b * 9 + k) * 16384;
  const float* Bm = Mpow + ((size_t)b * 9 + half) * 16384;
  float* C = Mpow + ((size_t)b * 9 + half + k) * 16384;
  __shared__ __align__(16) float As[16][132];
  __shared__ __align__(16) float Bs[16][132];
  int tid = threadIdx.x;
  int tx = tid & 15, ty = tid >> 4;
  float acc[8][8];
#pragma unroll
  for (int i = 0; i < 8; ++i)
#pragma unroll
    for (int j = 0; j < 8; ++j) acc[i][j] = 0.f;
  int ar = tid >> 1, ac = (tid & 1) * 8;
  int br = tid >> 4, bc = (tid & 15) * 8;
  for (int k0 = 0; k0 < 128; k0 += 16) {
    float4 a0 = *(const float4*)(A + (size_t)ar * 128 + k0 + ac);
    float4 a1 = *(const float4*)(A + (size_t)ar * 128 + k0 + ac + 4);
    float4 b0 = *(const float4*)(Bm + (size_t)(k0 + br) * 128 + bc);
    float4 b1 = *(const float4*)(Bm + (size_t)(k0 + br) * 128 + bc + 4);
    __syncthreads();
    As[ac + 0][ar] = a0.x; As[ac + 1][ar] = a0.y; As[ac + 2][ar] = a0.z; As[ac + 3][ar] = a0.w;
    As[ac + 4][ar] = a1.x; As[ac + 5][ar] = a1.y; As[ac + 6][ar] = a1.z; As[ac + 7][ar] = a1.w;
    *(float4*)(&Bs[br][bc]) = b0;
    *(float4*)(&Bs[br][bc + 4]) = b1;
    __syncthreads();
#pragma unroll
    for (int kk = 0; kk < 16; ++kk) {
      float4 av0 = *(const float4*)(&As[kk][ty * 8]);
      float4 av1 = *(const float4*)(&As[kk][ty * 8 + 4]);
      float4 bv0 = *(const float4*)(&Bs[kk][tx * 8]);
      float4 bv1 = *(const float4*)(&Bs[kk][tx * 8 + 4]);
      float aa[8] = {av0.x, av0.y, av0.z, av0.w, av1.x, av1.y, av1.z, av1.w};
      float bb[8] = {bv0.x, bv0.y, bv0.z, bv0.w, bv1.x, bv1.y, bv1.z, bv1.w};
#pragma unroll
      for (int i = 0; i < 8; ++i)
#pragma unroll
        for (int j = 0; j < 8; ++j) acc[i][j] = fmaf(aa[i], bb[j], acc[i][j]);
    }
  }
#pragma unroll
  for (int i = 0; i < 8; ++i) {
    *(float4*)(C + (size_t)(ty * 8 + i) * 128 + tx * 8) =
        make_float4(acc[i][0], acc[i][1], acc[i][2], acc[i][3]);
    *(float4*)(C + (size_t)(ty * 8 + i) * 128 + tx * 8 + 4) =
        make_float4(acc[i][4], acc[i][5], acc[i][6], acc[i][7]);
  }
}

// ---------------- K5b: chunk aggregates ----------------
__global__ __launch_bounds__(256) void ec_kernel(
    const float* __restrict__ Mpow, const float* __restrict__ PD,
    float* __restrict__ Ec) {
  int b = blockIdx.x >> 6, c = blockIdx.x & 63;
  int tid = threadIdx.x, t = tid & 127, dh = tid >> 7;
  __shared__ __align__(16) float Bus[7][128];
  __shared__ float red[128];
  const float* Bu = PD + (size_t)b * 512 * 1152 + 1024;
  for (int idx = tid; idx < 896; idx += 256)
    Bus[idx >> 7][idx & 127] = Bu[(size_t)(c * 8 + (idx >> 7)) * 1152 + (idx & 127)];
  __syncthreads();
  float acc = 0.f;
  const float* Mb = Mpow + (size_t)b * 9 * 16384;
  int d0 = dh * 64;
#pragma unroll
  for (int i = 0; i < 7; ++i) {
    const float* Mk = Mb + (size_t)(7 - i) * 16384 + t;
#pragma unroll 8
    for (int d = 0; d < 64; ++d)
      acc = fmaf(Bus[i][d0 + d], Mk[(size_t)(d0 + d) * 128], acc);
  }
  if (dh == 1) red[t] = acc;
  __syncthreads();
  if (dh == 0) {
    float tot = acc + red[t] + Bu[(size_t)(c * 8 + 7) * 1152 + t];
    Ec[((size_t)b * 64 + c) * 128 + t] = tot;
  }
}

// ---------------- K5c: serial chunk combine (Ec staged in LDS, dbuf state) ----------------
__global__ __launch_bounds__(128) void combine_kernel(
    const float* __restrict__ Mpow, const float* __restrict__ Ec,
    float* __restrict__ Hc) {
  int b = blockIdx.x, t = threadIdx.x;
  float w[128];
  const float* M8 = Mpow + ((size_t)b * 9 + 8) * 16384;
#pragma unroll
  for (int k = 0; k < 128; ++k) w[k] = M8[(size_t)k * 128 + t];
  __shared__ __align__(16) float ec_sh[64 * 128];
  const float* Ecb = Ec + (size_t)b * 8192;
#pragma unroll
  for (int i = 0; i < 16; ++i) {
    int idx = (t + i * 128) * 4;
    *(float4*)&ec_sh[idx] = *(const float4*)(Ecb + idx);
  }
  __shared__ __align__(16) float sh[2][128];
  sh[0][t] = 0.f;
  float* Hcb = Hc + (size_t)b * 8192;
  Hcb[t] = 0.f;
  __syncthreads();
  int cur = 0;
#pragma unroll 1
  for (int c = 0; c < 63; ++c) {
    float a0 = 0.f, a1 = 0.f, a2 = 0.f, a3 = 0.f;
#pragma unroll
    for (int k = 0; k < 128; k += 4) {
      float4 sv = *(const float4*)(&sh[cur][k]);
      a0 = fmaf(sv.x, w[k + 0], a0);
      a1 = fmaf(sv.y, w[k + 1], a1);
      a2 = fmaf(sv.z, w[k + 2], a2);
      a3 = fmaf(sv.w, w[k + 3], a3);
    }
    float hn = (a0 + a1) + (a2 + a3) + ec_sh[c * 128 + t];
    sh[cur ^ 1][t] = hn;
    Hcb[(c + 1) * 128 + t] = hn;
    __syncthreads();
    cur ^= 1;
  }
}

// ---------------- K5d: pass 2 (S2 out in bf16) ----------------
__global__ __launch_bounds__(256) void pass2_kernel(
    const float* __restrict__ Mpow, const float* __restrict__ PD,
    const float* __restrict__ Hc, unsigned short* __restrict__ S2) {
  int b = blockIdx.x >> 6, c = blockIdx.x & 63;
  int tid = threadIdx.x, t = tid & 127, dh = tid >> 7;
  __shared__ __align__(16) float Xs[15][128];
  __shared__ __align__(16) float red[8][128];
  const float* Bu = PD + (size_t)b * 512 * 1152 + 1024;
  for (int idx = tid; idx < 15 * 128; idx += 256) {
    int rr = idx >> 7, cc = idx & 127;
    float v = 0.f;
    if (rr == 7) v = Hc[((size_t)b * 64 + c) * 128 + cc];
    else if (rr > 7) v = Bu[(size_t)(c * 8 + rr - 8) * 1152 + cc];
    Xs[rr][cc] = v;
  }
  __syncthreads();
  float acc[8];
#pragma unroll
  for (int j = 0; j < 8; ++j) acc[j] = 0.f;
  const float* Mb = Mpow + (size_t)b * 9 * 16384;
  int d0 = dh * 64;
#pragma unroll 1
  for (int k = 1; k <= 8; ++k) {
    const float* Mk = Mb + (size_t)k * 16384 + t;
    const int xbase = 8 - k;
#pragma unroll 4
    for (int d4 = 0; d4 < 16; ++d4) {
      int d = d0 + d4 * 4;
      float m0 = Mk[(size_t)(d + 0) * 128];
      float m1 = Mk[(size_t)(d + 1) * 128];
      float m2 = Mk[(size_t)(d + 2) * 128];
      float m3 = Mk[(size_t)(d + 3) * 128];
#pragma unroll
      for (int j = 0; j < 8; ++j) {
        float4 xv = *(const float4*)(&Xs[xbase + j][d]);
        acc[j] = fmaf(xv.x, m0, acc[j]);
        acc[j] = fmaf(xv.y, m1, acc[j]);
        acc[j] = fmaf(xv.z, m2, acc[j]);
        acc[j] = fmaf(xv.w, m3, acc[j]);
      }
    }
  }
  if (dh == 1) {
#pragma unroll
    for (int j = 0; j < 8; ++j) red[j][t] = acc[j];
  }
  __syncthreads();
  if (dh == 0) {
    unsigned short* S2b = S2 + ((size_t)b * 512 + c * 8) * 128;
#pragma unroll
    for (int j = 0; j < 8; ++j)
      S2b[(size_t)j * 128 + t] = f2bf(acc[j] + red[j][t]);
  }
}

// ---------------- K7: OLA from YT -> sigT (both bf16, fully coalesced) ----------------
// sigT[b][r][p] = YT[b][r][p] + (p>0 ? YT[b][512+r][p-1] : 0)
__global__ void ola_kernel(const unsigned short* __restrict__ YT,
                           unsigned short* __restrict__ sigT) {
  int idx = blockIdx.x * 256 + threadIdx.x;   // 8*512*128 threads, 4 p's each
  int b = idx >> 16;
  int rem = idx & 65535;
  int r = rem >> 7, p4 = (rem & 127) * 4;
  const unsigned short* Y1 = YT + (size_t)b * 524288 + (size_t)r * 512 + p4;
  const unsigned short* Y2 = YT + (size_t)b * 524288 + (size_t)(512 + r) * 512 + p4 - 1;
  ushort4 t1 = *(const ushort4*)Y1;
  float o0 = bf2f(t1.x), o1 = bf2f(t1.y), o2 = bf2f(t1.z), o3 = bf2f(t1.w);
  if (p4 > 0) o0 += bf2f(Y2[0]);
  o1 += bf2f(Y2[1]);
  o2 += bf2f(Y2[2]);
  o3 += bf2f(Y2[3]);
  ushort4 o;
  o.x = f2bf(o0); o.y = f2bf(o1); o.z = f2bf(o2); o.w = f2bf(o3);
  *(ushort4*)(sigT + (size_t)b * 262144 + (size_t)r * 512 + p4) = o;
}

// ---------------- K8: conv = softmax + Toeplitz-on-the-fly + triangular MFMA GEMM ----------------
__global__ __launch_bounds__(256) void conv_mfma_kernel(
    const float* __restrict__ times,
    const unsigned short* __restrict__ sigT,   // [B][512][512]
    float* __restrict__ out) {                 // [B][512*512]
  const int b = blockIdx.z;
  const int m0 = blockIdx.y * 128;
  const int n0 = blockIdx.x * 128;
  __shared__ unsigned short imp_bf[512];
  __shared__ float red[256];
  __shared__ __align__(16) unsigned short As[2][128][40];
  __shared__ __align__(16) unsigned short Bs[2][128][40];
  const int tid = threadIdx.x;

  // softmax(times[b][0..511]) -> imp_bf (bf16)
  float v0 = times[b * 512 + tid], v1 = times[b * 512 + 256 + tid];
  red[tid] = fmaxf(v0, v1);
  __syncthreads();
  for (int s = 128; s > 0; s >>= 1) {
    if (tid < s) red[tid] = fmaxf(red[tid], red[tid + s]);
    __syncthreads();
  }
  float mx = red[0];
  __syncthreads();
  float e0 = expf(v0 - mx), e1 = expf(v1 - mx);
  red[tid] = e0 + e1;
  __syncthreads();
  for (int s = 128; s > 0; s >>= 1) {
    if (tid < s) red[tid] += red[tid + s];
    __syncthreads();
  }
  float inv = 1.f / red[0];
  imp_bf[tid] = f2bf(e0 * inv);
  imp_bf[256 + tid] = f2bf(e1 * inv);
  __syncthreads();

  const int lane = tid & 63, wave = tid >> 6;
  const int wr = (wave >> 1) * 64, wc = (wave & 1) * 64;
  const int l15 = lane & 15, g = lane >> 4;
  f32x4 acc[4][4];
#pragma unroll
  for (int i = 0; i < 4; ++i)
#pragma unroll
    for (int j = 0; j < 4; ++j)
#pragma unroll
      for (int r = 0; r < 4; ++r) acc[i][j][r] = 0.f;

  const int srow = tid >> 2, soct = tid & 3;
  const int q0 = m0 + srow, q1 = m0 + 64 + srow;
  const unsigned short* Bg = sigT + (size_t)b * 262144 + (size_t)(n0 + srow) * 512 + soct * 8;
  const size_t row64 = (size_t)64 * 512;
  const int nt = (m0 + 128) >> 5;   // triangular K bound

  bfrag bv0 = *(const bfrag*)(Bg);
  bfrag bv1 = *(const bfrag*)(Bg + row64);

  int cur = 0;
#pragma unroll 1
  for (int t = 0; t < nt; ++t) {
    const int k0 = t << 5;
    bfrag av0, av1;
#pragma unroll
    for (int j = 0; j < 8; ++j) {
      int p = k0 + soct * 8 + j;
      av0[j] = (p <= q0) ? (short)imp_bf[q0 - p] : (short)0;
      av1[j] = (p <= q1) ? (short)imp_bf[q1 - p] : (short)0;
    }
    *(bfrag*)(&As[cur][srow][soct * 8]) = av0;
    *(bfrag*)(&As[cur][64 + srow][soct * 8]) = av1;
    *(bfrag*)(&Bs[cur][srow][soct * 8]) = bv0;
    *(bfrag*)(&Bs[cur][64 + srow][soct * 8]) = bv1;
    __syncthreads();
    if (t + 1 < nt) {
      const int kn = (t + 1) << 5;
      bv0 = *(const bfrag*)(Bg + kn);
      bv1 = *(const bfrag*)(Bg + row64 + kn);
    }
    bfrag af[4], bf[4];
#pragma unroll
    for (int mi = 0; mi < 4; ++mi)
      af[mi] = *(const bfrag*)(&As[cur][wr + mi * 16 + l15][g * 8]);
#pragma unroll
    for (int nj = 0; nj < 4; ++nj)
      bf[nj] = *(const bfrag*)(&Bs[cur][wc + nj * 16 + l15][g * 8]);
#pragma unroll
    for (int mi = 0; mi < 4; ++mi)
#pragma unroll
      for (int nj = 0; nj < 4; ++nj)
        acc[mi][nj] = __builtin_amdgcn_mfma_f32_16x16x32_bf16(af[mi], bf[nj], acc[mi][nj], 0, 0, 0);
    cur ^= 1;
  }

  float* Cf = out + (size_t)b * 262144;
#pragma unroll
  for (int nj = 0; nj < 4; ++nj) {
    int n = n0 + wc + nj * 16 + l15;
#pragma unroll
    for (int mi = 0; mi < 4; ++mi) {
      int mbase = m0 + wr + mi * 16 + 4 * g;
#pragma unroll
      for (int r = 0; r < 4; ++r)
        Cf[(size_t)(mbase + r) * 512 + n] = acc[mi][nj][r];
    }
  }
}

// ---------------- launcher ----------------
extern "C" void kernel_launch(void* const* d_in, const int* in_sizes, int n_in,
                              void* d_out, int out_size, void* d_ws, size_t ws_size,
                              hipStream_t stream) {
  const float* control   = (const float*)d_in[0];
  const float* state_hv  = (const float*)d_in[1];
  const float* output_hv = (const float*)d_in[2];
  const float* input_hv  = (const float*)d_in[3];
  const float* direct_hv = (const float*)d_in[4];
  const float* proj_hv   = (const float*)d_in[5];
  const float* times     = (const float*)d_in[6];
  const float* A_proj   = (const float*)d_in[7];
  const float* B_proj   = (const float*)d_in[8];
  const float* A_state  = (const float*)d_in[9];
  const float* B_state  = (const float*)d_in[10];
  const float* A_input  = (const float*)d_in[11];
  const float* B_input  = (const float*)d_in[12];
  const float* A_output = (const float*)d_in[13];
  const float* B_output = (const float*)d_in[14];
  const float* A_direct = (const float*)d_in[15];
  const float* B_direct = (const float*)d_in[16];

  float* ws = (float*)d_ws;
  unsigned short* WpT   = (unsigned short*)(ws + OFF_WPT);
  unsigned short* WoT   = (unsigned short*)(ws + OFF_WOT);
  unsigned short* WdiT  = (unsigned short*)(ws + OFF_WDIT);
  unsigned short* ctrlT = (unsigned short*)(ws + OFF_CTRLT);
  unsigned short* proj  = (unsigned short*)(ws + OFF_PROJ);
  float* projD = ws + OFF_PROJD;
  unsigned short* S2 = (unsigned short*)(ws + OFF_S2);
  float* Mpow = ws + OFF_MPOW;
  float* Ec   = ws + OFF_EC;
  float* Hc   = ws + OFF_HC;
  unsigned short* YT   = (unsigned short*)(ws + OFF_Y);
  unsigned short* sigT = (unsigned short*)(ws + OFF_SIG);
  float* out  = (float*)d_out;

  // K1: all weight builds + latents + ctrl^2 transpose in one launch
  megabuild_kernel<<<3856, 256, 0, stream>>>(
      proj_hv, state_hv, input_hv, output_hv, direct_hv,
      A_proj, A_state, A_input, A_output, A_direct,
      B_proj, B_state, B_input, B_output, B_direct,
      control, WpT, WoT, WdiT, Mpow + 16384, ctrlT);

  // proj = ctrlT @ WpT^T  (M=512,N=1024,K=512) -> bf16
  mfma_gemm_kernel<0, 1><<<dim3(8, 4, 8), 256, 0, stream>>>(
      ctrlT, WpT, nullptr, 0, proj, 512, 1024, 512);

  // projD = proj @ WdiT^T  (M=512,N=1152,K=1024) -> f32
  mfma_gemm_kernel<0, 0><<<dim3(9, 4, 8), 256, 0, stream>>>(
      proj, WdiT, nullptr, 0, projD, 512, 1152, 1024);

  // chunked scan
  powers_kernel<<<8, 256, 0, stream>>>(Mpow, 1);
  powers_kernel<<<16, 256, 0, stream>>>(Mpow, 2);
  powers_kernel<<<32, 256, 0, stream>>>(Mpow, 4);
  ec_kernel<<<512, 256, 0, stream>>>(Mpow, projD, Ec);
  combine_kernel<<<8, 128, 0, stream>>>(Mpow, Ec, Hc);
  pass2_kernel<<<512, 256, 0, stream>>>(Mpow, projD, Hc, S2);

  // YT = ((S2 @ WoT^T + direct) * win)^T  (M=512,N=1024,K=128) -> bf16 [N][M]
  mfma_gemm_kernel<1, 2><<<dim3(8, 4, 8), 256, 0, stream>>>(
      S2, WoT, projD, 1152, YT, 512, 1024, 128);

  // OLA: sigT[r][p] = YT[r][p] + YT[512+r][p-1]
  ola_kernel<<<2048, 256, 0, stream>>>(YT, sigT);

  // conv: softmax + Toeplitz-A on the fly + triangular MFMA GEMM -> out
  conv_mfma_kernel<<<dim3(4, 4, 8), 256, 0, stream>>>(times, sigT, out);
}